// Round 3
// baseline (1794.862 us; speedup 1.0000x reference)
//
#include <hip/hip_runtime.h>
#include <math.h>

#define D_   256
#define H_   8
#define HD_  32
#define L_   4
#define P_   4
#define DF_  1024
#define BS_  8
#define NQ_  900
#define NV_  21760
#define M1   (BS_*NQ_)   // 7200
#define MV   (BS_*NV_)   // 174080
#define QKVW 768         // fused qkv row width
#define OAW  384         // fused off+aw row width

// ---------------------------------------------------------------- small tiled fp32 GEMM: C = A[M,K] @ W[N,K]^T + bias (+res)
// 64x64 tile, 4x4 micro-tile. Used for the N=256 projections (sa_out, ca).
template<bool ADDRES>
__global__ __launch_bounds__(256) void gemm_rt(const float* __restrict__ A,
                                               const float* __restrict__ Wt,
                                               const float* __restrict__ bias,
                                               const float* __restrict__ res,
                                               float* __restrict__ C,
                                               int M, int N, int K)
{
    __shared__ float As[16][64];
    __shared__ float Ws[16][64];
    const int bm = blockIdx.y * 64, bn = blockIdx.x * 64;
    const int tid = threadIdx.x;
    const int tx = tid & 15, ty = tid >> 4;
    const int lr = tid >> 2, lk = (tid & 3) * 4;
    float acc[4][4] = {{0.f}};

    for (int k0 = 0; k0 < K; k0 += 16) {
        int gm = bm + lr;
        float4 a4 = make_float4(0.f, 0.f, 0.f, 0.f);
        if (gm < M) a4 = *(const float4*)&A[(size_t)gm * K + k0 + lk];
        As[lk + 0][lr] = a4.x; As[lk + 1][lr] = a4.y;
        As[lk + 2][lr] = a4.z; As[lk + 3][lr] = a4.w;
        int gn = bn + lr;                       // N multiple of 64
        float4 w4 = *(const float4*)&Wt[(size_t)gn * K + k0 + lk];
        Ws[lk + 0][lr] = w4.x; Ws[lk + 1][lr] = w4.y;
        Ws[lk + 2][lr] = w4.z; Ws[lk + 3][lr] = w4.w;
        __syncthreads();
        #pragma unroll
        for (int kk = 0; kk < 16; kk++) {
            float4 av = *(const float4*)&As[kk][ty * 4];
            float4 wv = *(const float4*)&Ws[kk][tx * 4];
            float aa[4] = {av.x, av.y, av.z, av.w};
            float ww[4] = {wv.x, wv.y, wv.z, wv.w};
            #pragma unroll
            for (int i = 0; i < 4; i++)
                #pragma unroll
                for (int j = 0; j < 4; j++)
                    acc[i][j] += aa[i] * ww[j];
        }
        __syncthreads();
    }
    #pragma unroll
    for (int i = 0; i < 4; i++) {
        int row = bm + ty * 4 + i;
        if (row >= M) continue;
        #pragma unroll
        for (int j = 0; j < 4; j++) {
            int col = bn + tx * 4 + j;
            float v = acc[i][j] + bias[col];
            if (ADDRES) v += res[(size_t)row * N + col];
            C[(size_t)row * N + col] = v;
        }
    }
}

// ---------------------------------------------------------------- big fp32 GEMM core: 128x128 tile, 8x8 micro-tile
// N % 128 == 0, K % 16 == 0. A-rows clamped, stores guarded on M.
template<bool RELU>
__global__ __launch_bounds__(256) void gemm_big(const float* __restrict__ A,
                                                const float* __restrict__ Wt,
                                                const float* __restrict__ bias,
                                                float* __restrict__ C,
                                                int M, int N, int K)
{
    __shared__ float As[16][128];
    __shared__ float Ws[16][128];
    const int bm = blockIdx.y * 128, bn = blockIdx.x * 128;
    const int tid = threadIdx.x;
    const int tx = tid & 15, ty = tid >> 4;
    const int lr = tid >> 1, lk = (tid & 1) * 8;

    const int arow = min(bm + lr, M - 1);
    const float* aptr = A  + (size_t)arow * K + lk;
    const float* wptr = Wt + (size_t)(bn + lr) * K + lk;

    float acc[8][8] = {{0.f}};

    for (int k0 = 0; k0 < K; k0 += 16) {
        float4 a0 = *(const float4*)(aptr + k0);
        float4 a1 = *(const float4*)(aptr + k0 + 4);
        float4 w0 = *(const float4*)(wptr + k0);
        float4 w1 = *(const float4*)(wptr + k0 + 4);
        As[lk + 0][lr] = a0.x; As[lk + 1][lr] = a0.y; As[lk + 2][lr] = a0.z; As[lk + 3][lr] = a0.w;
        As[lk + 4][lr] = a1.x; As[lk + 5][lr] = a1.y; As[lk + 6][lr] = a1.z; As[lk + 7][lr] = a1.w;
        Ws[lk + 0][lr] = w0.x; Ws[lk + 1][lr] = w0.y; Ws[lk + 2][lr] = w0.z; Ws[lk + 3][lr] = w0.w;
        Ws[lk + 4][lr] = w1.x; Ws[lk + 5][lr] = w1.y; Ws[lk + 6][lr] = w1.z; Ws[lk + 7][lr] = w1.w;
        __syncthreads();
        #pragma unroll
        for (int kk = 0; kk < 16; kk++) {
            float4 alo = *(const float4*)&As[kk][ty * 4];
            float4 ahi = *(const float4*)&As[kk][ty * 4 + 64];
            float4 wlo = *(const float4*)&Ws[kk][tx * 4];
            float4 whi = *(const float4*)&Ws[kk][tx * 4 + 64];
            float av[8] = {alo.x, alo.y, alo.z, alo.w, ahi.x, ahi.y, ahi.z, ahi.w};
            float wv[8] = {wlo.x, wlo.y, wlo.z, wlo.w, whi.x, whi.y, whi.z, whi.w};
            #pragma unroll
            for (int i = 0; i < 8; i++)
                #pragma unroll
                for (int j = 0; j < 8; j++)
                    acc[i][j] += av[i] * wv[j];
        }
        __syncthreads();
    }

    float4 blo = *(const float4*)&bias[bn + tx * 4];
    float4 bhi = *(const float4*)&bias[bn + 64 + tx * 4];
    #pragma unroll
    for (int i = 0; i < 8; i++) {
        int row = bm + ((i < 4) ? (ty * 4 + i) : (64 + ty * 4 + i - 4));
        if (row >= M) continue;
        float4 v0 = make_float4(acc[i][0] + blo.x, acc[i][1] + blo.y,
                                acc[i][2] + blo.z, acc[i][3] + blo.w);
        float4 v1 = make_float4(acc[i][4] + bhi.x, acc[i][5] + bhi.y,
                                acc[i][6] + bhi.z, acc[i][7] + bhi.w);
        if (RELU) {
            v0.x = fmaxf(v0.x, 0.f); v0.y = fmaxf(v0.y, 0.f);
            v0.z = fmaxf(v0.z, 0.f); v0.w = fmaxf(v0.w, 0.f);
            v1.x = fmaxf(v1.x, 0.f); v1.y = fmaxf(v1.y, 0.f);
            v1.z = fmaxf(v1.z, 0.f); v1.w = fmaxf(v1.w, 0.f);
        }
        *(float4*)&C[(size_t)row * N + bn + tx * 4]      = v0;
        *(float4*)&C[(size_t)row * N + bn + 64 + tx * 4] = v1;
    }
}

// ---------------------------------------------------------------- fused QKV projection
// C[M1][768] = [A_qk | A_qk | A_tgt-cols] @ sa_in_w^T + sa_in_b, where
// A_qk = tgt + qpos for output cols < 512 (q,k), A = tgt for cols >= 512 (v).
// Column tiles never straddle the 512 boundary (128 | 512).
__global__ __launch_bounds__(256) void gemm_qkv(const float* __restrict__ tgt,
                                                const float* __restrict__ qpos,
                                                const float* __restrict__ W,
                                                const float* __restrict__ bias,
                                                float* __restrict__ C)
{
    __shared__ float As[16][128];
    __shared__ float Ws[16][128];
    const int bm = blockIdx.y * 128, bn = blockIdx.x * 128;
    const bool useQK = (blockIdx.x < 4);
    const int tid = threadIdx.x;
    const int tx = tid & 15, ty = tid >> 4;
    const int lr = tid >> 1, lk = (tid & 1) * 8;

    const int arow = min(bm + lr, M1 - 1);
    const float* aptr = tgt  + (size_t)arow * D_ + lk;
    const float* pptr = qpos + (size_t)arow * D_ + lk;
    const float* wptr = W + (size_t)(bn + lr) * D_ + lk;

    float acc[8][8] = {{0.f}};

    for (int k0 = 0; k0 < D_; k0 += 16) {
        float4 a0 = *(const float4*)(aptr + k0);
        float4 a1 = *(const float4*)(aptr + k0 + 4);
        if (useQK) {
            float4 p0 = *(const float4*)(pptr + k0);
            float4 p1 = *(const float4*)(pptr + k0 + 4);
            a0.x += p0.x; a0.y += p0.y; a0.z += p0.z; a0.w += p0.w;
            a1.x += p1.x; a1.y += p1.y; a1.z += p1.z; a1.w += p1.w;
        }
        float4 w0 = *(const float4*)(wptr + k0);
        float4 w1 = *(const float4*)(wptr + k0 + 4);
        As[lk + 0][lr] = a0.x; As[lk + 1][lr] = a0.y; As[lk + 2][lr] = a0.z; As[lk + 3][lr] = a0.w;
        As[lk + 4][lr] = a1.x; As[lk + 5][lr] = a1.y; As[lk + 6][lr] = a1.z; As[lk + 7][lr] = a1.w;
        Ws[lk + 0][lr] = w0.x; Ws[lk + 1][lr] = w0.y; Ws[lk + 2][lr] = w0.z; Ws[lk + 3][lr] = w0.w;
        Ws[lk + 4][lr] = w1.x; Ws[lk + 5][lr] = w1.y; Ws[lk + 6][lr] = w1.z; Ws[lk + 7][lr] = w1.w;
        __syncthreads();
        #pragma unroll
        for (int kk = 0; kk < 16; kk++) {
            float4 alo = *(const float4*)&As[kk][ty * 4];
            float4 ahi = *(const float4*)&As[kk][ty * 4 + 64];
            float4 wlo = *(const float4*)&Ws[kk][tx * 4];
            float4 whi = *(const float4*)&Ws[kk][tx * 4 + 64];
            float av[8] = {alo.x, alo.y, alo.z, alo.w, ahi.x, ahi.y, ahi.z, ahi.w};
            float wv[8] = {wlo.x, wlo.y, wlo.z, wlo.w, whi.x, whi.y, whi.z, whi.w};
            #pragma unroll
            for (int i = 0; i < 8; i++)
                #pragma unroll
                for (int j = 0; j < 8; j++)
                    acc[i][j] += av[i] * wv[j];
        }
        __syncthreads();
    }

    float4 blo = *(const float4*)&bias[bn + tx * 4];
    float4 bhi = *(const float4*)&bias[bn + 64 + tx * 4];
    #pragma unroll
    for (int i = 0; i < 8; i++) {
        int row = bm + ((i < 4) ? (ty * 4 + i) : (64 + ty * 4 + i - 4));
        if (row >= M1) continue;
        float4 v0 = make_float4(acc[i][0] + blo.x, acc[i][1] + blo.y,
                                acc[i][2] + blo.z, acc[i][3] + blo.w);
        float4 v1 = make_float4(acc[i][4] + bhi.x, acc[i][5] + bhi.y,
                                acc[i][6] + bhi.z, acc[i][7] + bhi.w);
        *(float4*)&C[(size_t)row * QKVW + bn + tx * 4]      = v0;
        *(float4*)&C[(size_t)row * QKVW + bn + 64 + tx * 4] = v1;
    }
}

// ---------------------------------------------------------------- fused off+aw projection
// A = tgt2 + qpos (fused add). Output C[M1][384]: cols 0-255 = off, 256-383 = aw logits.
// Column tile 0,1 -> off_w/off_b; tile 2 -> aw_w/aw_b.
__global__ __launch_bounds__(256) void gemm_offaw(const float* __restrict__ t2,
                                                  const float* __restrict__ qpos,
                                                  const float* __restrict__ off_w,
                                                  const float* __restrict__ off_b,
                                                  const float* __restrict__ aw_w,
                                                  const float* __restrict__ aw_b,
                                                  float* __restrict__ C)
{
    __shared__ float As[16][128];
    __shared__ float Ws[16][128];
    const int bm = blockIdx.y * 128, bn = blockIdx.x * 128;
    const float* Wbase = (bn < 256) ? off_w + (size_t)bn * D_ : aw_w + (size_t)(bn - 256) * D_;
    const float* Bbase = (bn < 256) ? off_b + bn              : aw_b + (bn - 256);
    const int tid = threadIdx.x;
    const int tx = tid & 15, ty = tid >> 4;
    const int lr = tid >> 1, lk = (tid & 1) * 8;

    const int arow = min(bm + lr, M1 - 1);
    const float* aptr = t2   + (size_t)arow * D_ + lk;
    const float* pptr = qpos + (size_t)arow * D_ + lk;
    const float* wptr = Wbase + (size_t)lr * D_ + lk;

    float acc[8][8] = {{0.f}};

    for (int k0 = 0; k0 < D_; k0 += 16) {
        float4 a0 = *(const float4*)(aptr + k0);
        float4 a1 = *(const float4*)(aptr + k0 + 4);
        float4 p0 = *(const float4*)(pptr + k0);
        float4 p1 = *(const float4*)(pptr + k0 + 4);
        a0.x += p0.x; a0.y += p0.y; a0.z += p0.z; a0.w += p0.w;
        a1.x += p1.x; a1.y += p1.y; a1.z += p1.z; a1.w += p1.w;
        float4 w0 = *(const float4*)(wptr + k0);
        float4 w1 = *(const float4*)(wptr + k0 + 4);
        As[lk + 0][lr] = a0.x; As[lk + 1][lr] = a0.y; As[lk + 2][lr] = a0.z; As[lk + 3][lr] = a0.w;
        As[lk + 4][lr] = a1.x; As[lk + 5][lr] = a1.y; As[lk + 6][lr] = a1.z; As[lk + 7][lr] = a1.w;
        Ws[lk + 0][lr] = w0.x; Ws[lk + 1][lr] = w0.y; Ws[lk + 2][lr] = w0.z; Ws[lk + 3][lr] = w0.w;
        Ws[lk + 4][lr] = w1.x; Ws[lk + 5][lr] = w1.y; Ws[lk + 6][lr] = w1.z; Ws[lk + 7][lr] = w1.w;
        __syncthreads();
        #pragma unroll
        for (int kk = 0; kk < 16; kk++) {
            float4 alo = *(const float4*)&As[kk][ty * 4];
            float4 ahi = *(const float4*)&As[kk][ty * 4 + 64];
            float4 wlo = *(const float4*)&Ws[kk][tx * 4];
            float4 whi = *(const float4*)&Ws[kk][tx * 4 + 64];
            float av[8] = {alo.x, alo.y, alo.z, alo.w, ahi.x, ahi.y, ahi.z, ahi.w};
            float wv[8] = {wlo.x, wlo.y, wlo.z, wlo.w, whi.x, whi.y, whi.z, whi.w};
            #pragma unroll
            for (int i = 0; i < 8; i++)
                #pragma unroll
                for (int j = 0; j < 8; j++)
                    acc[i][j] += av[i] * wv[j];
        }
        __syncthreads();
    }

    float4 blo = make_float4(Bbase[tx*4], Bbase[tx*4+1], Bbase[tx*4+2], Bbase[tx*4+3]);
    float4 bhi = make_float4(Bbase[64+tx*4], Bbase[64+tx*4+1], Bbase[64+tx*4+2], Bbase[64+tx*4+3]);
    #pragma unroll
    for (int i = 0; i < 8; i++) {
        int row = bm + ((i < 4) ? (ty * 4 + i) : (64 + ty * 4 + i - 4));
        if (row >= M1) continue;
        float4 v0 = make_float4(acc[i][0] + blo.x, acc[i][1] + blo.y,
                                acc[i][2] + blo.z, acc[i][3] + blo.w);
        float4 v1 = make_float4(acc[i][4] + bhi.x, acc[i][5] + bhi.y,
                                acc[i][6] + bhi.z, acc[i][7] + bhi.w);
        *(float4*)&C[(size_t)row * OAW + bn + tx * 4]      = v0;
        *(float4*)&C[(size_t)row * OAW + bn + 64 + tx * 4] = v1;
    }
}

// ---------------------------------------------------------------- self-attention over fused QKV buffer
// q at col 0, k at col 256, v at col 512; row stride 768.
#define TQ 16
__global__ __launch_bounds__(256) void attn_kernel(const float* __restrict__ QKV,
                                                   float* __restrict__ SA)
{
    const int b = blockIdx.z, h = blockIdx.y, q0 = blockIdx.x * TQ;
    __shared__ float Qs[TQ][HD_];
    __shared__ float S[TQ][904];
    __shared__ float red[TQ][16];
    __shared__ float rowmax[TQ], rowsum[TQ];
    const int tid = threadIdx.x;

    for (int idx = tid; idx < TQ * HD_; idx += 256) {
        int qi = idx / HD_, d = idx % HD_;
        int gq = q0 + qi;
        Qs[qi][d] = (gq < NQ_) ? QKV[((size_t)(b * NQ_ + gq)) * QKVW + h * HD_ + d] : 0.f;
    }
    __syncthreads();

    const float scale = 0.17677669529663687f;   // 1/sqrt(32)
    for (int j = tid; j < NQ_; j += 256) {
        const float* kp = QKV + ((size_t)(b * NQ_ + j)) * QKVW + 256 + h * HD_;
        float kr[HD_];
        #pragma unroll
        for (int d = 0; d < HD_; d += 4) {
            float4 kv = *(const float4*)&kp[d];
            kr[d] = kv.x; kr[d+1] = kv.y; kr[d+2] = kv.z; kr[d+3] = kv.w;
        }
        #pragma unroll
        for (int qi = 0; qi < TQ; qi++) {
            float sacc = 0.f;
            #pragma unroll
            for (int d = 0; d < HD_; d++) sacc += Qs[qi][d] * kr[d];
            S[qi][j] = sacc * scale;
        }
    }
    __syncthreads();

    const int r = tid >> 4, c = tid & 15;
    float lmax = -1e30f;
    for (int j = c; j < NQ_; j += 16) lmax = fmaxf(lmax, S[r][j]);
    red[r][c] = lmax;
    __syncthreads();
    if (c == 0) {
        float m = red[r][0];
        #pragma unroll
        for (int i = 1; i < 16; i++) m = fmaxf(m, red[r][i]);
        rowmax[r] = m;
    }
    __syncthreads();
    {
        float m = rowmax[r];
        float lsum = 0.f;
        for (int j = c; j < NQ_; j += 16) {
            float e = __expf(S[r][j] - m);
            S[r][j] = e;
            lsum += e;
        }
        red[r][c] = lsum;
    }
    __syncthreads();
    if (c == 0) {
        float s2 = 0.f;
        #pragma unroll
        for (int i = 0; i < 16; i++) s2 += red[r][i];
        rowsum[r] = s2;
    }
    __syncthreads();

    float acc0 = 0.f, acc1 = 0.f, acc2 = 0.f, acc3 = 0.f;
    const float* vbase = QKV + ((size_t)b * NQ_) * QKVW + 512 + h * HD_;
    for (int j = 0; j < NQ_; j += 2) {           // NQ_ even
        float p0 = S[r][j], p1 = S[r][j + 1];
        acc0 += p0 * vbase[(size_t)j * QKVW + c];
        acc1 += p0 * vbase[(size_t)j * QKVW + c + 16];
        acc2 += p1 * vbase[(size_t)(j + 1) * QKVW + c];
        acc3 += p1 * vbase[(size_t)(j + 1) * QKVW + c + 16];
    }
    acc0 += acc2; acc1 += acc3;
    int gq = q0 + r;
    if (gq < NQ_) {
        float inv = 1.f / rowsum[r];
        SA[((size_t)(b * NQ_ + gq)) * D_ + h * HD_ + c]      = acc0 * inv;
        SA[((size_t)(b * NQ_ + gq)) * D_ + h * HD_ + c + 16] = acc1 * inv;
    }
}

// ---------------------------------------------------------------- LayerNorm(x + y) * g + b, one wave per 256-wide row
__global__ __launch_bounds__(64) void ln_kernel(const float* __restrict__ X,
                                                const float* __restrict__ Y,
                                                const float* __restrict__ g,
                                                const float* __restrict__ bt,
                                                float* __restrict__ out)
{
    const int row = blockIdx.x;
    const int lane = threadIdx.x;
    const size_t base = (size_t)row * D_ + lane * 4;
    float4 x = *(const float4*)&X[base];
    float4 y = *(const float4*)&Y[base];
    float v0 = x.x + y.x, v1 = x.y + y.y, v2 = x.z + y.z, v3 = x.w + y.w;
    float s = v0 + v1 + v2 + v3;
    #pragma unroll
    for (int o = 32; o; o >>= 1) s += __shfl_xor(s, o);
    float mean = s * (1.f / D_);
    float d0 = v0 - mean, d1 = v1 - mean, d2 = v2 - mean, d3 = v3 - mean;
    float ss = d0 * d0 + d1 * d1 + d2 * d2 + d3 * d3;
    #pragma unroll
    for (int o = 32; o; o >>= 1) ss += __shfl_xor(ss, o);
    float rstd = rsqrtf(ss * (1.f / D_) + 1e-5f);
    float4 gg = *(const float4*)&g[lane * 4];
    float4 bb = *(const float4*)&bt[lane * 4];
    float4 o4 = make_float4(d0 * rstd * gg.x + bb.x, d1 * rstd * gg.y + bb.y,
                            d2 * rstd * gg.z + bb.z, d3 * rstd * gg.w + bb.w);
    *(float4*)&out[base] = o4;
}

// ---------------------------------------------------------------- softmax over L*P=16 aw logits per (b,q,h), in place
// aw lives at cols [256,384) of the 384-wide offaw buffer.
__global__ __launch_bounds__(256) void aw_softmax_kernel(float* __restrict__ offaw)
{
    int t = blockIdx.x * 256 + threadIdx.x;
    if (t >= M1 * H_) return;
    const int bq = t >> 3, h = t & 7;
    float* p = offaw + (size_t)bq * OAW + 256 + h * 16;
    float v[16];
    #pragma unroll
    for (int i = 0; i < 16; i += 4) {
        float4 q = *(const float4*)&p[i];
        v[i] = q.x; v[i+1] = q.y; v[i+2] = q.z; v[i+3] = q.w;
    }
    float m = v[0];
    #pragma unroll
    for (int i = 1; i < 16; i++) m = fmaxf(m, v[i]);
    float s = 0.f;
    #pragma unroll
    for (int i = 0; i < 16; i++) { v[i] = __expf(v[i] - m); s += v[i]; }
    float inv = 1.f / s;
    #pragma unroll
    for (int i = 0; i < 16; i += 4) {
        float4 q = make_float4(v[i] * inv, v[i+1] * inv, v[i+2] * inv, v[i+3] * inv);
        *(float4*)&p[i] = q;
    }
}

// ---------------------------------------------------------------- MSDA bilinear sampling
// 32 lanes per (b,q,h): lane = channel. Each corner load is one coalesced
// 128B global_load_dword across the half-group; scalar params broadcast.
__global__ __launch_bounds__(256) void msda_kernel(const float* __restrict__ value,
                                                   const float* __restrict__ offaw,
                                                   const float* __restrict__ ref,
                                                   float* __restrict__ out)
{
    const int g    = threadIdx.x >> 5;           // 8 groups per block
    const int lane = threadIdx.x & 31;
    const int t    = blockIdx.x * 8 + g;         // grid exact: t < M1*H_
    const int h  = t & 7;
    const int bq = t >> 3;
    const int b  = bq / NQ_;
    const float* offp = offaw + (size_t)bq * OAW + h * (L_ * P_ * 2);
    const float* awp  = offaw + (size_t)bq * OAW + 256 + h * (L_ * P_);
    const float* refp = ref + (size_t)bq * (L_ * 2);
    const float* vb   = value + ((size_t)b * NV_) * D_ + h * HD_ + lane;

    float acc = 0.f;
    const int LW[4] = {128, 64, 32, 16};
    const int LS[4] = {0, 16384, 20480, 21504};

    #pragma unroll
    for (int l = 0; l < L_; l++) {
        const int wi = LW[l];
        const float Wf = (float)wi;              // square levels: W == H
        float rx = refp[2 * l], ry = refp[2 * l + 1];
        #pragma unroll
        for (int p = 0; p < P_; p++) {
            float ox = offp[(l * P_ + p) * 2];
            float oy = offp[(l * P_ + p) * 2 + 1];
            float a  = awp[l * P_ + p];
            // loc*W - 0.5 = (ref + off/W)*W - 0.5 = ref*W + off - 0.5
            float lx = rx * Wf + ox - 0.5f;
            float ly = ry * Wf + oy - 0.5f;
            float x0f = floorf(lx), y0f = floorf(ly);
            float fx = lx - x0f, fy = ly - y0f;
            int x0 = (int)x0f, y0 = (int)y0f;
            #pragma unroll
            for (int dy = 0; dy < 2; dy++) {
                int yi = y0 + dy;
                if (yi < 0 || yi >= wi) continue;
                float wy = dy ? fy : 1.f - fy;
                #pragma unroll
                for (int dx = 0; dx < 2; dx++) {
                    int xi = x0 + dx;
                    if (xi < 0 || xi >= wi) continue;
                    float w = wy * (dx ? fx : 1.f - fx) * a;
                    acc += w * vb[(size_t)(LS[l] + yi * wi + xi) * D_];
                }
            }
        }
    }
    out[(size_t)bq * D_ + h * HD_ + lane] = acc;
}

// ---------------------------------------------------------------- launch
extern "C" void kernel_launch(void* const* d_in, const int* in_sizes, int n_in,
                              void* d_out, int out_size, void* d_ws, size_t ws_size,
                              hipStream_t stream)
{
    const float* tgt      = (const float*)d_in[0];
    const float* qpos     = (const float*)d_in[1];
    const float* ref      = (const float*)d_in[2];
    const float* src      = (const float*)d_in[3];
    const float* sa_in_w  = (const float*)d_in[4];
    const float* sa_in_b  = (const float*)d_in[5];
    const float* sa_out_w = (const float*)d_in[6];
    const float* sa_out_b = (const float*)d_in[7];
    const float* ln2_g    = (const float*)d_in[8];
    const float* ln2_b    = (const float*)d_in[9];
    const float* off_w    = (const float*)d_in[10];
    const float* off_b    = (const float*)d_in[11];
    const float* aw_w     = (const float*)d_in[12];
    const float* aw_b     = (const float*)d_in[13];
    const float* val_w    = (const float*)d_in[14];
    const float* val_b    = (const float*)d_in[15];
    const float* out_w    = (const float*)d_in[16];
    const float* out_b    = (const float*)d_in[17];
    const float* ln1_g    = (const float*)d_in[18];
    const float* ln1_b    = (const float*)d_in[19];
    const float* ffn1_w   = (const float*)d_in[20];
    const float* ffn1_b   = (const float*)d_in[21];
    const float* ffn2_w   = (const float*)d_in[22];
    const float* ffn2_b   = (const float*)d_in[23];
    const float* ln3_g    = (const float*)d_in[24];
    const float* ln3_b    = (const float*)d_in[25];

    // ---- workspace layout (222.5 MB of fp32), with lifetime-checked aliases ----
    float* ws    = (float*)d_ws;
    float* value = ws;                               // [MV*256]  44,564,480 f
    float* qkv   = ws + (size_t)MV * D_;             // [M1*768]   5,529,600 f
    float* battn = qkv + (size_t)M1 * QKVW;          // [M1*256]   1,843,200 f
    float* b2    = battn + (size_t)M1 * D_;          // [M1*256]  tgt2 (LN2 out)
    float* b4    = b2 + (size_t)M1 * D_;             // [M1*256]  tgt3 (LN1 out)
    // aliases into dead regions:
    float* bsa   = qkv;                              // sa_out out   (qkv dead after attn)
    float* offaw = qkv + (size_t)M1 * D_;            // [M1*384]     (fits in qkv region)
    float* bmsda = qkv;                              // msda out     (bsa dead after ln2)
    float* bca   = battn;                            // ca out       (battn dead after sa_out)
    float* hid   = value;                            // ffn hidden   (value dead after msda)
    float* bffn  = qkv;                              // ffn2 out     (bmsda dead after ca gemm)
    float* out   = (float*)d_out;

    // 1. fused qkv projection (q,k use tgt+qpos; v uses tgt)
    gemm_qkv<<<dim3(QKVW / 128, (M1 + 127) / 128), 256, 0, stream>>>(
        tgt, qpos, sa_in_w, sa_in_b, qkv);
    // 2. value = src @ val_w^T + val_b   (the big one: 174080x256x256)
    gemm_big<false><<<dim3(D_ / 128, (MV + 127) / 128), 256, 0, stream>>>(
        src, val_w, val_b, value, MV, D_, D_);
    // 3. self-attention
    attn_kernel<<<dim3((NQ_ + TQ - 1) / TQ, H_, BS_), 256, 0, stream>>>(qkv, battn);
    // 4. sa_out projection
    gemm_rt<false><<<dim3(D_ / 64, (M1 + 63) / 64), 256, 0, stream>>>(
        battn, sa_out_w, sa_out_b, nullptr, bsa, M1, D_, D_);
    // 5. tgt2 = LN(tgt + sa)
    ln_kernel<<<M1, 64, 0, stream>>>(tgt, bsa, ln2_g, ln2_b, b2);
    // 6. fused off+aw projection (A = tgt2 + qpos)
    gemm_offaw<<<dim3(OAW / 128, (M1 + 127) / 128), 256, 0, stream>>>(
        b2, qpos, off_w, off_b, aw_w, aw_b, offaw);
    // 7. softmax over aw logits
    aw_softmax_kernel<<<(M1 * H_ + 255) / 256, 256, 0, stream>>>(offaw);
    // 8. MSDA sampling (grid exact: 57600/8 = 7200 blocks)
    msda_kernel<<<M1 * H_ / 8, 256, 0, stream>>>(value, offaw, ref, bmsda);
    // 9. ca = msda @ out_w^T + out_b + tgt2
    gemm_rt<true><<<dim3(D_ / 64, (M1 + 63) / 64), 256, 0, stream>>>(
        bmsda, out_w, out_b, b2, bca, M1, D_, D_);
    // 10. tgt3 = LN(tgt2 + ca)
    ln_kernel<<<M1, 64, 0, stream>>>(b2, bca, ln1_g, ln1_b, b4);
    // 11. FFN
    gemm_big<true><<<dim3(DF_ / 128, (M1 + 127) / 128), 256, 0, stream>>>(
        b4, ffn1_w, ffn1_b, hid, M1, DF_, D_);
    gemm_big<false><<<dim3(D_ / 128, (M1 + 127) / 128), 256, 0, stream>>>(
        hid, ffn2_w, ffn2_b, bffn, M1, D_, DF_);
    // 12. out = LN(tgt3 + ffn)
    ln_kernel<<<M1, 64, 0, stream>>>(b4, bffn, ln3_g, ln3_b, out);
}

// Round 4
// 1353.315 us; speedup vs baseline: 1.3263x; 1.3263x over previous
//
#include <hip/hip_runtime.h>
#include <math.h>

#define D_   256
#define H_   8
#define HD_  32
#define L_   4
#define P_   4
#define DF_  1024
#define BS_  8
#define NQ_  900
#define NV_  21760
#define M1   (BS_*NQ_)   // 7200
#define MV   (BS_*NV_)   // 174080
#define QKVW 768         // fused qkv row width
#define OAW  384         // fused off+aw row width

// ---------------------------------------------------------------- small tiled fp32 GEMM: C = A[M,K] @ W[N,K]^T + bias (+res)
// 64x64 tile, 4x4 micro-tile. Used for the N=256 projections (sa_out, ca).
template<bool ADDRES>
__global__ __launch_bounds__(256) void gemm_rt(const float* __restrict__ A,
                                               const float* __restrict__ Wt,
                                               const float* __restrict__ bias,
                                               const float* __restrict__ res,
                                               float* __restrict__ C,
                                               int M, int N, int K)
{
    __shared__ float As[16][64];
    __shared__ float Ws[16][64];
    const int bm = blockIdx.y * 64, bn = blockIdx.x * 64;
    const int tid = threadIdx.x;
    const int tx = tid & 15, ty = tid >> 4;
    const int lr = tid >> 2, lk = (tid & 3) * 4;
    float acc[4][4] = {{0.f}};

    for (int k0 = 0; k0 < K; k0 += 16) {
        int gm = bm + lr;
        float4 a4 = make_float4(0.f, 0.f, 0.f, 0.f);
        if (gm < M) a4 = *(const float4*)&A[(size_t)gm * K + k0 + lk];
        As[lk + 0][lr] = a4.x; As[lk + 1][lr] = a4.y;
        As[lk + 2][lr] = a4.z; As[lk + 3][lr] = a4.w;
        int gn = bn + lr;                       // N multiple of 64
        float4 w4 = *(const float4*)&Wt[(size_t)gn * K + k0 + lk];
        Ws[lk + 0][lr] = w4.x; Ws[lk + 1][lr] = w4.y;
        Ws[lk + 2][lr] = w4.z; Ws[lk + 3][lr] = w4.w;
        __syncthreads();
        #pragma unroll
        for (int kk = 0; kk < 16; kk++) {
            float4 av = *(const float4*)&As[kk][ty * 4];
            float4 wv = *(const float4*)&Ws[kk][tx * 4];
            float aa[4] = {av.x, av.y, av.z, av.w};
            float ww[4] = {wv.x, wv.y, wv.z, wv.w};
            #pragma unroll
            for (int i = 0; i < 4; i++)
                #pragma unroll
                for (int j = 0; j < 4; j++)
                    acc[i][j] += aa[i] * ww[j];
        }
        __syncthreads();
    }
    #pragma unroll
    for (int i = 0; i < 4; i++) {
        int row = bm + ty * 4 + i;
        if (row >= M) continue;
        #pragma unroll
        for (int j = 0; j < 4; j++) {
            int col = bn + tx * 4 + j;
            float v = acc[i][j] + bias[col];
            if (ADDRES) v += res[(size_t)row * N + col];
            C[(size_t)row * N + col] = v;
        }
    }
}

// ---------------------------------------------------------------- big fp32 GEMM core: 128x128 tile, 8x8 micro-tile
// N % 128 == 0, K % 16 == 0. A-rows clamped, stores guarded on M.
template<bool RELU>
__global__ __launch_bounds__(256) void gemm_big(const float* __restrict__ A,
                                                const float* __restrict__ Wt,
                                                const float* __restrict__ bias,
                                                float* __restrict__ C,
                                                int M, int N, int K)
{
    __shared__ float As[16][128];
    __shared__ float Ws[16][128];
    const int bm = blockIdx.y * 128, bn = blockIdx.x * 128;
    const int tid = threadIdx.x;
    const int tx = tid & 15, ty = tid >> 4;
    const int lr = tid >> 1, lk = (tid & 1) * 8;

    const int arow = min(bm + lr, M - 1);
    const float* aptr = A  + (size_t)arow * K + lk;
    const float* wptr = Wt + (size_t)(bn + lr) * K + lk;

    float acc[8][8] = {{0.f}};

    for (int k0 = 0; k0 < K; k0 += 16) {
        float4 a0 = *(const float4*)(aptr + k0);
        float4 a1 = *(const float4*)(aptr + k0 + 4);
        float4 w0 = *(const float4*)(wptr + k0);
        float4 w1 = *(const float4*)(wptr + k0 + 4);
        As[lk + 0][lr] = a0.x; As[lk + 1][lr] = a0.y; As[lk + 2][lr] = a0.z; As[lk + 3][lr] = a0.w;
        As[lk + 4][lr] = a1.x; As[lk + 5][lr] = a1.y; As[lk + 6][lr] = a1.z; As[lk + 7][lr] = a1.w;
        Ws[lk + 0][lr] = w0.x; Ws[lk + 1][lr] = w0.y; Ws[lk + 2][lr] = w0.z; Ws[lk + 3][lr] = w0.w;
        Ws[lk + 4][lr] = w1.x; Ws[lk + 5][lr] = w1.y; Ws[lk + 6][lr] = w1.z; Ws[lk + 7][lr] = w1.w;
        __syncthreads();
        #pragma unroll
        for (int kk = 0; kk < 16; kk++) {
            float4 alo = *(const float4*)&As[kk][ty * 4];
            float4 ahi = *(const float4*)&As[kk][ty * 4 + 64];
            float4 wlo = *(const float4*)&Ws[kk][tx * 4];
            float4 whi = *(const float4*)&Ws[kk][tx * 4 + 64];
            float av[8] = {alo.x, alo.y, alo.z, alo.w, ahi.x, ahi.y, ahi.z, ahi.w};
            float wv[8] = {wlo.x, wlo.y, wlo.z, wlo.w, whi.x, whi.y, whi.z, whi.w};
            #pragma unroll
            for (int i = 0; i < 8; i++)
                #pragma unroll
                for (int j = 0; j < 8; j++)
                    acc[i][j] += av[i] * wv[j];
        }
        __syncthreads();
    }

    float4 blo = *(const float4*)&bias[bn + tx * 4];
    float4 bhi = *(const float4*)&bias[bn + 64 + tx * 4];
    #pragma unroll
    for (int i = 0; i < 8; i++) {
        int row = bm + ((i < 4) ? (ty * 4 + i) : (64 + ty * 4 + i - 4));
        if (row >= M) continue;
        float4 v0 = make_float4(acc[i][0] + blo.x, acc[i][1] + blo.y,
                                acc[i][2] + blo.z, acc[i][3] + blo.w);
        float4 v1 = make_float4(acc[i][4] + bhi.x, acc[i][5] + bhi.y,
                                acc[i][6] + bhi.z, acc[i][7] + bhi.w);
        if (RELU) {
            v0.x = fmaxf(v0.x, 0.f); v0.y = fmaxf(v0.y, 0.f);
            v0.z = fmaxf(v0.z, 0.f); v0.w = fmaxf(v0.w, 0.f);
            v1.x = fmaxf(v1.x, 0.f); v1.y = fmaxf(v1.y, 0.f);
            v1.z = fmaxf(v1.z, 0.f); v1.w = fmaxf(v1.w, 0.f);
        }
        *(float4*)&C[(size_t)row * N + bn + tx * 4]      = v0;
        *(float4*)&C[(size_t)row * N + bn + 64 + tx * 4] = v1;
    }
}

// ---------------------------------------------------------------- fused QKV projection
__global__ __launch_bounds__(256) void gemm_qkv(const float* __restrict__ tgt,
                                                const float* __restrict__ qpos,
                                                const float* __restrict__ W,
                                                const float* __restrict__ bias,
                                                float* __restrict__ C)
{
    __shared__ float As[16][128];
    __shared__ float Ws[16][128];
    const int bm = blockIdx.y * 128, bn = blockIdx.x * 128;
    const bool useQK = (blockIdx.x < 4);
    const int tid = threadIdx.x;
    const int tx = tid & 15, ty = tid >> 4;
    const int lr = tid >> 1, lk = (tid & 1) * 8;

    const int arow = min(bm + lr, M1 - 1);
    const float* aptr = tgt  + (size_t)arow * D_ + lk;
    const float* pptr = qpos + (size_t)arow * D_ + lk;
    const float* wptr = W + (size_t)(bn + lr) * D_ + lk;

    float acc[8][8] = {{0.f}};

    for (int k0 = 0; k0 < D_; k0 += 16) {
        float4 a0 = *(const float4*)(aptr + k0);
        float4 a1 = *(const float4*)(aptr + k0 + 4);
        if (useQK) {
            float4 p0 = *(const float4*)(pptr + k0);
            float4 p1 = *(const float4*)(pptr + k0 + 4);
            a0.x += p0.x; a0.y += p0.y; a0.z += p0.z; a0.w += p0.w;
            a1.x += p1.x; a1.y += p1.y; a1.z += p1.z; a1.w += p1.w;
        }
        float4 w0 = *(const float4*)(wptr + k0);
        float4 w1 = *(const float4*)(wptr + k0 + 4);
        As[lk + 0][lr] = a0.x; As[lk + 1][lr] = a0.y; As[lk + 2][lr] = a0.z; As[lk + 3][lr] = a0.w;
        As[lk + 4][lr] = a1.x; As[lk + 5][lr] = a1.y; As[lk + 6][lr] = a1.z; As[lk + 7][lr] = a1.w;
        Ws[lk + 0][lr] = w0.x; Ws[lk + 1][lr] = w0.y; Ws[lk + 2][lr] = w0.z; Ws[lk + 3][lr] = w0.w;
        Ws[lk + 4][lr] = w1.x; Ws[lk + 5][lr] = w1.y; Ws[lk + 6][lr] = w1.z; Ws[lk + 7][lr] = w1.w;
        __syncthreads();
        #pragma unroll
        for (int kk = 0; kk < 16; kk++) {
            float4 alo = *(const float4*)&As[kk][ty * 4];
            float4 ahi = *(const float4*)&As[kk][ty * 4 + 64];
            float4 wlo = *(const float4*)&Ws[kk][tx * 4];
            float4 whi = *(const float4*)&Ws[kk][tx * 4 + 64];
            float av[8] = {alo.x, alo.y, alo.z, alo.w, ahi.x, ahi.y, ahi.z, ahi.w};
            float wv[8] = {wlo.x, wlo.y, wlo.z, wlo.w, whi.x, whi.y, whi.z, whi.w};
            #pragma unroll
            for (int i = 0; i < 8; i++)
                #pragma unroll
                for (int j = 0; j < 8; j++)
                    acc[i][j] += av[i] * wv[j];
        }
        __syncthreads();
    }

    float4 blo = *(const float4*)&bias[bn + tx * 4];
    float4 bhi = *(const float4*)&bias[bn + 64 + tx * 4];
    #pragma unroll
    for (int i = 0; i < 8; i++) {
        int row = bm + ((i < 4) ? (ty * 4 + i) : (64 + ty * 4 + i - 4));
        if (row >= M1) continue;
        float4 v0 = make_float4(acc[i][0] + blo.x, acc[i][1] + blo.y,
                                acc[i][2] + blo.z, acc[i][3] + blo.w);
        float4 v1 = make_float4(acc[i][4] + bhi.x, acc[i][5] + bhi.y,
                                acc[i][6] + bhi.z, acc[i][7] + bhi.w);
        *(float4*)&C[(size_t)row * QKVW + bn + tx * 4]      = v0;
        *(float4*)&C[(size_t)row * QKVW + bn + 64 + tx * 4] = v1;
    }
}

// ---------------------------------------------------------------- fused off+aw projection
__global__ __launch_bounds__(256) void gemm_offaw(const float* __restrict__ t2,
                                                  const float* __restrict__ qpos,
                                                  const float* __restrict__ off_w,
                                                  const float* __restrict__ off_b,
                                                  const float* __restrict__ aw_w,
                                                  const float* __restrict__ aw_b,
                                                  float* __restrict__ C)
{
    __shared__ float As[16][128];
    __shared__ float Ws[16][128];
    const int bm = blockIdx.y * 128, bn = blockIdx.x * 128;
    const float* Wbase = (bn < 256) ? off_w + (size_t)bn * D_ : aw_w + (size_t)(bn - 256) * D_;
    const float* Bbase = (bn < 256) ? off_b + bn              : aw_b + (bn - 256);
    const int tid = threadIdx.x;
    const int tx = tid & 15, ty = tid >> 4;
    const int lr = tid >> 1, lk = (tid & 1) * 8;

    const int arow = min(bm + lr, M1 - 1);
    const float* aptr = t2   + (size_t)arow * D_ + lk;
    const float* pptr = qpos + (size_t)arow * D_ + lk;
    const float* wptr = Wbase + (size_t)lr * D_ + lk;

    float acc[8][8] = {{0.f}};

    for (int k0 = 0; k0 < D_; k0 += 16) {
        float4 a0 = *(const float4*)(aptr + k0);
        float4 a1 = *(const float4*)(aptr + k0 + 4);
        float4 p0 = *(const float4*)(pptr + k0);
        float4 p1 = *(const float4*)(pptr + k0 + 4);
        a0.x += p0.x; a0.y += p0.y; a0.z += p0.z; a0.w += p0.w;
        a1.x += p1.x; a1.y += p1.y; a1.z += p1.z; a1.w += p1.w;
        float4 w0 = *(const float4*)(wptr + k0);
        float4 w1 = *(const float4*)(wptr + k0 + 4);
        As[lk + 0][lr] = a0.x; As[lk + 1][lr] = a0.y; As[lk + 2][lr] = a0.z; As[lk + 3][lr] = a0.w;
        As[lk + 4][lr] = a1.x; As[lk + 5][lr] = a1.y; As[lk + 6][lr] = a1.z; As[lk + 7][lr] = a1.w;
        Ws[lk + 0][lr] = w0.x; Ws[lk + 1][lr] = w0.y; Ws[lk + 2][lr] = w0.z; Ws[lk + 3][lr] = w0.w;
        Ws[lk + 4][lr] = w1.x; Ws[lk + 5][lr] = w1.y; Ws[lk + 6][lr] = w1.z; Ws[lk + 7][lr] = w1.w;
        __syncthreads();
        #pragma unroll
        for (int kk = 0; kk < 16; kk++) {
            float4 alo = *(const float4*)&As[kk][ty * 4];
            float4 ahi = *(const float4*)&As[kk][ty * 4 + 64];
            float4 wlo = *(const float4*)&Ws[kk][tx * 4];
            float4 whi = *(const float4*)&Ws[kk][tx * 4 + 64];
            float av[8] = {alo.x, alo.y, alo.z, alo.w, ahi.x, ahi.y, ahi.z, ahi.w};
            float wv[8] = {wlo.x, wlo.y, wlo.z, wlo.w, whi.x, whi.y, whi.z, whi.w};
            #pragma unroll
            for (int i = 0; i < 8; i++)
                #pragma unroll
                for (int j = 0; j < 8; j++)
                    acc[i][j] += av[i] * wv[j];
        }
        __syncthreads();
    }

    float4 blo = make_float4(Bbase[tx*4], Bbase[tx*4+1], Bbase[tx*4+2], Bbase[tx*4+3]);
    float4 bhi = make_float4(Bbase[64+tx*4], Bbase[64+tx*4+1], Bbase[64+tx*4+2], Bbase[64+tx*4+3]);
    #pragma unroll
    for (int i = 0; i < 8; i++) {
        int row = bm + ((i < 4) ? (ty * 4 + i) : (64 + ty * 4 + i - 4));
        if (row >= M1) continue;
        float4 v0 = make_float4(acc[i][0] + blo.x, acc[i][1] + blo.y,
                                acc[i][2] + blo.z, acc[i][3] + blo.w);
        float4 v1 = make_float4(acc[i][4] + bhi.x, acc[i][5] + bhi.y,
                                acc[i][6] + bhi.z, acc[i][7] + bhi.w);
        *(float4*)&C[(size_t)row * OAW + bn + tx * 4]      = v0;
        *(float4*)&C[(size_t)row * OAW + bn + 64 + tx * 4] = v1;
    }
}

// ---------------------------------------------------------------- flash self-attention, online softmax, S never materialized
// Block = 128 threads (2 waves) = 128 queries of one (b,h).
// Thread: 2 queries x 16 channels (d-half across wave half); full score via shfl_xor(32).
// K/V tiled 64 keys in LDS (16 KB). All inner-loop LDS reads are broadcasts (0 conflicts).
#define ATK 64
__global__ __launch_bounds__(128) void attn_kernel(const float* __restrict__ QKV,
                                                   float* __restrict__ SA)
{
    const int b = blockIdx.z, h = blockIdx.y;
    const int q0 = blockIdx.x * 128;
    const int tid  = threadIdx.x;
    const int wave = tid >> 6, lane = tid & 63;
    const int qi = lane & 31, half = lane >> 5;

    __shared__ float Ks[ATK][HD_];
    __shared__ float Vs[ATK][HD_];

    const int q_a = q0 + wave * 64 + qi * 2;     // may exceed NQ_-1 (tail)
    const int q_b = q_a + 1;
    const int qa_c = min(q_a, NQ_ - 1);
    const int qb_c = min(q_b, NQ_ - 1);

    const float scale = 0.17677669529663687f;    // 1/sqrt(32)
    float Qa[16], Qb[16];
    {
        const float* pa = QKV + ((size_t)(b * NQ_ + qa_c)) * QKVW + h * HD_ + half * 16;
        const float* pb = QKV + ((size_t)(b * NQ_ + qb_c)) * QKVW + h * HD_ + half * 16;
        #pragma unroll
        for (int i = 0; i < 16; i += 4) {
            float4 va = *(const float4*)&pa[i];
            float4 vb = *(const float4*)&pb[i];
            Qa[i] = va.x * scale; Qa[i+1] = va.y * scale; Qa[i+2] = va.z * scale; Qa[i+3] = va.w * scale;
            Qb[i] = vb.x * scale; Qb[i+1] = vb.y * scale; Qb[i+2] = vb.z * scale; Qb[i+3] = vb.w * scale;
        }
    }

    float ma = -INFINITY, la = 0.f, mb = -INFINITY, lb = 0.f;
    float aa[16], ab[16];
    #pragma unroll
    for (int i = 0; i < 16; i++) { aa[i] = 0.f; ab[i] = 0.f; }

    for (int j0 = 0; j0 < NQ_; j0 += ATK) {
        const int jn = min(ATK, NQ_ - j0);
        __syncthreads();                          // previous tile fully consumed
        for (int f = tid; f < ATK * HD_ / 4; f += 128) {
            int j = f >> 3, d4 = (f & 7) << 2;
            if (j < jn) {
                const float* kp = QKV + ((size_t)(b * NQ_ + j0 + j)) * QKVW + 256 + h * HD_ + d4;
                *(float4*)&Ks[j][d4] = *(const float4*)kp;
                *(float4*)&Vs[j][d4] = *(const float4*)(kp + 256);
            }
        }
        __syncthreads();

        for (int j = 0; j < jn; j++) {
            float kr[16];
            #pragma unroll
            for (int i = 0; i < 16; i += 4) {
                float4 kv = *(const float4*)&Ks[j][half * 16 + i];
                kr[i] = kv.x; kr[i+1] = kv.y; kr[i+2] = kv.z; kr[i+3] = kv.w;
            }
            float sa0 = 0.f, sa1 = 0.f, sa2 = 0.f, sa3 = 0.f;
            float sb0 = 0.f, sb1 = 0.f, sb2 = 0.f, sb3 = 0.f;
            #pragma unroll
            for (int i = 0; i < 16; i += 4) {
                sa0 += Qa[i] * kr[i];   sa1 += Qa[i+1] * kr[i+1];
                sa2 += Qa[i+2] * kr[i+2]; sa3 += Qa[i+3] * kr[i+3];
                sb0 += Qb[i] * kr[i];   sb1 += Qb[i+1] * kr[i+1];
                sb2 += Qb[i+2] * kr[i+2]; sb3 += Qb[i+3] * kr[i+3];
            }
            float sA = (sa0 + sa1) + (sa2 + sa3);
            float sB = (sb0 + sb1) + (sb2 + sb3);
            sA += __shfl_xor(sA, 32);             // combine the two d-halves
            sB += __shfl_xor(sB, 32);

            float vr[16];
            #pragma unroll
            for (int i = 0; i < 16; i += 4) {
                float4 vv = *(const float4*)&Vs[j][half * 16 + i];
                vr[i] = vv.x; vr[i+1] = vv.y; vr[i+2] = vv.z; vr[i+3] = vv.w;
            }

            if (sA > ma) {                        // rare after warm-up (defer-max)
                float sc = __expf(ma - sA);
                la *= sc;
                #pragma unroll
                for (int i = 0; i < 16; i++) aa[i] *= sc;
                ma = sA;
            }
            float pA = __expf(sA - ma);
            la += pA;
            #pragma unroll
            for (int i = 0; i < 16; i++) aa[i] += pA * vr[i];

            if (sB > mb) {
                float sc = __expf(mb - sB);
                lb *= sc;
                #pragma unroll
                for (int i = 0; i < 16; i++) ab[i] *= sc;
                mb = sB;
            }
            float pB = __expf(sB - mb);
            lb += pB;
            #pragma unroll
            for (int i = 0; i < 16; i++) ab[i] += pB * vr[i];
        }
    }

    if (q_a < NQ_) {
        float inv = 1.f / la;
        float* op = SA + ((size_t)(b * NQ_ + q_a)) * D_ + h * HD_ + half * 16;
        #pragma unroll
        for (int i = 0; i < 16; i += 4) {
            float4 v = make_float4(aa[i]*inv, aa[i+1]*inv, aa[i+2]*inv, aa[i+3]*inv);
            *(float4*)&op[i] = v;
        }
    }
    if (q_b < NQ_) {
        float inv = 1.f / lb;
        float* op = SA + ((size_t)(b * NQ_ + q_b)) * D_ + h * HD_ + half * 16;
        #pragma unroll
        for (int i = 0; i < 16; i += 4) {
            float4 v = make_float4(ab[i]*inv, ab[i+1]*inv, ab[i+2]*inv, ab[i+3]*inv);
            *(float4*)&op[i] = v;
        }
    }
}

// ---------------------------------------------------------------- LayerNorm(x + y) * g + b, one wave per 256-wide row
__global__ __launch_bounds__(64) void ln_kernel(const float* __restrict__ X,
                                                const float* __restrict__ Y,
                                                const float* __restrict__ g,
                                                const float* __restrict__ bt,
                                                float* __restrict__ out)
{
    const int row = blockIdx.x;
    const int lane = threadIdx.x;
    const size_t base = (size_t)row * D_ + lane * 4;
    float4 x = *(const float4*)&X[base];
    float4 y = *(const float4*)&Y[base];
    float v0 = x.x + y.x, v1 = x.y + y.y, v2 = x.z + y.z, v3 = x.w + y.w;
    float s = v0 + v1 + v2 + v3;
    #pragma unroll
    for (int o = 32; o; o >>= 1) s += __shfl_xor(s, o);
    float mean = s * (1.f / D_);
    float d0 = v0 - mean, d1 = v1 - mean, d2 = v2 - mean, d3 = v3 - mean;
    float ss = d0 * d0 + d1 * d1 + d2 * d2 + d3 * d3;
    #pragma unroll
    for (int o = 32; o; o >>= 1) ss += __shfl_xor(ss, o);
    float rstd = rsqrtf(ss * (1.f / D_) + 1e-5f);
    float4 gg = *(const float4*)&g[lane * 4];
    float4 bb = *(const float4*)&bt[lane * 4];
    float4 o4 = make_float4(d0 * rstd * gg.x + bb.x, d1 * rstd * gg.y + bb.y,
                            d2 * rstd * gg.z + bb.z, d3 * rstd * gg.w + bb.w);
    *(float4*)&out[base] = o4;
}

// ---------------------------------------------------------------- softmax over L*P=16 aw logits per (b,q,h), in place
__global__ __launch_bounds__(256) void aw_softmax_kernel(float* __restrict__ offaw)
{
    int t = blockIdx.x * 256 + threadIdx.x;
    if (t >= M1 * H_) return;
    const int bq = t >> 3, h = t & 7;
    float* p = offaw + (size_t)bq * OAW + 256 + h * 16;
    float v[16];
    #pragma unroll
    for (int i = 0; i < 16; i += 4) {
        float4 q = *(const float4*)&p[i];
        v[i] = q.x; v[i+1] = q.y; v[i+2] = q.z; v[i+3] = q.w;
    }
    float m = v[0];
    #pragma unroll
    for (int i = 1; i < 16; i++) m = fmaxf(m, v[i]);
    float s = 0.f;
    #pragma unroll
    for (int i = 0; i < 16; i++) { v[i] = __expf(v[i] - m); s += v[i]; }
    float inv = 1.f / s;
    #pragma unroll
    for (int i = 0; i < 16; i += 4) {
        float4 q = make_float4(v[i] * inv, v[i+1] * inv, v[i+2] * inv, v[i+3] * inv);
        *(float4*)&p[i] = q;
    }
}

// ---------------------------------------------------------------- MSDA bilinear sampling
// 32 lanes per (b,q,h): lane = channel. Each corner load is one coalesced
// 128B global_load_dword across the half-group; scalar params broadcast.
__global__ __launch_bounds__(256) void msda_kernel(const float* __restrict__ value,
                                                   const float* __restrict__ offaw,
                                                   const float* __restrict__ ref,
                                                   float* __restrict__ out)
{
    const int g    = threadIdx.x >> 5;           // 8 groups per block
    const int lane = threadIdx.x & 31;
    const int t    = blockIdx.x * 8 + g;         // grid exact: t < M1*H_
    const int h  = t & 7;
    const int bq = t >> 3;
    const int b  = bq / NQ_;
    const float* offp = offaw + (size_t)bq * OAW + h * (L_ * P_ * 2);
    const float* awp  = offaw + (size_t)bq * OAW + 256 + h * (L_ * P_);
    const float* refp = ref + (size_t)bq * (L_ * 2);
    const float* vb   = value + ((size_t)b * NV_) * D_ + h * HD_ + lane;

    float acc = 0.f;
    const int LW[4] = {128, 64, 32, 16};
    const int LS[4] = {0, 16384, 20480, 21504};

    #pragma unroll
    for (int l = 0; l < L_; l++) {
        const int wi = LW[l];
        const float Wf = (float)wi;              // square levels: W == H
        float rx = refp[2 * l], ry = refp[2 * l + 1];
        #pragma unroll
        for (int p = 0; p < P_; p++) {
            float ox = offp[(l * P_ + p) * 2];
            float oy = offp[(l * P_ + p) * 2 + 1];
            float a  = awp[l * P_ + p];
            // loc*W - 0.5 = (ref + off/W)*W - 0.5 = ref*W + off - 0.5
            float lx = rx * Wf + ox - 0.5f;
            float ly = ry * Wf + oy - 0.5f;
            float x0f = floorf(lx), y0f = floorf(ly);
            float fx = lx - x0f, fy = ly - y0f;
            int x0 = (int)x0f, y0 = (int)y0f;
            #pragma unroll
            for (int dy = 0; dy < 2; dy++) {
                int yi = y0 + dy;
                if (yi < 0 || yi >= wi) continue;
                float wy = dy ? fy : 1.f - fy;
                #pragma unroll
                for (int dx = 0; dx < 2; dx++) {
                    int xi = x0 + dx;
                    if (xi < 0 || xi >= wi) continue;
                    float w = wy * (dx ? fx : 1.f - fx) * a;
                    acc += w * vb[(size_t)(LS[l] + yi * wi + xi) * D_];
                }
            }
        }
    }
    out[(size_t)bq * D_ + h * HD_ + lane] = acc;
}

// ---------------------------------------------------------------- launch
extern "C" void kernel_launch(void* const* d_in, const int* in_sizes, int n_in,
                              void* d_out, int out_size, void* d_ws, size_t ws_size,
                              hipStream_t stream)
{
    const float* tgt      = (const float*)d_in[0];
    const float* qpos     = (const float*)d_in[1];
    const float* ref      = (const float*)d_in[2];
    const float* src      = (const float*)d_in[3];
    const float* sa_in_w  = (const float*)d_in[4];
    const float* sa_in_b  = (const float*)d_in[5];
    const float* sa_out_w = (const float*)d_in[6];
    const float* sa_out_b = (const float*)d_in[7];
    const float* ln2_g    = (const float*)d_in[8];
    const float* ln2_b    = (const float*)d_in[9];
    const float* off_w    = (const float*)d_in[10];
    const float* off_b    = (const float*)d_in[11];
    const float* aw_w     = (const float*)d_in[12];
    const float* aw_b     = (const float*)d_in[13];
    const float* val_w    = (const float*)d_in[14];
    const float* val_b    = (const float*)d_in[15];
    const float* out_w    = (const float*)d_in[16];
    const float* out_b    = (const float*)d_in[17];
    const float* ln1_g    = (const float*)d_in[18];
    const float* ln1_b    = (const float*)d_in[19];
    const float* ffn1_w   = (const float*)d_in[20];
    const float* ffn1_b   = (const float*)d_in[21];
    const float* ffn2_w   = (const float*)d_in[22];
    const float* ffn2_b   = (const float*)d_in[23];
    const float* ln3_g    = (const float*)d_in[24];
    const float* ln3_b    = (const float*)d_in[25];

    // ---- workspace layout, lifetime-checked aliases ----
    float* ws    = (float*)d_ws;
    float* value = ws;                               // [MV*256]
    float* qkv   = ws + (size_t)MV * D_;             // [M1*768]
    float* battn = qkv + (size_t)M1 * QKVW;          // [M1*256]
    float* b2    = battn + (size_t)M1 * D_;          // [M1*256]  tgt2
    float* b4    = b2 + (size_t)M1 * D_;             // [M1*256]  tgt3
    float* bsa   = qkv;                              // sa_out out   (qkv dead after attn)
    float* offaw = qkv + (size_t)M1 * D_;            // [M1*384]
    float* bmsda = qkv;                              // msda out
    float* bca   = battn;                            // ca out
    float* hid   = value;                            // ffn hidden   (value dead after msda)
    float* bffn  = qkv;                              // ffn2 out
    float* out   = (float*)d_out;

    // 1. fused qkv projection (q,k use tgt+qpos; v uses tgt)
    gemm_qkv<<<dim3(QKVW / 128, (M1 + 127) / 128), 256, 0, stream>>>(
        tgt, qpos, sa_in_w, sa_in_b, qkv);
    // 2. value = src @ val_w^T + val_b   (174080x256x256)
    gemm_big<false><<<dim3(D_ / 128, (MV + 127) / 128), 256, 0, stream>>>(
        src, val_w, val_b, value, MV, D_, D_);
    // 3. flash self-attention
    attn_kernel<<<dim3((NQ_ + 127) / 128, H_, BS_), 128, 0, stream>>>(qkv, battn);
    // 4. sa_out projection
    gemm_rt<false><<<dim3(D_ / 64, (M1 + 63) / 64), 256, 0, stream>>>(
        battn, sa_out_w, sa_out_b, nullptr, bsa, M1, D_, D_);
    // 5. tgt2 = LN(tgt + sa)
    ln_kernel<<<M1, 64, 0, stream>>>(tgt, bsa, ln2_g, ln2_b, b2);
    // 6. fused off+aw projection (A = tgt2 + qpos)
    gemm_offaw<<<dim3(OAW / 128, (M1 + 127) / 128), 256, 0, stream>>>(
        b2, qpos, off_w, off_b, aw_w, aw_b, offaw);
    // 7. softmax over aw logits
    aw_softmax_kernel<<<(M1 * H_ + 255) / 256, 256, 0, stream>>>(offaw);
    // 8. MSDA sampling (grid exact: 57600/8 = 7200 blocks)
    msda_kernel<<<M1 * H_ / 8, 256, 0, stream>>>(value, offaw, ref, bmsda);
    // 9. ca = msda @ out_w^T + out_b + tgt2
    gemm_rt<true><<<dim3(D_ / 64, (M1 + 63) / 64), 256, 0, stream>>>(
        bmsda, out_w, out_b, b2, bca, M1, D_, D_);
    // 10. tgt3 = LN(tgt2 + ca)
    ln_kernel<<<M1, 64, 0, stream>>>(b2, bca, ln1_g, ln1_b, b4);
    // 11. FFN
    gemm_big<true><<<dim3(DF_ / 128, (M1 + 127) / 128), 256, 0, stream>>>(
        b4, ffn1_w, ffn1_b, hid, M1, DF_, D_);
    gemm_big<false><<<dim3(D_ / 128, (M1 + 127) / 128), 256, 0, stream>>>(
        hid, ffn2_w, ffn2_b, bffn, M1, D_, DF_);
    // 12. out = LN(tgt3 + ffn)
    ln_kernel<<<M1, 64, 0, stream>>>(b4, bffn, ln3_g, ln3_b, out);
}

// Round 5
// 1030.680 us; speedup vs baseline: 1.7414x; 1.3130x over previous
//
#include <hip/hip_runtime.h>
#include <math.h>

#define D_   256
#define H_   8
#define HD_  32
#define L_   4
#define P_   4
#define DF_  1024
#define BS_  8
#define NQ_  900
#define NV_  21760
#define M1   (BS_*NQ_)   // 7200
#define MV   (BS_*NV_)   // 174080
#define QKVW 768         // fused qkv row width
#define OAW  384         // fused off+aw row width
#define KS_  8           // attention key splits
#define KCH  113         // keys per split (8*113 = 904 >= 900)

typedef __attribute__((ext_vector_type(8))) short short8v;
typedef __attribute__((ext_vector_type(4))) float float4v;
typedef unsigned short ushort_t;
typedef unsigned int uint_t;

// f32 -> bf16 (RNE), bf16 -> f32
__device__ __forceinline__ ushort_t f2bf(float f) {
    uint_t u = __float_as_uint(f);
    u += 0x7FFFu + ((u >> 16) & 1u);
    return (ushort_t)(u >> 16);
}
__device__ __forceinline__ float bf2f(ushort_t h) {
    return __uint_as_float(((uint_t)h) << 16);
}

// ---------------------------------------------------------------- small tiled fp32 GEMM: C = A[M,K] @ W[N,K]^T + bias (+res)
template<bool ADDRES>
__global__ __launch_bounds__(256) void gemm_rt(const float* __restrict__ A,
                                               const float* __restrict__ Wt,
                                               const float* __restrict__ bias,
                                               const float* __restrict__ res,
                                               float* __restrict__ C,
                                               int M, int N, int K)
{
    __shared__ float As[16][64];
    __shared__ float Ws[16][64];
    const int bm = blockIdx.y * 64, bn = blockIdx.x * 64;
    const int tid = threadIdx.x;
    const int tx = tid & 15, ty = tid >> 4;
    const int lr = tid >> 2, lk = (tid & 3) * 4;
    float acc[4][4] = {{0.f}};

    for (int k0 = 0; k0 < K; k0 += 16) {
        int gm = bm + lr;
        float4 a4 = make_float4(0.f, 0.f, 0.f, 0.f);
        if (gm < M) a4 = *(const float4*)&A[(size_t)gm * K + k0 + lk];
        As[lk + 0][lr] = a4.x; As[lk + 1][lr] = a4.y;
        As[lk + 2][lr] = a4.z; As[lk + 3][lr] = a4.w;
        int gn = bn + lr;
        float4 w4 = *(const float4*)&Wt[(size_t)gn * K + k0 + lk];
        Ws[lk + 0][lr] = w4.x; Ws[lk + 1][lr] = w4.y;
        Ws[lk + 2][lr] = w4.z; Ws[lk + 3][lr] = w4.w;
        __syncthreads();
        #pragma unroll
        for (int kk = 0; kk < 16; kk++) {
            float4 av = *(const float4*)&As[kk][ty * 4];
            float4 wv = *(const float4*)&Ws[kk][tx * 4];
            float aa[4] = {av.x, av.y, av.z, av.w};
            float ww[4] = {wv.x, wv.y, wv.z, wv.w};
            #pragma unroll
            for (int i = 0; i < 4; i++)
                #pragma unroll
                for (int j = 0; j < 4; j++)
                    acc[i][j] += aa[i] * ww[j];
        }
        __syncthreads();
    }
    #pragma unroll
    for (int i = 0; i < 4; i++) {
        int row = bm + ty * 4 + i;
        if (row >= M) continue;
        #pragma unroll
        for (int j = 0; j < 4; j++) {
            int col = bn + tx * 4 + j;
            float v = acc[i][j] + bias[col];
            if (ADDRES) v += res[(size_t)row * N + col];
            C[(size_t)row * N + col] = v;
        }
    }
}

// ---------------------------------------------------------------- big fp32 GEMM core: 128x128 tile, 8x8 micro-tile (FFN)
template<bool RELU>
__global__ __launch_bounds__(256) void gemm_big(const float* __restrict__ A,
                                                const float* __restrict__ Wt,
                                                const float* __restrict__ bias,
                                                float* __restrict__ C,
                                                int M, int N, int K)
{
    __shared__ float As[16][128];
    __shared__ float Ws[16][128];
    const int bm = blockIdx.y * 128, bn = blockIdx.x * 128;
    const int tid = threadIdx.x;
    const int tx = tid & 15, ty = tid >> 4;
    const int lr = tid >> 1, lk = (tid & 1) * 8;

    const int arow = min(bm + lr, M - 1);
    const float* aptr = A  + (size_t)arow * K + lk;
    const float* wptr = Wt + (size_t)(bn + lr) * K + lk;

    float acc[8][8] = {{0.f}};

    for (int k0 = 0; k0 < K; k0 += 16) {
        float4 a0 = *(const float4*)(aptr + k0);
        float4 a1 = *(const float4*)(aptr + k0 + 4);
        float4 w0 = *(const float4*)(wptr + k0);
        float4 w1 = *(const float4*)(wptr + k0 + 4);
        As[lk + 0][lr] = a0.x; As[lk + 1][lr] = a0.y; As[lk + 2][lr] = a0.z; As[lk + 3][lr] = a0.w;
        As[lk + 4][lr] = a1.x; As[lk + 5][lr] = a1.y; As[lk + 6][lr] = a1.z; As[lk + 7][lr] = a1.w;
        Ws[lk + 0][lr] = w0.x; Ws[lk + 1][lr] = w0.y; Ws[lk + 2][lr] = w0.z; Ws[lk + 3][lr] = w0.w;
        Ws[lk + 4][lr] = w1.x; Ws[lk + 5][lr] = w1.y; Ws[lk + 6][lr] = w1.z; Ws[lk + 7][lr] = w1.w;
        __syncthreads();
        #pragma unroll
        for (int kk = 0; kk < 16; kk++) {
            float4 alo = *(const float4*)&As[kk][ty * 4];
            float4 ahi = *(const float4*)&As[kk][ty * 4 + 64];
            float4 wlo = *(const float4*)&Ws[kk][tx * 4];
            float4 whi = *(const float4*)&Ws[kk][tx * 4 + 64];
            float av[8] = {alo.x, alo.y, alo.z, alo.w, ahi.x, ahi.y, ahi.z, ahi.w};
            float wv[8] = {wlo.x, wlo.y, wlo.z, wlo.w, whi.x, whi.y, whi.z, whi.w};
            #pragma unroll
            for (int i = 0; i < 8; i++)
                #pragma unroll
                for (int j = 0; j < 8; j++)
                    acc[i][j] += av[i] * wv[j];
        }
        __syncthreads();
    }

    float4 blo = *(const float4*)&bias[bn + tx * 4];
    float4 bhi = *(const float4*)&bias[bn + 64 + tx * 4];
    #pragma unroll
    for (int i = 0; i < 8; i++) {
        int row = bm + ((i < 4) ? (ty * 4 + i) : (64 + ty * 4 + i - 4));
        if (row >= M) continue;
        float4 v0 = make_float4(acc[i][0] + blo.x, acc[i][1] + blo.y,
                                acc[i][2] + blo.z, acc[i][3] + blo.w);
        float4 v1 = make_float4(acc[i][4] + bhi.x, acc[i][5] + bhi.y,
                                acc[i][6] + bhi.z, acc[i][7] + bhi.w);
        if (RELU) {
            v0.x = fmaxf(v0.x, 0.f); v0.y = fmaxf(v0.y, 0.f);
            v0.z = fmaxf(v0.z, 0.f); v0.w = fmaxf(v0.w, 0.f);
            v1.x = fmaxf(v1.x, 0.f); v1.y = fmaxf(v1.y, 0.f);
            v1.z = fmaxf(v1.z, 0.f); v1.w = fmaxf(v1.w, 0.f);
        }
        *(float4*)&C[(size_t)row * N + bn + tx * 4]      = v0;
        *(float4*)&C[(size_t)row * N + bn + 64 + tx * 4] = v1;
    }
}

// ---------------------------------------------------------------- value projection: bf16 MFMA GEMM
// C_bf16[MV][256] = src[MV][256] @ val_w[256][256]^T + val_b.  MV % 128 == 0.
// Block: 256 thr (4 waves), tile 128x64; wave = 64x32 = 4x2 frags of 16x16x32.
// LDS fragment-ordered: frag chunk for lane l at consecutive 16B -> conflict-free b128.
__global__ __launch_bounds__(256) void gemm_val_bf16(const float* __restrict__ A,
                                                     const float* __restrict__ Wt,
                                                     const float* __restrict__ bias,
                                                     ushort_t* __restrict__ C)
{
    __shared__ short Al[8 * 64 * 8];       //  8 KB: 8 mfrag x 64 lane x 8 bf16 (one 32-k chunk)
    __shared__ short Wl[8 * 4 * 64 * 8];   // 32 KB: 8 kchunk x 4 nfrag x 64 lane x 8 bf16

    const int tid = threadIdx.x;
    const int bm = blockIdx.y * 128, bn = blockIdx.x * 64;

    // ---- stage W (64 n-rows x 256 k), fragment-ordered, once ----
    {
        const int wrow = tid >> 2;            // 0..63
        const int kq   = (tid & 3) * 64;      // k quarter
        const float* wp = Wt + (size_t)(bn + wrow) * D_ + kq;
        #pragma unroll
        for (int grp = 0; grp < 8; grp++) {   // 8 bf16 per group
            float4 f0 = *(const float4*)(wp + grp * 8);
            float4 f1 = *(const float4*)(wp + grp * 8 + 4);
            short8v v;
            v[0] = (short)f2bf(f0.x); v[1] = (short)f2bf(f0.y);
            v[2] = (short)f2bf(f0.z); v[3] = (short)f2bf(f0.w);
            v[4] = (short)f2bf(f1.x); v[5] = (short)f2bf(f1.y);
            v[6] = (short)f2bf(f1.z); v[7] = (short)f2bf(f1.w);
            int kg = (tid & 3) * 8 + grp;     // global k-group 0..31
            int kc = kg >> 2, kin = kg & 3;
            int off = (((kc * 4 + (wrow >> 4)) * 64) + kin * 16 + (wrow & 15)) * 8;
            *(short8v*)&Wl[off] = v;
        }
    }

    // ---- A staging helpers (row = tid>>1, khalf = (tid&1)*16) ----
    const int arow = tid >> 1;
    const int khalf = (tid & 1) * 16;
    const float* ap = A + (size_t)(bm + arow) * D_ + khalf;

    float4 r0, r1, r2, r3;
    r0 = *(const float4*)(ap + 0);  r1 = *(const float4*)(ap + 4);
    r2 = *(const float4*)(ap + 8);  r3 = *(const float4*)(ap + 12);

    const int l = tid & 63, w = tid >> 6;
    const int mbase = (w & 1) * 4, nbase = (w >> 1) * 2;
    float4v acc[4][2];
    #pragma unroll
    for (int m = 0; m < 4; m++)
        #pragma unroll
        for (int n = 0; n < 2; n++)
            acc[m][n] = (float4v){0.f, 0.f, 0.f, 0.f};

    __syncthreads();                           // W visible

    for (int kc = 0; kc < 8; kc++) {
        // write A chunk kc (fragment-ordered)
        {
            short8v v0, v1;
            v0[0] = (short)f2bf(r0.x); v0[1] = (short)f2bf(r0.y);
            v0[2] = (short)f2bf(r0.z); v0[3] = (short)f2bf(r0.w);
            v0[4] = (short)f2bf(r1.x); v0[5] = (short)f2bf(r1.y);
            v0[6] = (short)f2bf(r1.z); v0[7] = (short)f2bf(r1.w);
            v1[0] = (short)f2bf(r2.x); v1[1] = (short)f2bf(r2.y);
            v1[2] = (short)f2bf(r2.z); v1[3] = (short)f2bf(r2.w);
            v1[4] = (short)f2bf(r3.x); v1[5] = (short)f2bf(r3.y);
            v1[6] = (short)f2bf(r3.z); v1[7] = (short)f2bf(r3.w);
            int kg = (tid & 1) * 2;
            int off0 = (((arow >> 4) * 64) + kg * 16 + (arow & 15)) * 8;
            int off1 = (((arow >> 4) * 64) + (kg + 1) * 16 + (arow & 15)) * 8;
            *(short8v*)&Al[off0] = v0;
            *(short8v*)&Al[off1] = v1;
        }
        // prefetch next chunk (T14 split: issue early, consume after barrier)
        if (kc < 7) {
            const float* np = ap + (kc + 1) * 32;
            r0 = *(const float4*)(np + 0);  r1 = *(const float4*)(np + 4);
            r2 = *(const float4*)(np + 8);  r3 = *(const float4*)(np + 12);
        }
        __syncthreads();                        // A chunk visible

        short8v af0 = *(const short8v*)&Al[((mbase + 0) * 64 + l) * 8];
        short8v af1 = *(const short8v*)&Al[((mbase + 1) * 64 + l) * 8];
        short8v af2 = *(const short8v*)&Al[((mbase + 2) * 64 + l) * 8];
        short8v af3 = *(const short8v*)&Al[((mbase + 3) * 64 + l) * 8];
        short8v bf0 = *(const short8v*)&Wl[((kc * 4 + nbase + 0) * 64 + l) * 8];
        short8v bf1 = *(const short8v*)&Wl[((kc * 4 + nbase + 1) * 64 + l) * 8];

        acc[0][0] = __builtin_amdgcn_mfma_f32_16x16x32_bf16(af0, bf0, acc[0][0], 0, 0, 0);
        acc[0][1] = __builtin_amdgcn_mfma_f32_16x16x32_bf16(af0, bf1, acc[0][1], 0, 0, 0);
        acc[1][0] = __builtin_amdgcn_mfma_f32_16x16x32_bf16(af1, bf0, acc[1][0], 0, 0, 0);
        acc[1][1] = __builtin_amdgcn_mfma_f32_16x16x32_bf16(af1, bf1, acc[1][1], 0, 0, 0);
        acc[2][0] = __builtin_amdgcn_mfma_f32_16x16x32_bf16(af2, bf0, acc[2][0], 0, 0, 0);
        acc[2][1] = __builtin_amdgcn_mfma_f32_16x16x32_bf16(af2, bf1, acc[2][1], 0, 0, 0);
        acc[3][0] = __builtin_amdgcn_mfma_f32_16x16x32_bf16(af3, bf0, acc[3][0], 0, 0, 0);
        acc[3][1] = __builtin_amdgcn_mfma_f32_16x16x32_bf16(af3, bf1, acc[3][1], 0, 0, 0);

        __syncthreads();                        // compute done; safe to overwrite A
    }

    // ---- epilogue: C row = (l>>4)*4 + reg (within frag), col = l&15 ----
    #pragma unroll
    for (int n = 0; n < 2; n++) {
        int gc = bn + nbase * 16 + n * 16 + (l & 15);
        float bc = bias[gc];
        #pragma unroll
        for (int m = 0; m < 4; m++) {
            int gr = bm + mbase * 16 + m * 16 + (l >> 4) * 4;
            #pragma unroll
            for (int r = 0; r < 4; r++)
                C[(size_t)(gr + r) * D_ + gc] = f2bf(acc[m][n][r] + bc);
        }
    }
}

// ---------------------------------------------------------------- fused QKV projection
__global__ __launch_bounds__(256) void gemm_qkv(const float* __restrict__ tgt,
                                                const float* __restrict__ qpos,
                                                const float* __restrict__ W,
                                                const float* __restrict__ bias,
                                                float* __restrict__ C)
{
    __shared__ float As[16][128];
    __shared__ float Ws[16][128];
    const int bm = blockIdx.y * 128, bn = blockIdx.x * 128;
    const bool useQK = (blockIdx.x < 4);
    const int tid = threadIdx.x;
    const int tx = tid & 15, ty = tid >> 4;
    const int lr = tid >> 1, lk = (tid & 1) * 8;

    const int arow = min(bm + lr, M1 - 1);
    const float* aptr = tgt  + (size_t)arow * D_ + lk;
    const float* pptr = qpos + (size_t)arow * D_ + lk;
    const float* wptr = W + (size_t)(bn + lr) * D_ + lk;

    float acc[8][8] = {{0.f}};

    for (int k0 = 0; k0 < D_; k0 += 16) {
        float4 a0 = *(const float4*)(aptr + k0);
        float4 a1 = *(const float4*)(aptr + k0 + 4);
        if (useQK) {
            float4 p0 = *(const float4*)(pptr + k0);
            float4 p1 = *(const float4*)(pptr + k0 + 4);
            a0.x += p0.x; a0.y += p0.y; a0.z += p0.z; a0.w += p0.w;
            a1.x += p1.x; a1.y += p1.y; a1.z += p1.z; a1.w += p1.w;
        }
        float4 w0 = *(const float4*)(wptr + k0);
        float4 w1 = *(const float4*)(wptr + k0 + 4);
        As[lk + 0][lr] = a0.x; As[lk + 1][lr] = a0.y; As[lk + 2][lr] = a0.z; As[lk + 3][lr] = a0.w;
        As[lk + 4][lr] = a1.x; As[lk + 5][lr] = a1.y; As[lk + 6][lr] = a1.z; As[lk + 7][lr] = a1.w;
        Ws[lk + 0][lr] = w0.x; Ws[lk + 1][lr] = w0.y; Ws[lk + 2][lr] = w0.z; Ws[lk + 3][lr] = w0.w;
        Ws[lk + 4][lr] = w1.x; Ws[lk + 5][lr] = w1.y; Ws[lk + 6][lr] = w1.z; Ws[lk + 7][lr] = w1.w;
        __syncthreads();
        #pragma unroll
        for (int kk = 0; kk < 16; kk++) {
            float4 alo = *(const float4*)&As[kk][ty * 4];
            float4 ahi = *(const float4*)&As[kk][ty * 4 + 64];
            float4 wlo = *(const float4*)&Ws[kk][tx * 4];
            float4 whi = *(const float4*)&Ws[kk][tx * 4 + 64];
            float av[8] = {alo.x, alo.y, alo.z, alo.w, ahi.x, ahi.y, ahi.z, ahi.w};
            float wv[8] = {wlo.x, wlo.y, wlo.z, wlo.w, whi.x, whi.y, whi.z, whi.w};
            #pragma unroll
            for (int i = 0; i < 8; i++)
                #pragma unroll
                for (int j = 0; j < 8; j++)
                    acc[i][j] += av[i] * wv[j];
        }
        __syncthreads();
    }

    float4 blo = *(const float4*)&bias[bn + tx * 4];
    float4 bhi = *(const float4*)&bias[bn + 64 + tx * 4];
    #pragma unroll
    for (int i = 0; i < 8; i++) {
        int row = bm + ((i < 4) ? (ty * 4 + i) : (64 + ty * 4 + i - 4));
        if (row >= M1) continue;
        float4 v0 = make_float4(acc[i][0] + blo.x, acc[i][1] + blo.y,
                                acc[i][2] + blo.z, acc[i][3] + blo.w);
        float4 v1 = make_float4(acc[i][4] + bhi.x, acc[i][5] + bhi.y,
                                acc[i][6] + bhi.z, acc[i][7] + bhi.w);
        *(float4*)&C[(size_t)row * QKVW + bn + tx * 4]      = v0;
        *(float4*)&C[(size_t)row * QKVW + bn + 64 + tx * 4] = v1;
    }
}

// ---------------------------------------------------------------- fused off+aw projection
__global__ __launch_bounds__(256) void gemm_offaw(const float* __restrict__ t2,
                                                  const float* __restrict__ qpos,
                                                  const float* __restrict__ off_w,
                                                  const float* __restrict__ off_b,
                                                  const float* __restrict__ aw_w,
                                                  const float* __restrict__ aw_b,
                                                  float* __restrict__ C)
{
    __shared__ float As[16][128];
    __shared__ float Ws[16][128];
    const int bm = blockIdx.y * 128, bn = blockIdx.x * 128;
    const float* Wbase = (bn < 256) ? off_w + (size_t)bn * D_ : aw_w + (size_t)(bn - 256) * D_;
    const float* Bbase = (bn < 256) ? off_b + bn              : aw_b + (bn - 256);
    const int tid = threadIdx.x;
    const int tx = tid & 15, ty = tid >> 4;
    const int lr = tid >> 1, lk = (tid & 1) * 8;

    const int arow = min(bm + lr, M1 - 1);
    const float* aptr = t2   + (size_t)arow * D_ + lk;
    const float* pptr = qpos + (size_t)arow * D_ + lk;
    const float* wptr = Wbase + (size_t)lr * D_ + lk;

    float acc[8][8] = {{0.f}};

    for (int k0 = 0; k0 < D_; k0 += 16) {
        float4 a0 = *(const float4*)(aptr + k0);
        float4 a1 = *(const float4*)(aptr + k0 + 4);
        float4 p0 = *(const float4*)(pptr + k0);
        float4 p1 = *(const float4*)(pptr + k0 + 4);
        a0.x += p0.x; a0.y += p0.y; a0.z += p0.z; a0.w += p0.w;
        a1.x += p1.x; a1.y += p1.y; a1.z += p1.z; a1.w += p1.w;
        float4 w0 = *(const float4*)(wptr + k0);
        float4 w1 = *(const float4*)(wptr + k0 + 4);
        As[lk + 0][lr] = a0.x; As[lk + 1][lr] = a0.y; As[lk + 2][lr] = a0.z; As[lk + 3][lr] = a0.w;
        As[lk + 4][lr] = a1.x; As[lk + 5][lr] = a1.y; As[lk + 6][lr] = a1.z; As[lk + 7][lr] = a1.w;
        Ws[lk + 0][lr] = w0.x; Ws[lk + 1][lr] = w0.y; Ws[lk + 2][lr] = w0.z; Ws[lk + 3][lr] = w0.w;
        Ws[lk + 4][lr] = w1.x; Ws[lk + 5][lr] = w1.y; Ws[lk + 6][lr] = w1.z; Ws[lk + 7][lr] = w1.w;
        __syncthreads();
        #pragma unroll
        for (int kk = 0; kk < 16; kk++) {
            float4 alo = *(const float4*)&As[kk][ty * 4];
            float4 ahi = *(const float4*)&As[kk][ty * 4 + 64];
            float4 wlo = *(const float4*)&Ws[kk][tx * 4];
            float4 whi = *(const float4*)&Ws[kk][tx * 4 + 64];
            float av[8] = {alo.x, alo.y, alo.z, alo.w, ahi.x, ahi.y, ahi.z, ahi.w};
            float wv[8] = {wlo.x, wlo.y, wlo.z, wlo.w, whi.x, whi.y, whi.z, whi.w};
            #pragma unroll
            for (int i = 0; i < 8; i++)
                #pragma unroll
                for (int j = 0; j < 8; j++)
                    acc[i][j] += av[i] * wv[j];
        }
        __syncthreads();
    }

    float4 blo = make_float4(Bbase[tx*4], Bbase[tx*4+1], Bbase[tx*4+2], Bbase[tx*4+3]);
    float4 bhi = make_float4(Bbase[64+tx*4], Bbase[64+tx*4+1], Bbase[64+tx*4+2], Bbase[64+tx*4+3]);
    #pragma unroll
    for (int i = 0; i < 8; i++) {
        int row = bm + ((i < 4) ? (ty * 4 + i) : (64 + ty * 4 + i - 4));
        if (row >= M1) continue;
        float4 v0 = make_float4(acc[i][0] + blo.x, acc[i][1] + blo.y,
                                acc[i][2] + blo.z, acc[i][3] + blo.w);
        float4 v1 = make_float4(acc[i][4] + bhi.x, acc[i][5] + bhi.y,
                                acc[i][6] + bhi.z, acc[i][7] + bhi.w);
        *(float4*)&C[(size_t)row * OAW + bn + tx * 4]      = v0;
        *(float4*)&C[(size_t)row * OAW + bn + 64 + tx * 4] = v1;
    }
}

// ---------------------------------------------------------------- flash self-attention, split-K over keys (KS_ splits)
// Block: 128 thr (2 waves), 128 queries of one (b,h), keys [ks*KCH, min(900, ks*KCH+KCH)).
// Writes unnormalized partials (m, l, acc[32]) per (b,h,ks,q).
#define ATK 64
__global__ __launch_bounds__(128) void attn_kernel(const float* __restrict__ QKV,
                                                   float* __restrict__ pml,
                                                   float* __restrict__ pacc)
{
    const int b = blockIdx.z, h = blockIdx.y;
    const int qb = blockIdx.x & 7, ks = blockIdx.x >> 3;
    const int q0 = qb * 128;
    const int kstart = ks * KCH;
    const int kend   = min(NQ_, kstart + KCH);
    const int tid  = threadIdx.x;
    const int wave = tid >> 6, lane = tid & 63;
    const int qi = lane & 31, half = lane >> 5;

    __shared__ float Ksm[ATK][HD_];
    __shared__ float Vsm[ATK][HD_];

    const int q_a = q0 + wave * 64 + qi * 2;
    const int q_b = q_a + 1;
    const int qa_c = min(q_a, NQ_ - 1);
    const int qb_c = min(q_b, NQ_ - 1);

    const float scale = 0.17677669529663687f;    // 1/sqrt(32)
    float Qa[16], Qb[16];
    {
        const float* pa = QKV + ((size_t)(b * NQ_ + qa_c)) * QKVW + h * HD_ + half * 16;
        const float* pb = QKV + ((size_t)(b * NQ_ + qb_c)) * QKVW + h * HD_ + half * 16;
        #pragma unroll
        for (int i = 0; i < 16; i += 4) {
            float4 va = *(const float4*)&pa[i];
            float4 vb = *(const float4*)&pb[i];
            Qa[i] = va.x * scale; Qa[i+1] = va.y * scale; Qa[i+2] = va.z * scale; Qa[i+3] = va.w * scale;
            Qb[i] = vb.x * scale; Qb[i+1] = vb.y * scale; Qb[i+2] = vb.z * scale; Qb[i+3] = vb.w * scale;
        }
    }

    float ma = -INFINITY, la = 0.f, mb = -INFINITY, lb = 0.f;
    float aa[16], ab[16];
    #pragma unroll
    for (int i = 0; i < 16; i++) { aa[i] = 0.f; ab[i] = 0.f; }

    for (int j0 = kstart; j0 < kend; j0 += ATK) {
        const int jn = min(ATK, kend - j0);
        __syncthreads();
        for (int f = tid; f < ATK * HD_ / 4; f += 128) {
            int j = f >> 3, d4 = (f & 7) << 2;
            if (j < jn) {
                const float* kp = QKV + ((size_t)(b * NQ_ + j0 + j)) * QKVW + 256 + h * HD_ + d4;
                *(float4*)&Ksm[j][d4] = *(const float4*)kp;
                *(float4*)&Vsm[j][d4] = *(const float4*)(kp + 256);
            }
        }
        __syncthreads();

        for (int j = 0; j < jn; j++) {
            float kr[16];
            #pragma unroll
            for (int i = 0; i < 16; i += 4) {
                float4 kv = *(const float4*)&Ksm[j][half * 16 + i];
                kr[i] = kv.x; kr[i+1] = kv.y; kr[i+2] = kv.z; kr[i+3] = kv.w;
            }
            float sa0 = 0.f, sa1 = 0.f, sa2 = 0.f, sa3 = 0.f;
            float sb0 = 0.f, sb1 = 0.f, sb2 = 0.f, sb3 = 0.f;
            #pragma unroll
            for (int i = 0; i < 16; i += 4) {
                sa0 += Qa[i] * kr[i];     sa1 += Qa[i+1] * kr[i+1];
                sa2 += Qa[i+2] * kr[i+2]; sa3 += Qa[i+3] * kr[i+3];
                sb0 += Qb[i] * kr[i];     sb1 += Qb[i+1] * kr[i+1];
                sb2 += Qb[i+2] * kr[i+2]; sb3 += Qb[i+3] * kr[i+3];
            }
            float sA = (sa0 + sa1) + (sa2 + sa3);
            float sB = (sb0 + sb1) + (sb2 + sb3);
            sA += __shfl_xor(sA, 32);
            sB += __shfl_xor(sB, 32);

            float vr[16];
            #pragma unroll
            for (int i = 0; i < 16; i += 4) {
                float4 vv = *(const float4*)&Vsm[j][half * 16 + i];
                vr[i] = vv.x; vr[i+1] = vv.y; vr[i+2] = vv.z; vr[i+3] = vv.w;
            }

            if (sA > ma) {
                float sc = __expf(ma - sA);
                la *= sc;
                #pragma unroll
                for (int i = 0; i < 16; i++) aa[i] *= sc;
                ma = sA;
            }
            float pA = __expf(sA - ma);
            la += pA;
            #pragma unroll
            for (int i = 0; i < 16; i++) aa[i] += pA * vr[i];

            if (sB > mb) {
                float sc = __expf(mb - sB);
                lb *= sc;
                #pragma unroll
                for (int i = 0; i < 16; i++) ab[i] *= sc;
                mb = sB;
            }
            float pB = __expf(sB - mb);
            lb += pB;
            #pragma unroll
            for (int i = 0; i < 16; i++) ab[i] += pB * vr[i];
        }
    }

    const int bh = b * H_ + h;
    if (q_a < NQ_) {
        size_t base = (((size_t)bh * KS_ + ks) * NQ_ + q_a) * 32 + half * 16;
        #pragma unroll
        for (int i = 0; i < 16; i += 4) {
            float4 v = make_float4(aa[i], aa[i+1], aa[i+2], aa[i+3]);
            *(float4*)&pacc[base + i] = v;
        }
        if (half == 0) {
            size_t mb_ = (((size_t)bh * KS_ + ks) * NQ_ + q_a) * 2;
            pml[mb_] = ma; pml[mb_ + 1] = la;
        }
    }
    if (q_b < NQ_) {
        size_t base = (((size_t)bh * KS_ + ks) * NQ_ + q_b) * 32 + half * 16;
        #pragma unroll
        for (int i = 0; i < 16; i += 4) {
            float4 v = make_float4(ab[i], ab[i+1], ab[i+2], ab[i+3]);
            *(float4*)&pacc[base + i] = v;
        }
        if (half == 0) {
            size_t mb_ = (((size_t)bh * KS_ + ks) * NQ_ + q_b) * 2;
            pml[mb_] = mb; pml[mb_ + 1] = lb;
        }
    }
}

// ---------------------------------------------------------------- split-K combine: merge KS_ partials per (b,h,q)
// 32 lanes per (b,h,q): lane = channel. Grid exact: 57600/8 blocks.
__global__ __launch_bounds__(256) void attn_combine(const float* __restrict__ pml,
                                                    const float* __restrict__ pacc,
                                                    float* __restrict__ SA)
{
    const int g  = threadIdx.x >> 5;
    const int ch = threadIdx.x & 31;
    const int t  = blockIdx.x * 8 + g;       // (b*H + h)*NQ + q
    const int bh = t / NQ_, q = t - bh * NQ_;

    float mv[KS_], lv[KS_];
    float M = -INFINITY;
    #pragma unroll
    for (int i = 0; i < KS_; i++) {
        size_t mb = (((size_t)bh * KS_ + i) * NQ_ + q) * 2;
        mv[i] = pml[mb]; lv[i] = pml[mb + 1];
        M = fmaxf(M, mv[i]);
    }
    float L = 0.f, acc = 0.f;
    #pragma unroll
    for (int i = 0; i < KS_; i++) {
        float wgt = __expf(mv[i] - M);
        L += lv[i] * wgt;
        acc += wgt * pacc[(((size_t)bh * KS_ + i) * NQ_ + q) * 32 + ch];
    }
    const int b = bh >> 3, h = bh & 7;
    SA[((size_t)(b * NQ_ + q)) * D_ + h * HD_ + ch] = acc / L;
}

// ---------------------------------------------------------------- LayerNorm(x + y) * g + b, one wave per 256-wide row
__global__ __launch_bounds__(64) void ln_kernel(const float* __restrict__ X,
                                                const float* __restrict__ Y,
                                                const float* __restrict__ g,
                                                const float* __restrict__ bt,
                                                float* __restrict__ out)
{
    const int row = blockIdx.x;
    const int lane = threadIdx.x;
    const size_t base = (size_t)row * D_ + lane * 4;
    float4 x = *(const float4*)&X[base];
    float4 y = *(const float4*)&Y[base];
    float v0 = x.x + y.x, v1 = x.y + y.y, v2 = x.z + y.z, v3 = x.w + y.w;
    float s = v0 + v1 + v2 + v3;
    #pragma unroll
    for (int o = 32; o; o >>= 1) s += __shfl_xor(s, o);
    float mean = s * (1.f / D_);
    float d0 = v0 - mean, d1 = v1 - mean, d2 = v2 - mean, d3 = v3 - mean;
    float ss = d0 * d0 + d1 * d1 + d2 * d2 + d3 * d3;
    #pragma unroll
    for (int o = 32; o; o >>= 1) ss += __shfl_xor(ss, o);
    float rstd = rsqrtf(ss * (1.f / D_) + 1e-5f);
    float4 gg = *(const float4*)&g[lane * 4];
    float4 bb = *(const float4*)&bt[lane * 4];
    float4 o4 = make_float4(d0 * rstd * gg.x + bb.x, d1 * rstd * gg.y + bb.y,
                            d2 * rstd * gg.z + bb.z, d3 * rstd * gg.w + bb.w);
    *(float4*)&out[base] = o4;
}

// ---------------------------------------------------------------- softmax over L*P=16 aw logits per (b,q,h), in place
__global__ __launch_bounds__(256) void aw_softmax_kernel(float* __restrict__ offaw)
{
    int t = blockIdx.x * 256 + threadIdx.x;
    if (t >= M1 * H_) return;
    const int bq = t >> 3, h = t & 7;
    float* p = offaw + (size_t)bq * OAW + 256 + h * 16;
    float v[16];
    #pragma unroll
    for (int i = 0; i < 16; i += 4) {
        float4 q = *(const float4*)&p[i];
        v[i] = q.x; v[i+1] = q.y; v[i+2] = q.z; v[i+3] = q.w;
    }
    float m = v[0];
    #pragma unroll
    for (int i = 1; i < 16; i++) m = fmaxf(m, v[i]);
    float s = 0.f;
    #pragma unroll
    for (int i = 0; i < 16; i++) { v[i] = __expf(v[i] - m); s += v[i]; }
    float inv = 1.f / s;
    #pragma unroll
    for (int i = 0; i < 16; i += 4) {
        float4 q = make_float4(v[i] * inv, v[i+1] * inv, v[i+2] * inv, v[i+3] * inv);
        *(float4*)&p[i] = q;
    }
}

// ---------------------------------------------------------------- MSDA bilinear sampling (value in bf16)
__global__ __launch_bounds__(256) void msda_kernel(const ushort_t* __restrict__ value,
                                                   const float* __restrict__ offaw,
                                                   const float* __restrict__ ref,
                                                   float* __restrict__ out)
{
    const int g    = threadIdx.x >> 5;
    const int lane = threadIdx.x & 31;
    const int t    = blockIdx.x * 8 + g;
    const int h  = t & 7;
    const int bq = t >> 3;
    const int b  = bq / NQ_;
    const float* offp = offaw + (size_t)bq * OAW + h * (L_ * P_ * 2);
    const float* awp  = offaw + (size_t)bq * OAW + 256 + h * (L_ * P_);
    const float* refp = ref + (size_t)bq * (L_ * 2);
    const ushort_t* vb = value + ((size_t)b * NV_) * D_ + h * HD_ + lane;

    float acc = 0.f;
    const int LW[4] = {128, 64, 32, 16};
    const int LS[4] = {0, 16384, 20480, 21504};

    #pragma unroll
    for (int l = 0; l < L_; l++) {
        const int wi = LW[l];
        const float Wf = (float)wi;
        float rx = refp[2 * l], ry = refp[2 * l + 1];
        #pragma unroll
        for (int p = 0; p < P_; p++) {
            float ox = offp[(l * P_ + p) * 2];
            float oy = offp[(l * P_ + p) * 2 + 1];
            float a  = awp[l * P_ + p];
            float lx = rx * Wf + ox - 0.5f;
            float ly = ry * Wf + oy - 0.5f;
            float x0f = floorf(lx), y0f = floorf(ly);
            float fx = lx - x0f, fy = ly - y0f;
            int x0 = (int)x0f, y0 = (int)y0f;
            #pragma unroll
            for (int dy = 0; dy < 2; dy++) {
                int yi = y0 + dy;
                if (yi < 0 || yi >= wi) continue;
                float wy = dy ? fy : 1.f - fy;
                #pragma unroll
                for (int dx = 0; dx < 2; dx++) {
                    int xi = x0 + dx;
                    if (xi < 0 || xi >= wi) continue;
                    float w = wy * (dx ? fx : 1.f - fx) * a;
                    acc += w * bf2f(vb[(size_t)(LS[l] + yi * wi + xi) * D_]);
                }
            }
        }
    }
    out[(size_t)bq * D_ + h * HD_ + lane] = acc;
}

// ---------------------------------------------------------------- launch
extern "C" void kernel_launch(void* const* d_in, const int* in_sizes, int n_in,
                              void* d_out, int out_size, void* d_ws, size_t ws_size,
                              hipStream_t stream)
{
    const float* tgt      = (const float*)d_in[0];
    const float* qpos     = (const float*)d_in[1];
    const float* ref      = (const float*)d_in[2];
    const float* src      = (const float*)d_in[3];
    const float* sa_in_w  = (const float*)d_in[4];
    const float* sa_in_b  = (const float*)d_in[5];
    const float* sa_out_w = (const float*)d_in[6];
    const float* sa_out_b = (const float*)d_in[7];
    const float* ln2_g    = (const float*)d_in[8];
    const float* ln2_b    = (const float*)d_in[9];
    const float* off_w    = (const float*)d_in[10];
    const float* off_b    = (const float*)d_in[11];
    const float* aw_w     = (const float*)d_in[12];
    const float* aw_b     = (const float*)d_in[13];
    const float* val_w    = (const float*)d_in[14];
    const float* val_b    = (const float*)d_in[15];
    const float* out_w    = (const float*)d_in[16];
    const float* out_b    = (const float*)d_in[17];
    const float* ln1_g    = (const float*)d_in[18];
    const float* ln1_b    = (const float*)d_in[19];
    const float* ffn1_w   = (const float*)d_in[20];
    const float* ffn1_b   = (const float*)d_in[21];
    const float* ffn2_w   = (const float*)d_in[22];
    const float* ffn2_b   = (const float*)d_in[23];
    const float* ln3_g    = (const float*)d_in[24];
    const float* ln3_b    = (const float*)d_in[25];

    // ---- workspace layout (196 MB), lifetime-checked aliases ----
    float* ws      = (float*)d_ws;
    ushort_t* value = (ushort_t*)ws;                 // [MV*256] bf16 = 22,282,240 f32-slots
    float* qkv   = ws + 22282240;                    // [M1*768]
    float* battn = qkv + (size_t)M1 * QKVW;          // [M1*256]
    float* b2    = battn + (size_t)M1 * D_;          // [M1*256]  tgt2
    float* b4    = b2 + (size_t)M1 * D_;             // [M1*256]  tgt3
    float* pml   = b4 + (size_t)M1 * D_;             // [57600*8*2]
    float* pacc  = pml + (size_t)M1 * H_ * KS_ * 2;  // [57600*8*32]
    float* bsa   = qkv;                              // sa_out out   (qkv dead after attn+combine)
    float* offaw = qkv + (size_t)M1 * D_;            // [M1*384]
    float* bmsda = qkv;                              // msda out
    float* bca   = battn;                            // ca out
    float* hid   = pml;                              // ffn hidden (partials dead after combine)
    float* bffn  = qkv;                              // ffn2 out
    float* out   = (float*)d_out;

    // 1. fused qkv projection (q,k use tgt+qpos; v uses tgt)
    gemm_qkv<<<dim3(QKVW / 128, (M1 + 127) / 128), 256, 0, stream>>>(
        tgt, qpos, sa_in_w, sa_in_b, qkv);
    // 2. value = src @ val_w^T + val_b   (bf16 MFMA; MV % 128 == 0)
    gemm_val_bf16<<<dim3(D_ / 64, MV / 128), 256, 0, stream>>>(
        src, val_w, val_b, value);
    // 3. flash split-K self-attention + combine
    attn_kernel<<<dim3(8 * KS_, H_, BS_), 128, 0, stream>>>(qkv, pml, pacc);
    attn_combine<<<M1 * H_ / 8, 256, 0, stream>>>(pml, pacc, battn);
    // 4. sa_out projection
    gemm_rt<false><<<dim3(D_ / 64, (M1 + 63) / 64), 256, 0, stream>>>(
        battn, sa_out_w, sa_out_b, nullptr, bsa, M1, D_, D_);
    // 5. tgt2 = LN(tgt + sa)
    ln_kernel<<<M1, 64, 0, stream>>>(tgt, bsa, ln2_g, ln2_b, b2);
    // 6. fused off+aw projection (A = tgt2 + qpos)
    gemm_offaw<<<dim3(OAW / 128, (M1 + 127) / 128), 256, 0, stream>>>(
        b2, qpos, off_w, off_b, aw_w, aw_b, offaw);
    // 7. softmax over aw logits
    aw_softmax_kernel<<<(M1 * H_ + 255) / 256, 256, 0, stream>>>(offaw);
    // 8. MSDA sampling (bf16 value)
    msda_kernel<<<M1 * H_ / 8, 256, 0, stream>>>(value, offaw, ref, bmsda);
    // 9. ca = msda @ out_w^T + out_b + tgt2
    gemm_rt<true><<<dim3(D_ / 64, (M1 + 63) / 64), 256, 0, stream>>>(
        bmsda, out_w, out_b, b2, bca, M1, D_, D_);
    // 10. tgt3 = LN(tgt2 + ca)
    ln_kernel<<<M1, 64, 0, stream>>>(b2, bca, ln1_g, ln1_b, b4);
    // 11. FFN
    gemm_big<true><<<dim3(DF_ / 128, (M1 + 127) / 128), 256, 0, stream>>>(
        b4, ffn1_w, ffn1_b, hid, M1, DF_, D_);
    gemm_big<false><<<dim3(D_ / 128, (M1 + 127) / 128), 256, 0, stream>>>(
        hid, ffn2_w, ffn2_b, bffn, M1, D_, DF_);
    // 12. out = LN(tgt3 + ffn)
    ln_kernel<<<M1, 64, 0, stream>>>(b4, bffn, ln3_g, ln3_b, out);
}

// Round 6
// 868.897 us; speedup vs baseline: 2.0657x; 1.1862x over previous
//
#include <hip/hip_runtime.h>
#include <math.h>

#define D_   256
#define H_   8
#define HD_  32
#define L_   4
#define P_   4
#define DF_  1024
#define BS_  8
#define NQ_  900
#define NV_  21760
#define M1   (BS_*NQ_)   // 7200
#define MV   (BS_*NV_)   // 174080
#define QKVW 768         // fused qkv row width
#define OAW  384         // fused off+aw row width
#define KS_  8           // attention key splits
#define KCH  113         // keys per split (8*113 = 904 >= 900)

typedef __attribute__((ext_vector_type(8))) short short8v;
typedef __attribute__((ext_vector_type(4))) float float4v;
typedef unsigned short ushort_t;
typedef unsigned int uint_t;

// f32 -> bf16 (RNE), bf16 -> f32
__device__ __forceinline__ ushort_t f2bf(float f) {
    uint_t u = __float_as_uint(f);
    u += 0x7FFFu + ((u >> 16) & 1u);
    return (ushort_t)(u >> 16);
}
__device__ __forceinline__ float bf2f(ushort_t h) {
    return __uint_as_float(((uint_t)h) << 16);
}

// ================================================================ generic bf16-MFMA GEMM (fp32 in/out)
// C[M][ldc] slice at coffs: C[r][coffs+c] = (A(+A2))[M][K] @ W[N][K]^T + bias (+res)(relu)
// K % 256 == 0 (W staged in 256-k super-chunks), N % 64 == 0.
// Block 256 thr (4 waves), tile 128x64; wave = 64x32 = 4x2 frags of 16x16x32 bf16 MFMA.
// LDS fragment-ordered (conflict-free ds_read_b128); layout proven in gemm_val_bf16 (R4/R5).
template<bool ADD2, bool RELU, bool ADDRES>
__global__ __launch_bounds__(256) void gemm_mfma(const float* __restrict__ A,
                                                 const float* __restrict__ A2,
                                                 const float* __restrict__ Wt,
                                                 const float* __restrict__ bias,
                                                 const float* __restrict__ res,
                                                 float* __restrict__ C,
                                                 int M, int K, int ldc, int coffs)
{
    __shared__ short Al[8 * 64 * 8];       //  8 KB: one 32-k chunk, 8 mfrags
    __shared__ short Wl[8 * 4 * 64 * 8];   // 32 KB: one 256-k super-chunk, 8 kchunks x 4 nfrags

    const int tid = threadIdx.x;
    const int bm = blockIdx.y * 128, bn = blockIdx.x * 64;

    const int l = tid & 63, w = tid >> 6;
    const int mbase = (w & 1) * 4, nbase = (w >> 1) * 2;
    float4v acc[4][2];
    #pragma unroll
    for (int m = 0; m < 4; m++)
        #pragma unroll
        for (int n = 0; n < 2; n++)
            acc[m][n] = (float4v){0.f, 0.f, 0.f, 0.f};

    const int arow  = tid >> 1;
    const int arow_c = min(bm + arow, M - 1);            // clamp; stores guarded
    const int khalf = (tid & 1) * 16;
    const float* ap  = A + (size_t)arow_c * K + khalf;
    const float* ap2 = ADD2 ? (A2 + (size_t)arow_c * K + khalf) : nullptr;

    const int wrow = tid >> 2;            // 0..63
    const int kq   = (tid & 3) * 64;      // k-quarter within super-chunk

    for (int ks = 0; ks < K; ks += 256) {
        __syncthreads();                   // prior super-chunk fully consumed (Wl free)
        // ---- stage W super-chunk, fragment-ordered ----
        {
            const float* wp = Wt + (size_t)(bn + wrow) * K + ks + kq;
            #pragma unroll
            for (int grp = 0; grp < 8; grp++) {
                float4 f0 = *(const float4*)(wp + grp * 8);
                float4 f1 = *(const float4*)(wp + grp * 8 + 4);
                short8v v;
                v[0] = (short)f2bf(f0.x); v[1] = (short)f2bf(f0.y);
                v[2] = (short)f2bf(f0.z); v[3] = (short)f2bf(f0.w);
                v[4] = (short)f2bf(f1.x); v[5] = (short)f2bf(f1.y);
                v[6] = (short)f2bf(f1.z); v[7] = (short)f2bf(f1.w);
                int kg = (tid & 3) * 8 + grp;     // k-group 0..31 in super-chunk
                int kc = kg >> 2, kin = kg & 3;
                int off = (((kc * 4 + (wrow >> 4)) * 64) + kin * 16 + (wrow & 15)) * 8;
                *(short8v*)&Wl[off] = v;
            }
        }
        // ---- A regs for chunk 0 of this super-chunk ----
        float4 r0, r1, r2, r3;
        {
            const float* p = ap + ks;
            r0 = *(const float4*)(p + 0);  r1 = *(const float4*)(p + 4);
            r2 = *(const float4*)(p + 8);  r3 = *(const float4*)(p + 12);
            if (ADD2) {
                const float* p2 = ap2 + ks;
                float4 s0 = *(const float4*)(p2 + 0), s1 = *(const float4*)(p2 + 4);
                float4 s2 = *(const float4*)(p2 + 8), s3 = *(const float4*)(p2 + 12);
                r0.x += s0.x; r0.y += s0.y; r0.z += s0.z; r0.w += s0.w;
                r1.x += s1.x; r1.y += s1.y; r1.z += s1.z; r1.w += s1.w;
                r2.x += s2.x; r2.y += s2.y; r2.z += s2.z; r2.w += s2.w;
                r3.x += s3.x; r3.y += s3.y; r3.z += s3.z; r3.w += s3.w;
            }
        }

        for (int kc = 0; kc < 8; kc++) {
            // write A chunk (fragment-ordered)
            {
                short8v v0, v1;
                v0[0] = (short)f2bf(r0.x); v0[1] = (short)f2bf(r0.y);
                v0[2] = (short)f2bf(r0.z); v0[3] = (short)f2bf(r0.w);
                v0[4] = (short)f2bf(r1.x); v0[5] = (short)f2bf(r1.y);
                v0[6] = (short)f2bf(r1.z); v0[7] = (short)f2bf(r1.w);
                v1[0] = (short)f2bf(r2.x); v1[1] = (short)f2bf(r2.y);
                v1[2] = (short)f2bf(r2.z); v1[3] = (short)f2bf(r2.w);
                v1[4] = (short)f2bf(r3.x); v1[5] = (short)f2bf(r3.y);
                v1[6] = (short)f2bf(r3.z); v1[7] = (short)f2bf(r3.w);
                int kg = (tid & 1) * 2;
                int off0 = (((arow >> 4) * 64) + kg * 16 + (arow & 15)) * 8;
                int off1 = (((arow >> 4) * 64) + (kg + 1) * 16 + (arow & 15)) * 8;
                *(short8v*)&Al[off0] = v0;
                *(short8v*)&Al[off1] = v1;
            }
            // prefetch next chunk (issue-early)
            if (kc < 7) {
                const float* p = ap + ks + (kc + 1) * 32;
                r0 = *(const float4*)(p + 0);  r1 = *(const float4*)(p + 4);
                r2 = *(const float4*)(p + 8);  r3 = *(const float4*)(p + 12);
                if (ADD2) {
                    const float* p2 = ap2 + ks + (kc + 1) * 32;
                    float4 s0 = *(const float4*)(p2 + 0), s1 = *(const float4*)(p2 + 4);
                    float4 s2 = *(const float4*)(p2 + 8), s3 = *(const float4*)(p2 + 12);
                    r0.x += s0.x; r0.y += s0.y; r0.z += s0.z; r0.w += s0.w;
                    r1.x += s1.x; r1.y += s1.y; r1.z += s1.z; r1.w += s1.w;
                    r2.x += s2.x; r2.y += s2.y; r2.z += s2.z; r2.w += s2.w;
                    r3.x += s3.x; r3.y += s3.y; r3.z += s3.z; r3.w += s3.w;
                }
            }
            __syncthreads();               // Al (and Wl at kc==0) visible

            short8v af0 = *(const short8v*)&Al[((mbase + 0) * 64 + l) * 8];
            short8v af1 = *(const short8v*)&Al[((mbase + 1) * 64 + l) * 8];
            short8v af2 = *(const short8v*)&Al[((mbase + 2) * 64 + l) * 8];
            short8v af3 = *(const short8v*)&Al[((mbase + 3) * 64 + l) * 8];
            short8v bf0 = *(const short8v*)&Wl[((kc * 4 + nbase + 0) * 64 + l) * 8];
            short8v bf1 = *(const short8v*)&Wl[((kc * 4 + nbase + 1) * 64 + l) * 8];

            acc[0][0] = __builtin_amdgcn_mfma_f32_16x16x32_bf16(af0, bf0, acc[0][0], 0, 0, 0);
            acc[0][1] = __builtin_amdgcn_mfma_f32_16x16x32_bf16(af0, bf1, acc[0][1], 0, 0, 0);
            acc[1][0] = __builtin_amdgcn_mfma_f32_16x16x32_bf16(af1, bf0, acc[1][0], 0, 0, 0);
            acc[1][1] = __builtin_amdgcn_mfma_f32_16x16x32_bf16(af1, bf1, acc[1][1], 0, 0, 0);
            acc[2][0] = __builtin_amdgcn_mfma_f32_16x16x32_bf16(af2, bf0, acc[2][0], 0, 0, 0);
            acc[2][1] = __builtin_amdgcn_mfma_f32_16x16x32_bf16(af2, bf1, acc[2][1], 0, 0, 0);
            acc[3][0] = __builtin_amdgcn_mfma_f32_16x16x32_bf16(af3, bf0, acc[3][0], 0, 0, 0);
            acc[3][1] = __builtin_amdgcn_mfma_f32_16x16x32_bf16(af3, bf1, acc[3][1], 0, 0, 0);

            __syncthreads();               // reads done; Al may be overwritten
        }
    }

    // ---- epilogue: row = mfrag*16 + (l>>4)*4 + r, col = nfrag*16 + (l&15) ----
    #pragma unroll
    for (int n = 0; n < 2; n++) {
        int gc = bn + nbase * 16 + n * 16 + (l & 15);
        float bc = bias[gc];
        #pragma unroll
        for (int m = 0; m < 4; m++) {
            int gr0 = bm + mbase * 16 + m * 16 + (l >> 4) * 4;
            #pragma unroll
            for (int r = 0; r < 4; r++) {
                int gr = gr0 + r;
                if (gr >= M) continue;
                float v = acc[m][n][r] + bc;
                if (ADDRES) v += res[(size_t)gr * ldc + coffs + gc];
                if (RELU)   v = fmaxf(v, 0.f);
                C[(size_t)gr * ldc + coffs + gc] = v;
            }
        }
    }
}

// ================================================================ value projection: bf16 MFMA GEMM, bf16 output (proven R4)
__global__ __launch_bounds__(256) void gemm_val_bf16(const float* __restrict__ A,
                                                     const float* __restrict__ Wt,
                                                     const float* __restrict__ bias,
                                                     ushort_t* __restrict__ C)
{
    __shared__ short Al[8 * 64 * 8];
    __shared__ short Wl[8 * 4 * 64 * 8];

    const int tid = threadIdx.x;
    const int bm = blockIdx.y * 128, bn = blockIdx.x * 64;

    {
        const int wrow = tid >> 2;
        const int kq   = (tid & 3) * 64;
        const float* wp = Wt + (size_t)(bn + wrow) * D_ + kq;
        #pragma unroll
        for (int grp = 0; grp < 8; grp++) {
            float4 f0 = *(const float4*)(wp + grp * 8);
            float4 f1 = *(const float4*)(wp + grp * 8 + 4);
            short8v v;
            v[0] = (short)f2bf(f0.x); v[1] = (short)f2bf(f0.y);
            v[2] = (short)f2bf(f0.z); v[3] = (short)f2bf(f0.w);
            v[4] = (short)f2bf(f1.x); v[5] = (short)f2bf(f1.y);
            v[6] = (short)f2bf(f1.z); v[7] = (short)f2bf(f1.w);
            int kg = (tid & 3) * 8 + grp;
            int kc = kg >> 2, kin = kg & 3;
            int off = (((kc * 4 + (wrow >> 4)) * 64) + kin * 16 + (wrow & 15)) * 8;
            *(short8v*)&Wl[off] = v;
        }
    }

    const int arow = tid >> 1;
    const int khalf = (tid & 1) * 16;
    const float* ap = A + (size_t)(bm + arow) * D_ + khalf;

    float4 r0, r1, r2, r3;
    r0 = *(const float4*)(ap + 0);  r1 = *(const float4*)(ap + 4);
    r2 = *(const float4*)(ap + 8);  r3 = *(const float4*)(ap + 12);

    const int l = tid & 63, w = tid >> 6;
    const int mbase = (w & 1) * 4, nbase = (w >> 1) * 2;
    float4v acc[4][2];
    #pragma unroll
    for (int m = 0; m < 4; m++)
        #pragma unroll
        for (int n = 0; n < 2; n++)
            acc[m][n] = (float4v){0.f, 0.f, 0.f, 0.f};

    __syncthreads();

    for (int kc = 0; kc < 8; kc++) {
        {
            short8v v0, v1;
            v0[0] = (short)f2bf(r0.x); v0[1] = (short)f2bf(r0.y);
            v0[2] = (short)f2bf(r0.z); v0[3] = (short)f2bf(r0.w);
            v0[4] = (short)f2bf(r1.x); v0[5] = (short)f2bf(r1.y);
            v0[6] = (short)f2bf(r1.z); v0[7] = (short)f2bf(r1.w);
            v1[0] = (short)f2bf(r2.x); v1[1] = (short)f2bf(r2.y);
            v1[2] = (short)f2bf(r2.z); v1[3] = (short)f2bf(r2.w);
            v1[4] = (short)f2bf(r3.x); v1[5] = (short)f2bf(r3.y);
            v1[6] = (short)f2bf(r3.z); v1[7] = (short)f2bf(r3.w);
            int kg = (tid & 1) * 2;
            int off0 = (((arow >> 4) * 64) + kg * 16 + (arow & 15)) * 8;
            int off1 = (((arow >> 4) * 64) + (kg + 1) * 16 + (arow & 15)) * 8;
            *(short8v*)&Al[off0] = v0;
            *(short8v*)&Al[off1] = v1;
        }
        if (kc < 7) {
            const float* np = ap + (kc + 1) * 32;
            r0 = *(const float4*)(np + 0);  r1 = *(const float4*)(np + 4);
            r2 = *(const float4*)(np + 8);  r3 = *(const float4*)(np + 12);
        }
        __syncthreads();

        short8v af0 = *(const short8v*)&Al[((mbase + 0) * 64 + l) * 8];
        short8v af1 = *(const short8v*)&Al[((mbase + 1) * 64 + l) * 8];
        short8v af2 = *(const short8v*)&Al[((mbase + 2) * 64 + l) * 8];
        short8v af3 = *(const short8v*)&Al[((mbase + 3) * 64 + l) * 8];
        short8v bf0 = *(const short8v*)&Wl[((kc * 4 + nbase + 0) * 64 + l) * 8];
        short8v bf1 = *(const short8v*)&Wl[((kc * 4 + nbase + 1) * 64 + l) * 8];

        acc[0][0] = __builtin_amdgcn_mfma_f32_16x16x32_bf16(af0, bf0, acc[0][0], 0, 0, 0);
        acc[0][1] = __builtin_amdgcn_mfma_f32_16x16x32_bf16(af0, bf1, acc[0][1], 0, 0, 0);
        acc[1][0] = __builtin_amdgcn_mfma_f32_16x16x32_bf16(af1, bf0, acc[1][0], 0, 0, 0);
        acc[1][1] = __builtin_amdgcn_mfma_f32_16x16x32_bf16(af1, bf1, acc[1][1], 0, 0, 0);
        acc[2][0] = __builtin_amdgcn_mfma_f32_16x16x32_bf16(af2, bf0, acc[2][0], 0, 0, 0);
        acc[2][1] = __builtin_amdgcn_mfma_f32_16x16x32_bf16(af2, bf1, acc[2][1], 0, 0, 0);
        acc[3][0] = __builtin_amdgcn_mfma_f32_16x16x32_bf16(af3, bf0, acc[3][0], 0, 0, 0);
        acc[3][1] = __builtin_amdgcn_mfma_f32_16x16x32_bf16(af3, bf1, acc[3][1], 0, 0, 0);

        __syncthreads();
    }

    #pragma unroll
    for (int n = 0; n < 2; n++) {
        int gc = bn + nbase * 16 + n * 16 + (l & 15);
        float bc = bias[gc];
        #pragma unroll
        for (int m = 0; m < 4; m++) {
            int gr = bm + mbase * 16 + m * 16 + (l >> 4) * 4;
            #pragma unroll
            for (int r = 0; r < 4; r++)
                C[(size_t)(gr + r) * D_ + gc] = f2bf(acc[m][n][r] + bc);
        }
    }
}

// ================================================================ flash self-attention, split-K over keys
#define ATK 64
__global__ __launch_bounds__(128) void attn_kernel(const float* __restrict__ QKV,
                                                   float* __restrict__ pml,
                                                   float* __restrict__ pacc)
{
    const int b = blockIdx.z, h = blockIdx.y;
    const int qb = blockIdx.x & 7, ks = blockIdx.x >> 3;
    const int q0 = qb * 128;
    const int kstart = ks * KCH;
    const int kend   = min(NQ_, kstart + KCH);
    const int tid  = threadIdx.x;
    const int wave = tid >> 6, lane = tid & 63;
    const int qi = lane & 31, half = lane >> 5;

    __shared__ float Ksm[ATK][HD_];
    __shared__ float Vsm[ATK][HD_];

    const int q_a = q0 + wave * 64 + qi * 2;
    const int q_b = q_a + 1;
    const int qa_c = min(q_a, NQ_ - 1);
    const int qb_c = min(q_b, NQ_ - 1);

    const float scale = 0.17677669529663687f;    // 1/sqrt(32)
    float Qa[16], Qb[16];
    {
        const float* pa = QKV + ((size_t)(b * NQ_ + qa_c)) * QKVW + h * HD_ + half * 16;
        const float* pb = QKV + ((size_t)(b * NQ_ + qb_c)) * QKVW + h * HD_ + half * 16;
        #pragma unroll
        for (int i = 0; i < 16; i += 4) {
            float4 va = *(const float4*)&pa[i];
            float4 vb = *(const float4*)&pb[i];
            Qa[i] = va.x * scale; Qa[i+1] = va.y * scale; Qa[i+2] = va.z * scale; Qa[i+3] = va.w * scale;
            Qb[i] = vb.x * scale; Qb[i+1] = vb.y * scale; Qb[i+2] = vb.z * scale; Qb[i+3] = vb.w * scale;
        }
    }

    float ma = -INFINITY, la = 0.f, mb = -INFINITY, lb = 0.f;
    float aa[16], ab[16];
    #pragma unroll
    for (int i = 0; i < 16; i++) { aa[i] = 0.f; ab[i] = 0.f; }

    for (int j0 = kstart; j0 < kend; j0 += ATK) {
        const int jn = min(ATK, kend - j0);
        __syncthreads();
        for (int f = tid; f < ATK * HD_ / 4; f += 128) {
            int j = f >> 3, d4 = (f & 7) << 2;
            if (j < jn) {
                const float* kp = QKV + ((size_t)(b * NQ_ + j0 + j)) * QKVW + 256 + h * HD_ + d4;
                *(float4*)&Ksm[j][d4] = *(const float4*)kp;
                *(float4*)&Vsm[j][d4] = *(const float4*)(kp + 256);
            }
        }
        __syncthreads();

        for (int j = 0; j < jn; j++) {
            float kr[16];
            #pragma unroll
            for (int i = 0; i < 16; i += 4) {
                float4 kv = *(const float4*)&Ksm[j][half * 16 + i];
                kr[i] = kv.x; kr[i+1] = kv.y; kr[i+2] = kv.z; kr[i+3] = kv.w;
            }
            float sa0 = 0.f, sa1 = 0.f, sa2 = 0.f, sa3 = 0.f;
            float sb0 = 0.f, sb1 = 0.f, sb2 = 0.f, sb3 = 0.f;
            #pragma unroll
            for (int i = 0; i < 16; i += 4) {
                sa0 += Qa[i] * kr[i];     sa1 += Qa[i+1] * kr[i+1];
                sa2 += Qa[i+2] * kr[i+2]; sa3 += Qa[i+3] * kr[i+3];
                sb0 += Qb[i] * kr[i];     sb1 += Qb[i+1] * kr[i+1];
                sb2 += Qb[i+2] * kr[i+2]; sb3 += Qb[i+3] * kr[i+3];
            }
            float sA = (sa0 + sa1) + (sa2 + sa3);
            float sB = (sb0 + sb1) + (sb2 + sb3);
            sA += __shfl_xor(sA, 32);
            sB += __shfl_xor(sB, 32);

            float vr[16];
            #pragma unroll
            for (int i = 0; i < 16; i += 4) {
                float4 vv = *(const float4*)&Vsm[j][half * 16 + i];
                vr[i] = vv.x; vr[i+1] = vv.y; vr[i+2] = vv.z; vr[i+3] = vv.w;
            }

            if (sA > ma) {
                float sc = __expf(ma - sA);
                la *= sc;
                #pragma unroll
                for (int i = 0; i < 16; i++) aa[i] *= sc;
                ma = sA;
            }
            float pA = __expf(sA - ma);
            la += pA;
            #pragma unroll
            for (int i = 0; i < 16; i++) aa[i] += pA * vr[i];

            if (sB > mb) {
                float sc = __expf(mb - sB);
                lb *= sc;
                #pragma unroll
                for (int i = 0; i < 16; i++) ab[i] *= sc;
                mb = sB;
            }
            float pB = __expf(sB - mb);
            lb += pB;
            #pragma unroll
            for (int i = 0; i < 16; i++) ab[i] += pB * vr[i];
        }
    }

    const int bh = b * H_ + h;
    if (q_a < NQ_) {
        size_t base = (((size_t)bh * KS_ + ks) * NQ_ + q_a) * 32 + half * 16;
        #pragma unroll
        for (int i = 0; i < 16; i += 4) {
            float4 v = make_float4(aa[i], aa[i+1], aa[i+2], aa[i+3]);
            *(float4*)&pacc[base + i] = v;
        }
        if (half == 0) {
            size_t mb_ = (((size_t)bh * KS_ + ks) * NQ_ + q_a) * 2;
            pml[mb_] = ma; pml[mb_ + 1] = la;
        }
    }
    if (q_b < NQ_) {
        size_t base = (((size_t)bh * KS_ + ks) * NQ_ + q_b) * 32 + half * 16;
        #pragma unroll
        for (int i = 0; i < 16; i += 4) {
            float4 v = make_float4(ab[i], ab[i+1], ab[i+2], ab[i+3]);
            *(float4*)&pacc[base + i] = v;
        }
        if (half == 0) {
            size_t mb_ = (((size_t)bh * KS_ + ks) * NQ_ + q_b) * 2;
            pml[mb_] = mb; pml[mb_ + 1] = lb;
        }
    }
}

// ================================================================ split-K combine
__global__ __launch_bounds__(256) void attn_combine(const float* __restrict__ pml,
                                                    const float* __restrict__ pacc,
                                                    float* __restrict__ SA)
{
    const int g  = threadIdx.x >> 5;
    const int ch = threadIdx.x & 31;
    const int t  = blockIdx.x * 8 + g;       // (b*H + h)*NQ + q
    const int bh = t / NQ_, q = t - bh * NQ_;

    float mv[KS_], lv[KS_];
    float M = -INFINITY;
    #pragma unroll
    for (int i = 0; i < KS_; i++) {
        size_t mb = (((size_t)bh * KS_ + i) * NQ_ + q) * 2;
        mv[i] = pml[mb]; lv[i] = pml[mb + 1];
        M = fmaxf(M, mv[i]);
    }
    float L = 0.f, acc = 0.f;
    #pragma unroll
    for (int i = 0; i < KS_; i++) {
        float wgt = __expf(mv[i] - M);
        L += lv[i] * wgt;
        acc += wgt * pacc[(((size_t)bh * KS_ + i) * NQ_ + q) * 32 + ch];
    }
    const int b = bh >> 3, h = bh & 7;
    SA[((size_t)(b * NQ_ + q)) * D_ + h * HD_ + ch] = acc / L;
}

// ================================================================ LayerNorm(x + y) * g + b
__global__ __launch_bounds__(64) void ln_kernel(const float* __restrict__ X,
                                                const float* __restrict__ Y,
                                                const float* __restrict__ g,
                                                const float* __restrict__ bt,
                                                float* __restrict__ out)
{
    const int row = blockIdx.x;
    const int lane = threadIdx.x;
    const size_t base = (size_t)row * D_ + lane * 4;
    float4 x = *(const float4*)&X[base];
    float4 y = *(const float4*)&Y[base];
    float v0 = x.x + y.x, v1 = x.y + y.y, v2 = x.z + y.z, v3 = x.w + y.w;
    float s = v0 + v1 + v2 + v3;
    #pragma unroll
    for (int o = 32; o; o >>= 1) s += __shfl_xor(s, o);
    float mean = s * (1.f / D_);
    float d0 = v0 - mean, d1 = v1 - mean, d2 = v2 - mean, d3 = v3 - mean;
    float ss = d0 * d0 + d1 * d1 + d2 * d2 + d3 * d3;
    #pragma unroll
    for (int o = 32; o; o >>= 1) ss += __shfl_xor(ss, o);
    float rstd = rsqrtf(ss * (1.f / D_) + 1e-5f);
    float4 gg = *(const float4*)&g[lane * 4];
    float4 bb = *(const float4*)&bt[lane * 4];
    float4 o4 = make_float4(d0 * rstd * gg.x + bb.x, d1 * rstd * gg.y + bb.y,
                            d2 * rstd * gg.z + bb.z, d3 * rstd * gg.w + bb.w);
    *(float4*)&out[base] = o4;
}

// ================================================================ softmax over 16 aw logits, in place
__global__ __launch_bounds__(256) void aw_softmax_kernel(float* __restrict__ offaw)
{
    int t = blockIdx.x * 256 + threadIdx.x;
    if (t >= M1 * H_) return;
    const int bq = t >> 3, h = t & 7;
    float* p = offaw + (size_t)bq * OAW + 256 + h * 16;
    float v[16];
    #pragma unroll
    for (int i = 0; i < 16; i += 4) {
        float4 q = *(const float4*)&p[i];
        v[i] = q.x; v[i+1] = q.y; v[i+2] = q.z; v[i+3] = q.w;
    }
    float m = v[0];
    #pragma unroll
    for (int i = 1; i < 16; i++) m = fmaxf(m, v[i]);
    float s = 0.f;
    #pragma unroll
    for (int i = 0; i < 16; i++) { v[i] = __expf(v[i] - m); s += v[i]; }
    float inv = 1.f / s;
    #pragma unroll
    for (int i = 0; i < 16; i += 4) {
        float4 q = make_float4(v[i] * inv, v[i+1] * inv, v[i+2] * inv, v[i+3] * inv);
        *(float4*)&p[i] = q;
    }
}

// ================================================================ MSDA bilinear sampling (bf16 value)
__global__ __launch_bounds__(256) void msda_kernel(const ushort_t* __restrict__ value,
                                                   const float* __restrict__ offaw,
                                                   const float* __restrict__ ref,
                                                   float* __restrict__ out)
{
    const int g    = threadIdx.x >> 5;
    const int lane = threadIdx.x & 31;
    const int t    = blockIdx.x * 8 + g;
    const int h  = t & 7;
    const int bq = t >> 3;
    const int b  = bq / NQ_;
    const float* offp = offaw + (size_t)bq * OAW + h * (L_ * P_ * 2);
    const float* awp  = offaw + (size_t)bq * OAW + 256 + h * (L_ * P_);
    const float* refp = ref + (size_t)bq * (L_ * 2);
    const ushort_t* vb = value + ((size_t)b * NV_) * D_ + h * HD_ + lane;

    float acc = 0.f;
    const int LW[4] = {128, 64, 32, 16};
    const int LS[4] = {0, 16384, 20480, 21504};

    #pragma unroll
    for (int l = 0; l < L_; l++) {
        const int wi = LW[l];
        const float Wf = (float)wi;
        float rx = refp[2 * l], ry = refp[2 * l + 1];
        #pragma unroll
        for (int p = 0; p < P_; p++) {
            float ox = offp[(l * P_ + p) * 2];
            float oy = offp[(l * P_ + p) * 2 + 1];
            float a  = awp[l * P_ + p];
            float lx = rx * Wf + ox - 0.5f;
            float ly = ry * Wf + oy - 0.5f;
            float x0f = floorf(lx), y0f = floorf(ly);
            float fx = lx - x0f, fy = ly - y0f;
            int x0 = (int)x0f, y0 = (int)y0f;
            #pragma unroll
            for (int dy = 0; dy < 2; dy++) {
                int yi = y0 + dy;
                if (yi < 0 || yi >= wi) continue;
                float wy = dy ? fy : 1.f - fy;
                #pragma unroll
                for (int dx = 0; dx < 2; dx++) {
                    int xi = x0 + dx;
                    if (xi < 0 || xi >= wi) continue;
                    float w = wy * (dx ? fx : 1.f - fx) * a;
                    acc += w * bf2f(vb[(size_t)(LS[l] + yi * wi + xi) * D_]);
                }
            }
        }
    }
    out[(size_t)bq * D_ + h * HD_ + lane] = acc;
}

// ================================================================ launch
extern "C" void kernel_launch(void* const* d_in, const int* in_sizes, int n_in,
                              void* d_out, int out_size, void* d_ws, size_t ws_size,
                              hipStream_t stream)
{
    const float* tgt      = (const float*)d_in[0];
    const float* qpos     = (const float*)d_in[1];
    const float* ref      = (const float*)d_in[2];
    const float* src      = (const float*)d_in[3];
    const float* sa_in_w  = (const float*)d_in[4];
    const float* sa_in_b  = (const float*)d_in[5];
    const float* sa_out_w = (const float*)d_in[6];
    const float* sa_out_b = (const float*)d_in[7];
    const float* ln2_g    = (const float*)d_in[8];
    const float* ln2_b    = (const float*)d_in[9];
    const float* off_w    = (const float*)d_in[10];
    const float* off_b    = (const float*)d_in[11];
    const float* aw_w     = (const float*)d_in[12];
    const float* aw_b     = (const float*)d_in[13];
    const float* val_w    = (const float*)d_in[14];
    const float* val_b    = (const float*)d_in[15];
    const float* out_w    = (const float*)d_in[16];
    const float* out_b    = (const float*)d_in[17];
    const float* ln1_g    = (const float*)d_in[18];
    const float* ln1_b    = (const float*)d_in[19];
    const float* ffn1_w   = (const float*)d_in[20];
    const float* ffn1_b   = (const float*)d_in[21];
    const float* ffn2_w   = (const float*)d_in[22];
    const float* ffn2_b   = (const float*)d_in[23];
    const float* ln3_g    = (const float*)d_in[24];
    const float* ln3_b    = (const float*)d_in[25];

    // ---- workspace layout (196 MB), lifetime-checked aliases ----
    float* ws      = (float*)d_ws;
    ushort_t* value = (ushort_t*)ws;                 // [MV*256] bf16 = 22,282,240 f32-slots
    float* qkv   = ws + 22282240;                    // [M1*768]
    float* battn = qkv + (size_t)M1 * QKVW;          // [M1*256]
    float* b2    = battn + (size_t)M1 * D_;          // [M1*256]  tgt2
    float* b4    = b2 + (size_t)M1 * D_;             // [M1*256]  tgt3
    float* pml   = b4 + (size_t)M1 * D_;             // [57600*8*2]
    float* pacc  = pml + (size_t)M1 * H_ * KS_ * 2;  // [57600*8*32]
    float* bsa   = qkv;                              // sa_out out   (qkv dead after attn+combine)
    float* offaw = qkv + (size_t)M1 * D_;            // [M1*384]
    float* bmsda = qkv;                              // msda out
    float* bca   = battn;                            // ca out
    float* hid   = pml;                              // ffn hidden [M1*1024] (partials dead after combine)
    float* bffn  = qkv;                              // ffn2 out
    float* out   = (float*)d_out;

    const dim3 g57_4(4, 57), g57_8(8, 57), g57_2(2, 57), g57_16(16, 57);

    // 1. qkv projection: q,k (A=tgt+qpos, N=512) and v (A=tgt, N=256) into fused [M1][768]
    gemm_mfma<true,  false, false><<<g57_8, 256, 0, stream>>>(
        tgt, qpos, sa_in_w, sa_in_b, nullptr, qkv, M1, D_, QKVW, 0);
    gemm_mfma<false, false, false><<<g57_4, 256, 0, stream>>>(
        tgt, nullptr, sa_in_w + 2 * D_ * D_, sa_in_b + 2 * D_, nullptr, qkv, M1, D_, QKVW, 512);
    // 2. value = src @ val_w^T + val_b   (bf16 out; MV % 128 == 0)
    gemm_val_bf16<<<dim3(D_ / 64, MV / 128), 256, 0, stream>>>(
        src, val_w, val_b, value);
    // 3. flash split-K self-attention + combine
    attn_kernel<<<dim3(8 * KS_, H_, BS_), 128, 0, stream>>>(qkv, pml, pacc);
    attn_combine<<<M1 * H_ / 8, 256, 0, stream>>>(pml, pacc, battn);
    // 4. sa_out projection
    gemm_mfma<false, false, false><<<g57_4, 256, 0, stream>>>(
        battn, nullptr, sa_out_w, sa_out_b, nullptr, bsa, M1, D_, D_, 0);
    // 5. tgt2 = LN(tgt + sa)
    ln_kernel<<<M1, 64, 0, stream>>>(tgt, bsa, ln2_g, ln2_b, b2);
    // 6. off (N=256) + aw (N=128) projections, A = tgt2 + qpos, into fused [M1][384]
    gemm_mfma<true, false, false><<<g57_4, 256, 0, stream>>>(
        b2, qpos, off_w, off_b, nullptr, offaw, M1, D_, OAW, 0);
    gemm_mfma<true, false, false><<<g57_2, 256, 0, stream>>>(
        b2, qpos, aw_w, aw_b, nullptr, offaw, M1, D_, OAW, 256);
    // 7. softmax over aw logits
    aw_softmax_kernel<<<(M1 * H_ + 255) / 256, 256, 0, stream>>>(offaw);
    // 8. MSDA sampling (bf16 value)
    msda_kernel<<<M1 * H_ / 8, 256, 0, stream>>>(value, offaw, ref, bmsda);
    // 9. ca = msda @ out_w^T + out_b + tgt2
    gemm_mfma<false, false, true><<<g57_4, 256, 0, stream>>>(
        bmsda, nullptr, out_w, out_b, b2, bca, M1, D_, D_, 0);
    // 10. tgt3 = LN(tgt2 + ca)
    ln_kernel<<<M1, 64, 0, stream>>>(b2, bca, ln1_g, ln1_b, b4);
    // 11. FFN: hid = relu(tgt3 @ ffn1^T + b) [N=1024]; ffn2 K=1024
    gemm_mfma<false, true,  false><<<g57_16, 256, 0, stream>>>(
        b4, nullptr, ffn1_w, ffn1_b, nullptr, hid, M1, D_, DF_, 0);
    gemm_mfma<false, false, false><<<g57_4, 256, 0, stream>>>(
        hid, nullptr, ffn2_w, ffn2_b, nullptr, bffn, M1, DF_, D_, 0);
    // 12. out = LN(tgt3 + ffn)
    ln_kernel<<<M1, 64, 0, stream>>>(b4, bffn, ln3_g, ln3_b, out);
}

// Round 7
// 722.918 us; speedup vs baseline: 2.4828x; 1.2019x over previous
//
#include <hip/hip_runtime.h>
#include <math.h>

#define D_   256
#define H_   8
#define HD_  32
#define L_   4
#define P_   4
#define DF_  1024
#define BS_  8
#define NQ_  900
#define NV_  21760
#define M1   (BS_*NQ_)   // 7200
#define MV   (BS_*NV_)   // 174080
#define QKVW 768         // fused qkv row width
#define OAW  384         // fused off+aw row width
#define KT_  64          // attention key tile

typedef __attribute__((ext_vector_type(8))) short short8v;
typedef __attribute__((ext_vector_type(4))) float float4v;
typedef unsigned short ushort_t;
typedef unsigned int uint_t;

// f32 -> bf16 (RNE), bf16 -> f32
__device__ __forceinline__ ushort_t f2bf(float f) {
    uint_t u = __float_as_uint(f);
    u += 0x7FFFu + ((u >> 16) & 1u);
    return (ushort_t)(u >> 16);
}
__device__ __forceinline__ float bf2f(ushort_t h) {
    return __uint_as_float(((uint_t)h) << 16);
}

// ================================================================ generic bf16-MFMA GEMM (fp32 in/out)  [proven R5/R6]
template<bool ADD2, bool RELU, bool ADDRES>
__global__ __launch_bounds__(256) void gemm_mfma(const float* __restrict__ A,
                                                 const float* __restrict__ A2,
                                                 const float* __restrict__ Wt,
                                                 const float* __restrict__ bias,
                                                 const float* __restrict__ res,
                                                 float* __restrict__ C,
                                                 int M, int K, int ldc, int coffs)
{
    __shared__ short Al[8 * 64 * 8];
    __shared__ short Wl[8 * 4 * 64 * 8];

    const int tid = threadIdx.x;
    const int bm = blockIdx.y * 128, bn = blockIdx.x * 64;

    const int l = tid & 63, w = tid >> 6;
    const int mbase = (w & 1) * 4, nbase = (w >> 1) * 2;
    float4v acc[4][2];
    #pragma unroll
    for (int m = 0; m < 4; m++)
        #pragma unroll
        for (int n = 0; n < 2; n++)
            acc[m][n] = (float4v){0.f, 0.f, 0.f, 0.f};

    const int arow  = tid >> 1;
    const int arow_c = min(bm + arow, M - 1);
    const int khalf = (tid & 1) * 16;
    const float* ap  = A + (size_t)arow_c * K + khalf;
    const float* ap2 = ADD2 ? (A2 + (size_t)arow_c * K + khalf) : nullptr;

    const int wrow = tid >> 2;
    const int kq   = (tid & 3) * 64;

    for (int ks = 0; ks < K; ks += 256) {
        __syncthreads();
        {
            const float* wp = Wt + (size_t)(bn + wrow) * K + ks + kq;
            #pragma unroll
            for (int grp = 0; grp < 8; grp++) {
                float4 f0 = *(const float4*)(wp + grp * 8);
                float4 f1 = *(const float4*)(wp + grp * 8 + 4);
                short8v v;
                v[0] = (short)f2bf(f0.x); v[1] = (short)f2bf(f0.y);
                v[2] = (short)f2bf(f0.z); v[3] = (short)f2bf(f0.w);
                v[4] = (short)f2bf(f1.x); v[5] = (short)f2bf(f1.y);
                v[6] = (short)f2bf(f1.z); v[7] = (short)f2bf(f1.w);
                int kg = (tid & 3) * 8 + grp;
                int kc = kg >> 2, kin = kg & 3;
                int off = (((kc * 4 + (wrow >> 4)) * 64) + kin * 16 + (wrow & 15)) * 8;
                *(short8v*)&Wl[off] = v;
            }
        }
        float4 r0, r1, r2, r3;
        {
            const float* p = ap + ks;
            r0 = *(const float4*)(p + 0);  r1 = *(const float4*)(p + 4);
            r2 = *(const float4*)(p + 8);  r3 = *(const float4*)(p + 12);
            if (ADD2) {
                const float* p2 = ap2 + ks;
                float4 s0 = *(const float4*)(p2 + 0), s1 = *(const float4*)(p2 + 4);
                float4 s2 = *(const float4*)(p2 + 8), s3 = *(const float4*)(p2 + 12);
                r0.x += s0.x; r0.y += s0.y; r0.z += s0.z; r0.w += s0.w;
                r1.x += s1.x; r1.y += s1.y; r1.z += s1.z; r1.w += s1.w;
                r2.x += s2.x; r2.y += s2.y; r2.z += s2.z; r2.w += s2.w;
                r3.x += s3.x; r3.y += s3.y; r3.z += s3.z; r3.w += s3.w;
            }
        }

        for (int kc = 0; kc < 8; kc++) {
            {
                short8v v0, v1;
                v0[0] = (short)f2bf(r0.x); v0[1] = (short)f2bf(r0.y);
                v0[2] = (short)f2bf(r0.z); v0[3] = (short)f2bf(r0.w);
                v0[4] = (short)f2bf(r1.x); v0[5] = (short)f2bf(r1.y);
                v0[6] = (short)f2bf(r1.z); v0[7] = (short)f2bf(r1.w);
                v1[0] = (short)f2bf(r2.x); v1[1] = (short)f2bf(r2.y);
                v1[2] = (short)f2bf(r2.z); v1[3] = (short)f2bf(r2.w);
                v1[4] = (short)f2bf(r3.x); v1[5] = (short)f2bf(r3.y);
                v1[6] = (short)f2bf(r3.z); v1[7] = (short)f2bf(r3.w);
                int kg = (tid & 1) * 2;
                int off0 = (((arow >> 4) * 64) + kg * 16 + (arow & 15)) * 8;
                int off1 = (((arow >> 4) * 64) + (kg + 1) * 16 + (arow & 15)) * 8;
                *(short8v*)&Al[off0] = v0;
                *(short8v*)&Al[off1] = v1;
            }
            if (kc < 7) {
                const float* p = ap + ks + (kc + 1) * 32;
                r0 = *(const float4*)(p + 0);  r1 = *(const float4*)(p + 4);
                r2 = *(const float4*)(p + 8);  r3 = *(const float4*)(p + 12);
                if (ADD2) {
                    const float* p2 = ap2 + ks + (kc + 1) * 32;
                    float4 s0 = *(const float4*)(p2 + 0), s1 = *(const float4*)(p2 + 4);
                    float4 s2 = *(const float4*)(p2 + 8), s3 = *(const float4*)(p2 + 12);
                    r0.x += s0.x; r0.y += s0.y; r0.z += s0.z; r0.w += s0.w;
                    r1.x += s1.x; r1.y += s1.y; r1.z += s1.z; r1.w += s1.w;
                    r2.x += s2.x; r2.y += s2.y; r2.z += s2.z; r2.w += s2.w;
                    r3.x += s3.x; r3.y += s3.y; r3.z += s3.z; r3.w += s3.w;
                }
            }
            __syncthreads();

            short8v af0 = *(const short8v*)&Al[((mbase + 0) * 64 + l) * 8];
            short8v af1 = *(const short8v*)&Al[((mbase + 1) * 64 + l) * 8];
            short8v af2 = *(const short8v*)&Al[((mbase + 2) * 64 + l) * 8];
            short8v af3 = *(const short8v*)&Al[((mbase + 3) * 64 + l) * 8];
            short8v bf0 = *(const short8v*)&Wl[((kc * 4 + nbase + 0) * 64 + l) * 8];
            short8v bf1 = *(const short8v*)&Wl[((kc * 4 + nbase + 1) * 64 + l) * 8];

            acc[0][0] = __builtin_amdgcn_mfma_f32_16x16x32_bf16(af0, bf0, acc[0][0], 0, 0, 0);
            acc[0][1] = __builtin_amdgcn_mfma_f32_16x16x32_bf16(af0, bf1, acc[0][1], 0, 0, 0);
            acc[1][0] = __builtin_amdgcn_mfma_f32_16x16x32_bf16(af1, bf0, acc[1][0], 0, 0, 0);
            acc[1][1] = __builtin_amdgcn_mfma_f32_16x16x32_bf16(af1, bf1, acc[1][1], 0, 0, 0);
            acc[2][0] = __builtin_amdgcn_mfma_f32_16x16x32_bf16(af2, bf0, acc[2][0], 0, 0, 0);
            acc[2][1] = __builtin_amdgcn_mfma_f32_16x16x32_bf16(af2, bf1, acc[2][1], 0, 0, 0);
            acc[3][0] = __builtin_amdgcn_mfma_f32_16x16x32_bf16(af3, bf0, acc[3][0], 0, 0, 0);
            acc[3][1] = __builtin_amdgcn_mfma_f32_16x16x32_bf16(af3, bf1, acc[3][1], 0, 0, 0);

            __syncthreads();
        }
    }

    #pragma unroll
    for (int n = 0; n < 2; n++) {
        int gc = bn + nbase * 16 + n * 16 + (l & 15);
        float bc = bias[gc];
        #pragma unroll
        for (int m = 0; m < 4; m++) {
            int gr0 = bm + mbase * 16 + m * 16 + (l >> 4) * 4;
            #pragma unroll
            for (int r = 0; r < 4; r++) {
                int gr = gr0 + r;
                if (gr >= M) continue;
                float v = acc[m][n][r] + bc;
                if (ADDRES) v += res[(size_t)gr * ldc + coffs + gc];
                if (RELU)   v = fmaxf(v, 0.f);
                C[(size_t)gr * ldc + coffs + gc] = v;
            }
        }
    }
}

// ================================================================ value projection: bf16 MFMA GEMM, bf16 output  [proven R4]
__global__ __launch_bounds__(256) void gemm_val_bf16(const float* __restrict__ A,
                                                     const float* __restrict__ Wt,
                                                     const float* __restrict__ bias,
                                                     ushort_t* __restrict__ C)
{
    __shared__ short Al[8 * 64 * 8];
    __shared__ short Wl[8 * 4 * 64 * 8];

    const int tid = threadIdx.x;
    const int bm = blockIdx.y * 128, bn = blockIdx.x * 64;

    {
        const int wrow = tid >> 2;
        const int kq   = (tid & 3) * 64;
        const float* wp = Wt + (size_t)(bn + wrow) * D_ + kq;
        #pragma unroll
        for (int grp = 0; grp < 8; grp++) {
            float4 f0 = *(const float4*)(wp + grp * 8);
            float4 f1 = *(const float4*)(wp + grp * 8 + 4);
            short8v v;
            v[0] = (short)f2bf(f0.x); v[1] = (short)f2bf(f0.y);
            v[2] = (short)f2bf(f0.z); v[3] = (short)f2bf(f0.w);
            v[4] = (short)f2bf(f1.x); v[5] = (short)f2bf(f1.y);
            v[6] = (short)f2bf(f1.z); v[7] = (short)f2bf(f1.w);
            int kg = (tid & 3) * 8 + grp;
            int kc = kg >> 2, kin = kg & 3;
            int off = (((kc * 4 + (wrow >> 4)) * 64) + kin * 16 + (wrow & 15)) * 8;
            *(short8v*)&Wl[off] = v;
        }
    }

    const int arow = tid >> 1;
    const int khalf = (tid & 1) * 16;
    const float* ap = A + (size_t)(bm + arow) * D_ + khalf;

    float4 r0, r1, r2, r3;
    r0 = *(const float4*)(ap + 0);  r1 = *(const float4*)(ap + 4);
    r2 = *(const float4*)(ap + 8);  r3 = *(const float4*)(ap + 12);

    const int l = tid & 63, w = tid >> 6;
    const int mbase = (w & 1) * 4, nbase = (w >> 1) * 2;
    float4v acc[4][2];
    #pragma unroll
    for (int m = 0; m < 4; m++)
        #pragma unroll
        for (int n = 0; n < 2; n++)
            acc[m][n] = (float4v){0.f, 0.f, 0.f, 0.f};

    __syncthreads();

    for (int kc = 0; kc < 8; kc++) {
        {
            short8v v0, v1;
            v0[0] = (short)f2bf(r0.x); v0[1] = (short)f2bf(r0.y);
            v0[2] = (short)f2bf(r0.z); v0[3] = (short)f2bf(r0.w);
            v0[4] = (short)f2bf(r1.x); v0[5] = (short)f2bf(r1.y);
            v0[6] = (short)f2bf(r1.z); v0[7] = (short)f2bf(r1.w);
            v1[0] = (short)f2bf(r2.x); v1[1] = (short)f2bf(r2.y);
            v1[2] = (short)f2bf(r2.z); v1[3] = (short)f2bf(r2.w);
            v1[4] = (short)f2bf(r3.x); v1[5] = (short)f2bf(r3.y);
            v1[6] = (short)f2bf(r3.z); v1[7] = (short)f2bf(r3.w);
            int kg = (tid & 1) * 2;
            int off0 = (((arow >> 4) * 64) + kg * 16 + (arow & 15)) * 8;
            int off1 = (((arow >> 4) * 64) + (kg + 1) * 16 + (arow & 15)) * 8;
            *(short8v*)&Al[off0] = v0;
            *(short8v*)&Al[off1] = v1;
        }
        if (kc < 7) {
            const float* np = ap + (kc + 1) * 32;
            r0 = *(const float4*)(np + 0);  r1 = *(const float4*)(np + 4);
            r2 = *(const float4*)(np + 8);  r3 = *(const float4*)(np + 12);
        }
        __syncthreads();

        short8v af0 = *(const short8v*)&Al[((mbase + 0) * 64 + l) * 8];
        short8v af1 = *(const short8v*)&Al[((mbase + 1) * 64 + l) * 8];
        short8v af2 = *(const short8v*)&Al[((mbase + 2) * 64 + l) * 8];
        short8v af3 = *(const short8v*)&Al[((mbase + 3) * 64 + l) * 8];
        short8v bf0 = *(const short8v*)&Wl[((kc * 4 + nbase + 0) * 64 + l) * 8];
        short8v bf1 = *(const short8v*)&Wl[((kc * 4 + nbase + 1) * 64 + l) * 8];

        acc[0][0] = __builtin_amdgcn_mfma_f32_16x16x32_bf16(af0, bf0, acc[0][0], 0, 0, 0);
        acc[0][1] = __builtin_amdgcn_mfma_f32_16x16x32_bf16(af0, bf1, acc[0][1], 0, 0, 0);
        acc[1][0] = __builtin_amdgcn_mfma_f32_16x16x32_bf16(af1, bf0, acc[1][0], 0, 0, 0);
        acc[1][1] = __builtin_amdgcn_mfma_f32_16x16x32_bf16(af1, bf1, acc[1][1], 0, 0, 0);
        acc[2][0] = __builtin_amdgcn_mfma_f32_16x16x32_bf16(af2, bf0, acc[2][0], 0, 0, 0);
        acc[2][1] = __builtin_amdgcn_mfma_f32_16x16x32_bf16(af2, bf1, acc[2][1], 0, 0, 0);
        acc[3][0] = __builtin_amdgcn_mfma_f32_16x16x32_bf16(af3, bf0, acc[3][0], 0, 0, 0);
        acc[3][1] = __builtin_amdgcn_mfma_f32_16x16x32_bf16(af3, bf1, acc[3][1], 0, 0, 0);

        __syncthreads();
    }

    #pragma unroll
    for (int n = 0; n < 2; n++) {
        int gc = bn + nbase * 16 + n * 16 + (l & 15);
        float bc = bias[gc];
        #pragma unroll
        for (int m = 0; m < 4; m++) {
            int gr = bm + mbase * 16 + m * 16 + (l >> 4) * 4;
            #pragma unroll
            for (int r = 0; r < 4; r++)
                C[(size_t)(gr + r) * D_ + gc] = f2bf(acc[m][n][r] + bc);
        }
    }
}

// ================================================================ bf16-MFMA flash self-attention
// Block 256 thr / 4 waves = 64 queries of one (b,h); wave handles 16 q.
// Swapped QK^T: mfma(K_frag, Q_frag) -> lane l holds S[key][q=l&15].
// Softmax reduce over lanes {q,q+16,q+32,q+48} via shfl_xor(16/32).
// P relayout to A-frag order via per-wave LDS round-trip; PV via mfma(P, V^T-frag).
__global__ __launch_bounds__(256) void attn_mfma(const float* __restrict__ QKV,
                                                 float* __restrict__ SA)
{
    const int bh = blockIdx.y;
    const int b = bh >> 3, h = bh & 7;
    const int q0 = blockIdx.x * 64;
    const int tid = threadIdx.x, l = tid & 63, w = tid >> 6;

    __shared__ short Ql[4][64][8];        // 4 KB  q-frags (frag f: q=f*16+(l&15), d=(l>>4)*8+j)
    __shared__ short Kl[4][64][8];        // 4 KB  key-frags, same form
    __shared__ short Vl[2][2][64][8];     // 4 KB  [kf][nf]: V[key=kf*32+(l>>4)*8+j][d=nf*16+(l&15)]
    __shared__ short Pl[4][2][64][8];     // 8 KB  per-wave P A-frags
    __shared__ float cs[4][16];           // per-wave per-q broadcast

    const float scale = 0.17677669529663687f;    // 1/sqrt(32)

    // ---- stage Q once (pre-scaled) ----
    {
        const int qrow = tid >> 2, dgrp = tid & 3;
        const int qg = min(q0 + qrow, NQ_ - 1);
        const float* qp = QKV + ((size_t)(b * NQ_ + qg)) * QKVW + h * HD_ + dgrp * 8;
        float4 f0 = *(const float4*)qp, f1 = *(const float4*)(qp + 4);
        short8v v;
        v[0] = (short)f2bf(f0.x * scale); v[1] = (short)f2bf(f0.y * scale);
        v[2] = (short)f2bf(f0.z * scale); v[3] = (short)f2bf(f0.w * scale);
        v[4] = (short)f2bf(f1.x * scale); v[5] = (short)f2bf(f1.y * scale);
        v[6] = (short)f2bf(f1.z * scale); v[7] = (short)f2bf(f1.w * scale);
        *(short8v*)&Ql[qrow >> 4][(qrow & 15) + 16 * dgrp][0] = v;
    }
    __syncthreads();
    const short8v qf = *(const short8v*)&Ql[w][l][0];

    float m = -INFINITY, lsum = 0.f;
    float4v o0 = (float4v){0.f, 0.f, 0.f, 0.f};
    float4v o1 = (float4v){0.f, 0.f, 0.f, 0.f};

    for (int kt0 = 0; kt0 < NQ_; kt0 += KT_) {
        // ---- stage K tile (A-frag order) + V tile (B-frag order) ----
        {
            const int krow = tid >> 2, dgrp = tid & 3;
            const int key = kt0 + krow;
            float4 f0 = make_float4(0.f,0.f,0.f,0.f), f1 = f0;
            float4 g0 = f0, g1 = f0;
            if (key < NQ_) {
                const float* kp = QKV + ((size_t)(b * NQ_ + key)) * QKVW + 256 + h * HD_ + dgrp * 8;
                f0 = *(const float4*)kp;       f1 = *(const float4*)(kp + 4);
                g0 = *(const float4*)(kp+256); g1 = *(const float4*)(kp + 260);  // V row
            }
            short8v v;
            v[0] = (short)f2bf(f0.x); v[1] = (short)f2bf(f0.y);
            v[2] = (short)f2bf(f0.z); v[3] = (short)f2bf(f0.w);
            v[4] = (short)f2bf(f1.x); v[5] = (short)f2bf(f1.y);
            v[6] = (short)f2bf(f1.z); v[7] = (short)f2bf(f1.w);
            *(short8v*)&Kl[krow >> 4][(krow & 15) + 16 * dgrp][0] = v;

            const int kf = krow >> 5;
            const int lb = 16 * ((krow & 31) >> 3);
            const int j  = krow & 7;
            const int d0 = dgrp * 8;
            Vl[kf][(d0+0)>>4][((d0+0)&15)+lb][j] = (short)f2bf(g0.x);
            Vl[kf][(d0+1)>>4][((d0+1)&15)+lb][j] = (short)f2bf(g0.y);
            Vl[kf][(d0+2)>>4][((d0+2)&15)+lb][j] = (short)f2bf(g0.z);
            Vl[kf][(d0+3)>>4][((d0+3)&15)+lb][j] = (short)f2bf(g0.w);
            Vl[kf][(d0+4)>>4][((d0+4)&15)+lb][j] = (short)f2bf(g1.x);
            Vl[kf][(d0+5)>>4][((d0+5)&15)+lb][j] = (short)f2bf(g1.y);
            Vl[kf][(d0+6)>>4][((d0+6)&15)+lb][j] = (short)f2bf(g1.z);
            Vl[kf][(d0+7)>>4][((d0+7)&15)+lb][j] = (short)f2bf(g1.w);
        }
        __syncthreads();

        // ---- QK^T: 4 MFMAs -> lane l holds S[key=f*16+(l>>4)*4+r][q=l&15] ----
        float4v s[4];
        #pragma unroll
        for (int f = 0; f < 4; f++) {
            short8v kfr = *(const short8v*)&Kl[f][l][0];
            s[f] = __builtin_amdgcn_mfma_f32_16x16x32_bf16(
                kfr, qf, (float4v){0.f, 0.f, 0.f, 0.f}, 0, 0, 0);
        }
        if (kt0 + KT_ > NQ_) {             // tail mask
            #pragma unroll
            for (int f = 0; f < 4; f++)
                #pragma unroll
                for (int r = 0; r < 4; r++)
                    if (kt0 + f * 16 + (l >> 4) * 4 + r >= NQ_) s[f][r] = -1e30f;
        }

        // ---- online softmax ----
        float tm = -1e30f;
        #pragma unroll
        for (int f = 0; f < 4; f++)
            #pragma unroll
            for (int r = 0; r < 4; r++) tm = fmaxf(tm, s[f][r]);
        tm = fmaxf(tm, __shfl_xor(tm, 16));
        tm = fmaxf(tm, __shfl_xor(tm, 32));
        float mnew = fmaxf(m, tm);
        float c = __expf(m - mnew);
        m = mnew;
        float ps = 0.f;
        #pragma unroll
        for (int f = 0; f < 4; f++)
            #pragma unroll
            for (int r = 0; r < 4; r++) {
                float p = __expf(s[f][r] - m);
                s[f][r] = p; ps += p;
            }
        ps += __shfl_xor(ps, 16);
        ps += __shfl_xor(ps, 32);
        lsum = lsum * c + ps;
        if ((l >> 4) == 0) cs[w][l & 15] = c;          // per-q rescale broadcast
        float4 c4 = *(const float4*)&cs[w][(l >> 4) * 4];
        o0[0] *= c4.x; o0[1] *= c4.y; o0[2] *= c4.z; o0[3] *= c4.w;
        o1[0] *= c4.x; o1[1] *= c4.y; o1[2] *= c4.z; o1[3] *= c4.w;

        // ---- P -> bf16, relayout to A-frag order via per-wave LDS ----
        #pragma unroll
        for (int f = 0; f < 4; f++) {
            uint_t lo = (uint_t)f2bf(s[f][0]) | ((uint_t)f2bf(s[f][1]) << 16);
            uint_t hi = (uint_t)f2bf(s[f][2]) | ((uint_t)f2bf(s[f][3]) << 16);
            int lp = (l & 15) + 16 * ((f & 1) * 2 + ((l >> 4) >> 1));
            int j0 = ((l >> 4) & 1) * 4;
            *(uint2*)&Pl[w][f >> 1][lp][j0] = make_uint2(lo, hi);
        }
        // ---- PV: 4 MFMAs, accumulate O[16q][32d] ----
        #pragma unroll
        for (int kf = 0; kf < 2; kf++) {
            short8v pa = *(const short8v*)&Pl[w][kf][l][0];
            short8v v0 = *(const short8v*)&Vl[kf][0][l][0];
            short8v v1 = *(const short8v*)&Vl[kf][1][l][0];
            o0 = __builtin_amdgcn_mfma_f32_16x16x32_bf16(pa, v0, o0, 0, 0, 0);
            o1 = __builtin_amdgcn_mfma_f32_16x16x32_bf16(pa, v1, o1, 0, 0, 0);
        }
        __syncthreads();                   // before next tile overwrites Kl/Vl
    }

    // ---- finalize: divide by per-q lsum, store ----
    if ((l >> 4) == 0) cs[w][l & 15] = lsum;
    float4 l4 = *(const float4*)&cs[w][(l >> 4) * 4];
    float linv[4] = {1.f / l4.x, 1.f / l4.y, 1.f / l4.z, 1.f / l4.w};
    #pragma unroll
    for (int r = 0; r < 4; r++) {
        int qg = q0 + w * 16 + (l >> 4) * 4 + r;
        if (qg < NQ_) {
            float* op = SA + ((size_t)(b * NQ_ + qg)) * D_ + h * HD_ + (l & 15);
            op[0]  = o0[r] * linv[r];
            op[16] = o1[r] * linv[r];
        }
    }
}

// ================================================================ LayerNorm(x + y) * g + b
__global__ __launch_bounds__(64) void ln_kernel(const float* __restrict__ X,
                                                const float* __restrict__ Y,
                                                const float* __restrict__ g,
                                                const float* __restrict__ bt,
                                                float* __restrict__ out)
{
    const int row = blockIdx.x;
    const int lane = threadIdx.x;
    const size_t base = (size_t)row * D_ + lane * 4;
    float4 x = *(const float4*)&X[base];
    float4 y = *(const float4*)&Y[base];
    float v0 = x.x + y.x, v1 = x.y + y.y, v2 = x.z + y.z, v3 = x.w + y.w;
    float s = v0 + v1 + v2 + v3;
    #pragma unroll
    for (int o = 32; o; o >>= 1) s += __shfl_xor(s, o);
    float mean = s * (1.f / D_);
    float d0 = v0 - mean, d1 = v1 - mean, d2 = v2 - mean, d3 = v3 - mean;
    float ss = d0 * d0 + d1 * d1 + d2 * d2 + d3 * d3;
    #pragma unroll
    for (int o = 32; o; o >>= 1) ss += __shfl_xor(ss, o);
    float rstd = rsqrtf(ss * (1.f / D_) + 1e-5f);
    float4 gg = *(const float4*)&g[lane * 4];
    float4 bb = *(const float4*)&bt[lane * 4];
    float4 o4 = make_float4(d0 * rstd * gg.x + bb.x, d1 * rstd * gg.y + bb.y,
                            d2 * rstd * gg.z + bb.z, d3 * rstd * gg.w + bb.w);
    *(float4*)&out[base] = o4;
}

// ================================================================ softmax over 16 aw logits, in place
__global__ __launch_bounds__(256) void aw_softmax_kernel(float* __restrict__ offaw)
{
    int t = blockIdx.x * 256 + threadIdx.x;
    if (t >= M1 * H_) return;
    const int bq = t >> 3, h = t & 7;
    float* p = offaw + (size_t)bq * OAW + 256 + h * 16;
    float v[16];
    #pragma unroll
    for (int i = 0; i < 16; i += 4) {
        float4 q = *(const float4*)&p[i];
        v[i] = q.x; v[i+1] = q.y; v[i+2] = q.z; v[i+3] = q.w;
    }
    float m = v[0];
    #pragma unroll
    for (int i = 1; i < 16; i++) m = fmaxf(m, v[i]);
    float s = 0.f;
    #pragma unroll
    for (int i = 0; i < 16; i++) { v[i] = __expf(v[i] - m); s += v[i]; }
    float inv = 1.f / s;
    #pragma unroll
    for (int i = 0; i < 16; i += 4) {
        float4 q = make_float4(v[i] * inv, v[i+1] * inv, v[i+2] * inv, v[i+3] * inv);
        *(float4*)&p[i] = q;
    }
}

// ================================================================ MSDA bilinear sampling (bf16 value)
__global__ __launch_bounds__(256) void msda_kernel(const ushort_t* __restrict__ value,
                                                   const float* __restrict__ offaw,
                                                   const float* __restrict__ ref,
                                                   float* __restrict__ out)
{
    const int g    = threadIdx.x >> 5;
    const int lane = threadIdx.x & 31;
    const int t    = blockIdx.x * 8 + g;
    const int h  = t & 7;
    const int bq = t >> 3;
    const int b  = bq / NQ_;
    const float* offp = offaw + (size_t)bq * OAW + h * (L_ * P_ * 2);
    const float* awp  = offaw + (size_t)bq * OAW + 256 + h * (L_ * P_);
    const float* refp = ref + (size_t)bq * (L_ * 2);
    const ushort_t* vb = value + ((size_t)b * NV_) * D_ + h * HD_ + lane;

    float acc = 0.f;
    const int LW[4] = {128, 64, 32, 16};
    const int LS[4] = {0, 16384, 20480, 21504};

    #pragma unroll
    for (int l = 0; l < L_; l++) {
        const int wi = LW[l];
        const float Wf = (float)wi;
        float rx = refp[2 * l], ry = refp[2 * l + 1];
        #pragma unroll
        for (int p = 0; p < P_; p++) {
            float ox = offp[(l * P_ + p) * 2];
            float oy = offp[(l * P_ + p) * 2 + 1];
            float a  = awp[l * P_ + p];
            float lx = rx * Wf + ox - 0.5f;
            float ly = ry * Wf + oy - 0.5f;
            float x0f = floorf(lx), y0f = floorf(ly);
            float fx = lx - x0f, fy = ly - y0f;
            int x0 = (int)x0f, y0 = (int)y0f;
            #pragma unroll
            for (int dy = 0; dy < 2; dy++) {
                int yi = y0 + dy;
                if (yi < 0 || yi >= wi) continue;
                float wy = dy ? fy : 1.f - fy;
                #pragma unroll
                for (int dx = 0; dx < 2; dx++) {
                    int xi = x0 + dx;
                    if (xi < 0 || xi >= wi) continue;
                    float w = wy * (dx ? fx : 1.f - fx) * a;
                    acc += w * bf2f(vb[(size_t)(LS[l] + yi * wi + xi) * D_]);
                }
            }
        }
    }
    out[(size_t)bq * D_ + h * HD_ + lane] = acc;
}

// ================================================================ launch
extern "C" void kernel_launch(void* const* d_in, const int* in_sizes, int n_in,
                              void* d_out, int out_size, void* d_ws, size_t ws_size,
                              hipStream_t stream)
{
    const float* tgt      = (const float*)d_in[0];
    const float* qpos     = (const float*)d_in[1];
    const float* ref      = (const float*)d_in[2];
    const float* src      = (const float*)d_in[3];
    const float* sa_in_w  = (const float*)d_in[4];
    const float* sa_in_b  = (const float*)d_in[5];
    const float* sa_out_w = (const float*)d_in[6];
    const float* sa_out_b = (const float*)d_in[7];
    const float* ln2_g    = (const float*)d_in[8];
    const float* ln2_b    = (const float*)d_in[9];
    const float* off_w    = (const float*)d_in[10];
    const float* off_b    = (const float*)d_in[11];
    const float* aw_w     = (const float*)d_in[12];
    const float* aw_b     = (const float*)d_in[13];
    const float* val_w    = (const float*)d_in[14];
    const float* val_b    = (const float*)d_in[15];
    const float* out_w    = (const float*)d_in[16];
    const float* out_b    = (const float*)d_in[17];
    const float* ln1_g    = (const float*)d_in[18];
    const float* ln1_b    = (const float*)d_in[19];
    const float* ffn1_w   = (const float*)d_in[20];
    const float* ffn1_b   = (const float*)d_in[21];
    const float* ffn2_w   = (const float*)d_in[22];
    const float* ffn2_b   = (const float*)d_in[23];
    const float* ln3_g    = (const float*)d_in[24];
    const float* ln3_b    = (const float*)d_in[25];

    // ---- workspace layout, lifetime-checked aliases ----
    float* ws      = (float*)d_ws;
    ushort_t* value = (ushort_t*)ws;                 // [MV*256] bf16 = 22,282,240 f32-slots
    float* qkv   = ws + 22282240;                    // [M1*768]
    float* battn = qkv + (size_t)M1 * QKVW;          // [M1*256]
    float* b2    = battn + (size_t)M1 * D_;          // [M1*256]  tgt2
    float* b4    = b2 + (size_t)M1 * D_;             // [M1*256]  tgt3
    float* hid   = b4 + (size_t)M1 * D_;             // [M1*1024] ffn hidden
    float* bsa   = qkv;                              // sa_out out (qkv dead after attn)
    float* offaw = qkv + (size_t)M1 * D_;            // [M1*384]
    float* bmsda = qkv;                              // msda out
    float* bca   = battn;                            // ca out
    float* bffn  = qkv;                              // ffn2 out
    float* out   = (float*)d_out;

    const dim3 g57_4(4, 57), g57_8(8, 57), g57_2(2, 57), g57_16(16, 57);

    // 1. qkv projection: q,k (A=tgt+qpos, N=512) and v (A=tgt, N=256) into fused [M1][768]
    gemm_mfma<true,  false, false><<<g57_8, 256, 0, stream>>>(
        tgt, qpos, sa_in_w, sa_in_b, nullptr, qkv, M1, D_, QKVW, 0);
    gemm_mfma<false, false, false><<<g57_4, 256, 0, stream>>>(
        tgt, nullptr, sa_in_w + 2 * D_ * D_, sa_in_b + 2 * D_, nullptr, qkv, M1, D_, QKVW, 512);
    // 2. value = src @ val_w^T + val_b   (bf16 out; MV % 128 == 0)
    gemm_val_bf16<<<dim3(D_ / 64, MV / 128), 256, 0, stream>>>(
        src, val_w, val_b, value);
    // 3. bf16-MFMA flash self-attention (no split-K, no combine)
    attn_mfma<<<dim3((NQ_ + 63) / 64, BS_ * H_), 256, 0, stream>>>(qkv, battn);
    // 4. sa_out projection
    gemm_mfma<false, false, false><<<g57_4, 256, 0, stream>>>(
        battn, nullptr, sa_out_w, sa_out_b, nullptr, bsa, M1, D_, D_, 0);
    // 5. tgt2 = LN(tgt + sa)
    ln_kernel<<<M1, 64, 0, stream>>>(tgt, bsa, ln2_g, ln2_b, b2);
    // 6. off (N=256) + aw (N=128) projections, A = tgt2 + qpos, into fused [M1][384]
    gemm_mfma<true, false, false><<<g57_4, 256, 0, stream>>>(
        b2, qpos, off_w, off_b, nullptr, offaw, M1, D_, OAW, 0);
    gemm_mfma<true, false, false><<<g57_2, 256, 0, stream>>>(
        b2, qpos, aw_w, aw_b, nullptr, offaw, M1, D_, OAW, 256);
    // 7. softmax over aw logits
    aw_softmax_kernel<<<(M1 * H_ + 255) / 256, 256, 0, stream>>>(offaw);
    // 8. MSDA sampling (bf16 value)
    msda_kernel<<<M1 * H_ / 8, 256, 0, stream>>>(value, offaw, ref, bmsda);
    // 9. ca = msda @ out_w^T + out_b + tgt2
    gemm_mfma<false, false, true><<<g57_4, 256, 0, stream>>>(
        bmsda, nullptr, out_w, out_b, b2, bca, M1, D_, D_, 0);
    // 10. tgt3 = LN(tgt2 + ca)
    ln_kernel<<<M1, 64, 0, stream>>>(b2, bca, ln1_g, ln1_b, b4);
    // 11. FFN
    gemm_mfma<false, true,  false><<<g57_16, 256, 0, stream>>>(
        b4, nullptr, ffn1_w, ffn1_b, nullptr, hid, M1, D_, DF_, 0);
    gemm_mfma<false, false, false><<<g57_4, 256, 0, stream>>>(
        hid, nullptr, ffn2_w, ffn2_b, nullptr, bffn, M1, DF_, D_, 0);
    // 12. out = LN(tgt3 + ffn)
    ln_kernel<<<M1, 64, 0, stream>>>(b4, bffn, ln3_g, ln3_b, out);
}

// Round 8
// 696.629 us; speedup vs baseline: 2.5765x; 1.0377x over previous
//
#include <hip/hip_runtime.h>
#include <math.h>

#define D_   256
#define H_   8
#define HD_  32
#define L_   4
#define P_   4
#define DF_  1024
#define BS_  8
#define NQ_  900
#define NV_  21760
#define M1   (BS_*NQ_)   // 7200
#define MV   (BS_*NV_)   // 174080
#define QKVW 768         // fused qkv row width
#define OAW  384         // fused off+aw row width
#define KT_  64          // attention key tile

typedef __attribute__((ext_vector_type(8))) short short8v;
typedef __attribute__((ext_vector_type(4))) float float4v;
typedef unsigned short ushort_t;
typedef unsigned int uint_t;

// f32 -> bf16 (RNE), bf16 -> f32
__device__ __forceinline__ ushort_t f2bf(float f) {
    uint_t u = __float_as_uint(f);
    u += 0x7FFFu + ((u >> 16) & 1u);
    return (ushort_t)(u >> 16);
}
__device__ __forceinline__ float bf2f(ushort_t h) {
    return __uint_as_float(((uint_t)h) << 16);
}

// ================================================================ generic bf16-MFMA GEMM (fp32 in/out)  [proven R5/R6]
template<bool ADD2, bool RELU, bool ADDRES>
__global__ __launch_bounds__(256) void gemm_mfma(const float* __restrict__ A,
                                                 const float* __restrict__ A2,
                                                 const float* __restrict__ Wt,
                                                 const float* __restrict__ bias,
                                                 const float* __restrict__ res,
                                                 float* __restrict__ C,
                                                 int M, int K, int ldc, int coffs)
{
    __shared__ short Al[8 * 64 * 8];
    __shared__ short Wl[8 * 4 * 64 * 8];

    const int tid = threadIdx.x;
    const int bm = blockIdx.y * 128, bn = blockIdx.x * 64;

    const int l = tid & 63, w = tid >> 6;
    const int mbase = (w & 1) * 4, nbase = (w >> 1) * 2;
    float4v acc[4][2];
    #pragma unroll
    for (int m = 0; m < 4; m++)
        #pragma unroll
        for (int n = 0; n < 2; n++)
            acc[m][n] = (float4v){0.f, 0.f, 0.f, 0.f};

    const int arow  = tid >> 1;
    const int arow_c = min(bm + arow, M - 1);
    const int khalf = (tid & 1) * 16;
    const float* ap  = A + (size_t)arow_c * K + khalf;
    const float* ap2 = ADD2 ? (A2 + (size_t)arow_c * K + khalf) : nullptr;

    const int wrow = tid >> 2;
    const int kq   = (tid & 3) * 64;

    for (int ks = 0; ks < K; ks += 256) {
        __syncthreads();
        {
            const float* wp = Wt + (size_t)(bn + wrow) * K + ks + kq;
            #pragma unroll
            for (int grp = 0; grp < 8; grp++) {
                float4 f0 = *(const float4*)(wp + grp * 8);
                float4 f1 = *(const float4*)(wp + grp * 8 + 4);
                short8v v;
                v[0] = (short)f2bf(f0.x); v[1] = (short)f2bf(f0.y);
                v[2] = (short)f2bf(f0.z); v[3] = (short)f2bf(f0.w);
                v[4] = (short)f2bf(f1.x); v[5] = (short)f2bf(f1.y);
                v[6] = (short)f2bf(f1.z); v[7] = (short)f2bf(f1.w);
                int kg = (tid & 3) * 8 + grp;
                int kc = kg >> 2, kin = kg & 3;
                int off = (((kc * 4 + (wrow >> 4)) * 64) + kin * 16 + (wrow & 15)) * 8;
                *(short8v*)&Wl[off] = v;
            }
        }
        float4 r0, r1, r2, r3;
        {
            const float* p = ap + ks;
            r0 = *(const float4*)(p + 0);  r1 = *(const float4*)(p + 4);
            r2 = *(const float4*)(p + 8);  r3 = *(const float4*)(p + 12);
            if (ADD2) {
                const float* p2 = ap2 + ks;
                float4 s0 = *(const float4*)(p2 + 0), s1 = *(const float4*)(p2 + 4);
                float4 s2 = *(const float4*)(p2 + 8), s3 = *(const float4*)(p2 + 12);
                r0.x += s0.x; r0.y += s0.y; r0.z += s0.z; r0.w += s0.w;
                r1.x += s1.x; r1.y += s1.y; r1.z += s1.z; r1.w += s1.w;
                r2.x += s2.x; r2.y += s2.y; r2.z += s2.z; r2.w += s2.w;
                r3.x += s3.x; r3.y += s3.y; r3.z += s3.z; r3.w += s3.w;
            }
        }

        for (int kc = 0; kc < 8; kc++) {
            {
                short8v v0, v1;
                v0[0] = (short)f2bf(r0.x); v0[1] = (short)f2bf(r0.y);
                v0[2] = (short)f2bf(r0.z); v0[3] = (short)f2bf(r0.w);
                v0[4] = (short)f2bf(r1.x); v0[5] = (short)f2bf(r1.y);
                v0[6] = (short)f2bf(r1.z); v0[7] = (short)f2bf(r1.w);
                v1[0] = (short)f2bf(r2.x); v1[1] = (short)f2bf(r2.y);
                v1[2] = (short)f2bf(r2.z); v1[3] = (short)f2bf(r2.w);
                v1[4] = (short)f2bf(r3.x); v1[5] = (short)f2bf(r3.y);
                v1[6] = (short)f2bf(r3.z); v1[7] = (short)f2bf(r3.w);
                int kg = (tid & 1) * 2;
                int off0 = (((arow >> 4) * 64) + kg * 16 + (arow & 15)) * 8;
                int off1 = (((arow >> 4) * 64) + (kg + 1) * 16 + (arow & 15)) * 8;
                *(short8v*)&Al[off0] = v0;
                *(short8v*)&Al[off1] = v1;
            }
            if (kc < 7) {
                const float* p = ap + ks + (kc + 1) * 32;
                r0 = *(const float4*)(p + 0);  r1 = *(const float4*)(p + 4);
                r2 = *(const float4*)(p + 8);  r3 = *(const float4*)(p + 12);
                if (ADD2) {
                    const float* p2 = ap2 + ks + (kc + 1) * 32;
                    float4 s0 = *(const float4*)(p2 + 0), s1 = *(const float4*)(p2 + 4);
                    float4 s2 = *(const float4*)(p2 + 8), s3 = *(const float4*)(p2 + 12);
                    r0.x += s0.x; r0.y += s0.y; r0.z += s0.z; r0.w += s0.w;
                    r1.x += s1.x; r1.y += s1.y; r1.z += s1.z; r1.w += s1.w;
                    r2.x += s2.x; r2.y += s2.y; r2.z += s2.z; r2.w += s2.w;
                    r3.x += s3.x; r3.y += s3.y; r3.z += s3.z; r3.w += s3.w;
                }
            }
            __syncthreads();

            short8v af0 = *(const short8v*)&Al[((mbase + 0) * 64 + l) * 8];
            short8v af1 = *(const short8v*)&Al[((mbase + 1) * 64 + l) * 8];
            short8v af2 = *(const short8v*)&Al[((mbase + 2) * 64 + l) * 8];
            short8v af3 = *(const short8v*)&Al[((mbase + 3) * 64 + l) * 8];
            short8v bf0 = *(const short8v*)&Wl[((kc * 4 + nbase + 0) * 64 + l) * 8];
            short8v bf1 = *(const short8v*)&Wl[((kc * 4 + nbase + 1) * 64 + l) * 8];

            acc[0][0] = __builtin_amdgcn_mfma_f32_16x16x32_bf16(af0, bf0, acc[0][0], 0, 0, 0);
            acc[0][1] = __builtin_amdgcn_mfma_f32_16x16x32_bf16(af0, bf1, acc[0][1], 0, 0, 0);
            acc[1][0] = __builtin_amdgcn_mfma_f32_16x16x32_bf16(af1, bf0, acc[1][0], 0, 0, 0);
            acc[1][1] = __builtin_amdgcn_mfma_f32_16x16x32_bf16(af1, bf1, acc[1][1], 0, 0, 0);
            acc[2][0] = __builtin_amdgcn_mfma_f32_16x16x32_bf16(af2, bf0, acc[2][0], 0, 0, 0);
            acc[2][1] = __builtin_amdgcn_mfma_f32_16x16x32_bf16(af2, bf1, acc[2][1], 0, 0, 0);
            acc[3][0] = __builtin_amdgcn_mfma_f32_16x16x32_bf16(af3, bf0, acc[3][0], 0, 0, 0);
            acc[3][1] = __builtin_amdgcn_mfma_f32_16x16x32_bf16(af3, bf1, acc[3][1], 0, 0, 0);

            __syncthreads();
        }
    }

    #pragma unroll
    for (int n = 0; n < 2; n++) {
        int gc = bn + nbase * 16 + n * 16 + (l & 15);
        float bc = bias[gc];
        #pragma unroll
        for (int m = 0; m < 4; m++) {
            int gr0 = bm + mbase * 16 + m * 16 + (l >> 4) * 4;
            #pragma unroll
            for (int r = 0; r < 4; r++) {
                int gr = gr0 + r;
                if (gr >= M) continue;
                float v = acc[m][n][r] + bc;
                if (ADDRES) v += res[(size_t)gr * ldc + coffs + gc];
                if (RELU)   v = fmaxf(v, 0.f);
                C[(size_t)gr * ldc + coffs + gc] = v;
            }
        }
    }
}

// ================================================================ value projection: bf16 MFMA, fragment-direct A loads
// C_bf16[MV][256] = src[MV][256] @ val_w[256][256]^T + val_b.
// Block 256 thr / 4 waves; tile 256 rows x 64 cols (wave w = rows bm+w*64..+63, all 4 n-frags).
// A loaded fragment-direct global->reg (no LDS, NO k-loop barriers); W (L2-resident) staged once.
// 1D grid 2720 blocks, XCD-swizzled (bijective: 2720 = 8*340) so the 4 n-tiles of an
// m-tile are consecutive on ONE XCD -> each A-tile fetched from HBM exactly once.
#define VNB 2720   // (MV/256) * 4
__global__ __launch_bounds__(256) void gemm_val_bf16(const float* __restrict__ A,
                                                     const float* __restrict__ Wt,
                                                     const float* __restrict__ bias,
                                                     ushort_t* __restrict__ C)
{
    __shared__ short Wl[8 * 4 * 64 * 8];   // 32 KB: full K for 64 n-rows, frag-ordered

    const int tid = threadIdx.x;
    const int bid = blockIdx.x;
    const int swz = (bid & 7) * (VNB / 8) + (bid >> 3);
    const int bm = (swz >> 2) * 256, bn = (swz & 3) * 64;

    // ---- stage W once (frag-ordered, same layout as proven kernel) ----
    {
        const int wrow = tid >> 2;            // 0..63
        const int kq   = (tid & 3) * 64;
        const float* wp = Wt + (size_t)(bn + wrow) * D_ + kq;
        #pragma unroll
        for (int grp = 0; grp < 8; grp++) {
            float4 f0 = *(const float4*)(wp + grp * 8);
            float4 f1 = *(const float4*)(wp + grp * 8 + 4);
            short8v v;
            v[0] = (short)f2bf(f0.x); v[1] = (short)f2bf(f0.y);
            v[2] = (short)f2bf(f0.z); v[3] = (short)f2bf(f0.w);
            v[4] = (short)f2bf(f1.x); v[5] = (short)f2bf(f1.y);
            v[6] = (short)f2bf(f1.z); v[7] = (short)f2bf(f1.w);
            int kg = (tid & 3) * 8 + grp;
            int kc = kg >> 2, kin = kg & 3;
            int off = (((kc * 4 + (wrow >> 4)) * 64) + kin * 16 + (wrow & 15)) * 8;
            *(short8v*)&Wl[off] = v;
        }
    }
    __syncthreads();                           // only barrier in the kernel

    const int l = tid & 63, w = tid >> 6;
    const int rowbase = bm + w * 64;
    // lane l loads A[rowbase + mf*16 + (l&15)][kc*32 + (l>>4)*8 + j], j=0..7
    const float* ap = A + (size_t)(rowbase + (l & 15)) * D_ + (l >> 4) * 8;

    float4v acc[4][4];
    #pragma unroll
    for (int mf = 0; mf < 4; mf++)
        #pragma unroll
        for (int nf = 0; nf < 4; nf++)
            acc[mf][nf] = (float4v){0.f, 0.f, 0.f, 0.f};

    #pragma unroll
    for (int kc = 0; kc < 8; kc++) {
        short8v af[4];
        #pragma unroll
        for (int mf = 0; mf < 4; mf++) {
            const float* p = ap + (size_t)(mf * 16) * D_ + kc * 32;
            float4 f0 = *(const float4*)p;
            float4 f1 = *(const float4*)(p + 4);
            short8v v;
            v[0] = (short)f2bf(f0.x); v[1] = (short)f2bf(f0.y);
            v[2] = (short)f2bf(f0.z); v[3] = (short)f2bf(f0.w);
            v[4] = (short)f2bf(f1.x); v[5] = (short)f2bf(f1.y);
            v[6] = (short)f2bf(f1.z); v[7] = (short)f2bf(f1.w);
            af[mf] = v;
        }
        #pragma unroll
        for (int nf = 0; nf < 4; nf++) {
            short8v bf = *(const short8v*)&Wl[((kc * 4 + nf) * 64 + l) * 8];
            acc[0][nf] = __builtin_amdgcn_mfma_f32_16x16x32_bf16(af[0], bf, acc[0][nf], 0, 0, 0);
            acc[1][nf] = __builtin_amdgcn_mfma_f32_16x16x32_bf16(af[1], bf, acc[1][nf], 0, 0, 0);
            acc[2][nf] = __builtin_amdgcn_mfma_f32_16x16x32_bf16(af[2], bf, acc[2][nf], 0, 0, 0);
            acc[3][nf] = __builtin_amdgcn_mfma_f32_16x16x32_bf16(af[3], bf, acc[3][nf], 0, 0, 0);
        }
    }

    // ---- epilogue: row = rowbase + mf*16 + (l>>4)*4 + r, col = bn + nf*16 + (l&15) ----
    #pragma unroll
    for (int nf = 0; nf < 4; nf++) {
        int gc = bn + nf * 16 + (l & 15);
        float bc = bias[gc];
        #pragma unroll
        for (int mf = 0; mf < 4; mf++) {
            int gr = rowbase + mf * 16 + (l >> 4) * 4;
            #pragma unroll
            for (int r = 0; r < 4; r++)
                C[(size_t)(gr + r) * D_ + gc] = f2bf(acc[mf][nf][r] + bc);
        }
    }
}

// ================================================================ bf16-MFMA flash self-attention  [proven R7]
__global__ __launch_bounds__(256) void attn_mfma(const float* __restrict__ QKV,
                                                 float* __restrict__ SA)
{
    const int bh = blockIdx.y;
    const int b = bh >> 3, h = bh & 7;
    const int q0 = blockIdx.x * 64;
    const int tid = threadIdx.x, l = tid & 63, w = tid >> 6;

    __shared__ short Ql[4][64][8];
    __shared__ short Kl[4][64][8];
    __shared__ short Vl[2][2][64][8];
    __shared__ short Pl[4][2][64][8];
    __shared__ float cs[4][16];

    const float scale = 0.17677669529663687f;    // 1/sqrt(32)

    {
        const int qrow = tid >> 2, dgrp = tid & 3;
        const int qg = min(q0 + qrow, NQ_ - 1);
        const float* qp = QKV + ((size_t)(b * NQ_ + qg)) * QKVW + h * HD_ + dgrp * 8;
        float4 f0 = *(const float4*)qp, f1 = *(const float4*)(qp + 4);
        short8v v;
        v[0] = (short)f2bf(f0.x * scale); v[1] = (short)f2bf(f0.y * scale);
        v[2] = (short)f2bf(f0.z * scale); v[3] = (short)f2bf(f0.w * scale);
        v[4] = (short)f2bf(f1.x * scale); v[5] = (short)f2bf(f1.y * scale);
        v[6] = (short)f2bf(f1.z * scale); v[7] = (short)f2bf(f1.w * scale);
        *(short8v*)&Ql[qrow >> 4][(qrow & 15) + 16 * dgrp][0] = v;
    }
    __syncthreads();
    const short8v qf = *(const short8v*)&Ql[w][l][0];

    float m = -INFINITY, lsum = 0.f;
    float4v o0 = (float4v){0.f, 0.f, 0.f, 0.f};
    float4v o1 = (float4v){0.f, 0.f, 0.f, 0.f};

    for (int kt0 = 0; kt0 < NQ_; kt0 += KT_) {
        {
            const int krow = tid >> 2, dgrp = tid & 3;
            const int key = kt0 + krow;
            float4 f0 = make_float4(0.f,0.f,0.f,0.f), f1 = f0;
            float4 g0 = f0, g1 = f0;
            if (key < NQ_) {
                const float* kp = QKV + ((size_t)(b * NQ_ + key)) * QKVW + 256 + h * HD_ + dgrp * 8;
                f0 = *(const float4*)kp;       f1 = *(const float4*)(kp + 4);
                g0 = *(const float4*)(kp+256); g1 = *(const float4*)(kp + 260);
            }
            short8v v;
            v[0] = (short)f2bf(f0.x); v[1] = (short)f2bf(f0.y);
            v[2] = (short)f2bf(f0.z); v[3] = (short)f2bf(f0.w);
            v[4] = (short)f2bf(f1.x); v[5] = (short)f2bf(f1.y);
            v[6] = (short)f2bf(f1.z); v[7] = (short)f2bf(f1.w);
            *(short8v*)&Kl[krow >> 4][(krow & 15) + 16 * dgrp][0] = v;

            const int kf = krow >> 5;
            const int lb = 16 * ((krow & 31) >> 3);
            const int j  = krow & 7;
            const int d0 = dgrp * 8;
            Vl[kf][(d0+0)>>4][((d0+0)&15)+lb][j] = (short)f2bf(g0.x);
            Vl[kf][(d0+1)>>4][((d0+1)&15)+lb][j] = (short)f2bf(g0.y);
            Vl[kf][(d0+2)>>4][((d0+2)&15)+lb][j] = (short)f2bf(g0.z);
            Vl[kf][(d0+3)>>4][((d0+3)&15)+lb][j] = (short)f2bf(g0.w);
            Vl[kf][(d0+4)>>4][((d0+4)&15)+lb][j] = (short)f2bf(g1.x);
            Vl[kf][(d0+5)>>4][((d0+5)&15)+lb][j] = (short)f2bf(g1.y);
            Vl[kf][(d0+6)>>4][((d0+6)&15)+lb][j] = (short)f2bf(g1.z);
            Vl[kf][(d0+7)>>4][((d0+7)&15)+lb][j] = (short)f2bf(g1.w);
        }
        __syncthreads();

        float4v s[4];
        #pragma unroll
        for (int f = 0; f < 4; f++) {
            short8v kfr = *(const short8v*)&Kl[f][l][0];
            s[f] = __builtin_amdgcn_mfma_f32_16x16x32_bf16(
                kfr, qf, (float4v){0.f, 0.f, 0.f, 0.f}, 0, 0, 0);
        }
        if (kt0 + KT_ > NQ_) {
            #pragma unroll
            for (int f = 0; f < 4; f++)
                #pragma unroll
                for (int r = 0; r < 4; r++)
                    if (kt0 + f * 16 + (l >> 4) * 4 + r >= NQ_) s[f][r] = -1e30f;
        }

        float tm = -1e30f;
        #pragma unroll
        for (int f = 0; f < 4; f++)
            #pragma unroll
            for (int r = 0; r < 4; r++) tm = fmaxf(tm, s[f][r]);
        tm = fmaxf(tm, __shfl_xor(tm, 16));
        tm = fmaxf(tm, __shfl_xor(tm, 32));
        float mnew = fmaxf(m, tm);
        float c = __expf(m - mnew);
        m = mnew;
        float ps = 0.f;
        #pragma unroll
        for (int f = 0; f < 4; f++)
            #pragma unroll
            for (int r = 0; r < 4; r++) {
                float p = __expf(s[f][r] - m);
                s[f][r] = p; ps += p;
            }
        ps += __shfl_xor(ps, 16);
        ps += __shfl_xor(ps, 32);
        lsum = lsum * c + ps;
        if ((l >> 4) == 0) cs[w][l & 15] = c;
        float4 c4 = *(const float4*)&cs[w][(l >> 4) * 4];
        o0[0] *= c4.x; o0[1] *= c4.y; o0[2] *= c4.z; o0[3] *= c4.w;
        o1[0] *= c4.x; o1[1] *= c4.y; o1[2] *= c4.z; o1[3] *= c4.w;

        #pragma unroll
        for (int f = 0; f < 4; f++) {
            uint_t lo = (uint_t)f2bf(s[f][0]) | ((uint_t)f2bf(s[f][1]) << 16);
            uint_t hi = (uint_t)f2bf(s[f][2]) | ((uint_t)f2bf(s[f][3]) << 16);
            int lp = (l & 15) + 16 * ((f & 1) * 2 + ((l >> 4) >> 1));
            int j0 = ((l >> 4) & 1) * 4;
            *(uint2*)&Pl[w][f >> 1][lp][j0] = make_uint2(lo, hi);
        }
        #pragma unroll
        for (int kf = 0; kf < 2; kf++) {
            short8v pa = *(const short8v*)&Pl[w][kf][l][0];
            short8v v0 = *(const short8v*)&Vl[kf][0][l][0];
            short8v v1 = *(const short8v*)&Vl[kf][1][l][0];
            o0 = __builtin_amdgcn_mfma_f32_16x16x32_bf16(pa, v0, o0, 0, 0, 0);
            o1 = __builtin_amdgcn_mfma_f32_16x16x32_bf16(pa, v1, o1, 0, 0, 0);
        }
        __syncthreads();
    }

    if ((l >> 4) == 0) cs[w][l & 15] = lsum;
    float4 l4 = *(const float4*)&cs[w][(l >> 4) * 4];
    float linv[4] = {1.f / l4.x, 1.f / l4.y, 1.f / l4.z, 1.f / l4.w};
    #pragma unroll
    for (int r = 0; r < 4; r++) {
        int qg = q0 + w * 16 + (l >> 4) * 4 + r;
        if (qg < NQ_) {
            float* op = SA + ((size_t)(b * NQ_ + qg)) * D_ + h * HD_ + (l & 15);
            op[0]  = o0[r] * linv[r];
            op[16] = o1[r] * linv[r];
        }
    }
}

// ================================================================ LayerNorm(x + y) * g + b
__global__ __launch_bounds__(64) void ln_kernel(const float* __restrict__ X,
                                                const float* __restrict__ Y,
                                                const float* __restrict__ g,
                                                const float* __restrict__ bt,
                                                float* __restrict__ out)
{
    const int row = blockIdx.x;
    const int lane = threadIdx.x;
    const size_t base = (size_t)row * D_ + lane * 4;
    float4 x = *(const float4*)&X[base];
    float4 y = *(const float4*)&Y[base];
    float v0 = x.x + y.x, v1 = x.y + y.y, v2 = x.z + y.z, v3 = x.w + y.w;
    float s = v0 + v1 + v2 + v3;
    #pragma unroll
    for (int o = 32; o; o >>= 1) s += __shfl_xor(s, o);
    float mean = s * (1.f / D_);
    float d0 = v0 - mean, d1 = v1 - mean, d2 = v2 - mean, d3 = v3 - mean;
    float ss = d0 * d0 + d1 * d1 + d2 * d2 + d3 * d3;
    #pragma unroll
    for (int o = 32; o; o >>= 1) ss += __shfl_xor(ss, o);
    float rstd = rsqrtf(ss * (1.f / D_) + 1e-5f);
    float4 gg = *(const float4*)&g[lane * 4];
    float4 bb = *(const float4*)&bt[lane * 4];
    float4 o4 = make_float4(d0 * rstd * gg.x + bb.x, d1 * rstd * gg.y + bb.y,
                            d2 * rstd * gg.z + bb.z, d3 * rstd * gg.w + bb.w);
    *(float4*)&out[base] = o4;
}

// ================================================================ softmax over 16 aw logits, in place
__global__ __launch_bounds__(256) void aw_softmax_kernel(float* __restrict__ offaw)
{
    int t = blockIdx.x * 256 + threadIdx.x;
    if (t >= M1 * H_) return;
    const int bq = t >> 3, h = t & 7;
    float* p = offaw + (size_t)bq * OAW + 256 + h * 16;
    float v[16];
    #pragma unroll
    for (int i = 0; i < 16; i += 4) {
        float4 q = *(const float4*)&p[i];
        v[i] = q.x; v[i+1] = q.y; v[i+2] = q.z; v[i+3] = q.w;
    }
    float m = v[0];
    #pragma unroll
    for (int i = 1; i < 16; i++) m = fmaxf(m, v[i]);
    float s = 0.f;
    #pragma unroll
    for (int i = 0; i < 16; i++) { v[i] = __expf(v[i] - m); s += v[i]; }
    float inv = 1.f / s;
    #pragma unroll
    for (int i = 0; i < 16; i += 4) {
        float4 q = make_float4(v[i] * inv, v[i+1] * inv, v[i+2] * inv, v[i+3] * inv);
        *(float4*)&p[i] = q;
    }
}

// ================================================================ MSDA bilinear sampling (bf16 value)
__global__ __launch_bounds__(256) void msda_kernel(const ushort_t* __restrict__ value,
                                                   const float* __restrict__ offaw,
                                                   const float* __restrict__ ref,
                                                   float* __restrict__ out)
{
    const int g    = threadIdx.x >> 5;
    const int lane = threadIdx.x & 31;
    const int t    = blockIdx.x * 8 + g;
    const int h  = t & 7;
    const int bq = t >> 3;
    const int b  = bq / NQ_;
    const float* offp = offaw + (size_t)bq * OAW + h * (L_ * P_ * 2);
    const float* awp  = offaw + (size_t)bq * OAW + 256 + h * (L_ * P_);
    const float* refp = ref + (size_t)bq * (L_ * 2);
    const ushort_t* vb = value + ((size_t)b * NV_) * D_ + h * HD_ + lane;

    float acc = 0.f;
    const int LW[4] = {128, 64, 32, 16};
    const int LS[4] = {0, 16384, 20480, 21504};

    #pragma unroll
    for (int l = 0; l < L_; l++) {
        const int wi = LW[l];
        const float Wf = (float)wi;
        float rx = refp[2 * l], ry = refp[2 * l + 1];
        #pragma unroll
        for (int p = 0; p < P_; p++) {
            float ox = offp[(l * P_ + p) * 2];
            float oy = offp[(l * P_ + p) * 2 + 1];
            float a  = awp[l * P_ + p];
            float lx = rx * Wf + ox - 0.5f;
            float ly = ry * Wf + oy - 0.5f;
            float x0f = floorf(lx), y0f = floorf(ly);
            float fx = lx - x0f, fy = ly - y0f;
            int x0 = (int)x0f, y0 = (int)y0f;
            #pragma unroll
            for (int dy = 0; dy < 2; dy++) {
                int yi = y0 + dy;
                if (yi < 0 || yi >= wi) continue;
                float wy = dy ? fy : 1.f - fy;
                #pragma unroll
                for (int dx = 0; dx < 2; dx++) {
                    int xi = x0 + dx;
                    if (xi < 0 || xi >= wi) continue;
                    float w = wy * (dx ? fx : 1.f - fx) * a;
                    acc += w * bf2f(vb[(size_t)(LS[l] + yi * wi + xi) * D_]);
                }
            }
        }
    }
    out[(size_t)bq * D_ + h * HD_ + lane] = acc;
}

// ================================================================ launch
extern "C" void kernel_launch(void* const* d_in, const int* in_sizes, int n_in,
                              void* d_out, int out_size, void* d_ws, size_t ws_size,
                              hipStream_t stream)
{
    const float* tgt      = (const float*)d_in[0];
    const float* qpos     = (const float*)d_in[1];
    const float* ref      = (const float*)d_in[2];
    const float* src      = (const float*)d_in[3];
    const float* sa_in_w  = (const float*)d_in[4];
    const float* sa_in_b  = (const float*)d_in[5];
    const float* sa_out_w = (const float*)d_in[6];
    const float* sa_out_b = (const float*)d_in[7];
    const float* ln2_g    = (const float*)d_in[8];
    const float* ln2_b    = (const float*)d_in[9];
    const float* off_w    = (const float*)d_in[10];
    const float* off_b    = (const float*)d_in[11];
    const float* aw_w     = (const float*)d_in[12];
    const float* aw_b     = (const float*)d_in[13];
    const float* val_w    = (const float*)d_in[14];
    const float* val_b    = (const float*)d_in[15];
    const float* out_w    = (const float*)d_in[16];
    const float* out_b    = (const float*)d_in[17];
    const float* ln1_g    = (const float*)d_in[18];
    const float* ln1_b    = (const float*)d_in[19];
    const float* ffn1_w   = (const float*)d_in[20];
    const float* ffn1_b   = (const float*)d_in[21];
    const float* ffn2_w   = (const float*)d_in[22];
    const float* ffn2_b   = (const float*)d_in[23];
    const float* ln3_g    = (const float*)d_in[24];
    const float* ln3_b    = (const float*)d_in[25];

    // ---- workspace layout, lifetime-checked aliases ----
    float* ws      = (float*)d_ws;
    ushort_t* value = (ushort_t*)ws;                 // [MV*256] bf16 = 22,282,240 f32-slots
    float* qkv   = ws + 22282240;                    // [M1*768]
    float* battn = qkv + (size_t)M1 * QKVW;          // [M1*256]
    float* b2    = battn + (size_t)M1 * D_;          // [M1*256]  tgt2
    float* b4    = b2 + (size_t)M1 * D_;             // [M1*256]  tgt3
    float* hid   = b4 + (size_t)M1 * D_;             // [M1*1024] ffn hidden
    float* bsa   = qkv;                              // sa_out out (qkv dead after attn)
    float* offaw = qkv + (size_t)M1 * D_;            // [M1*384]
    float* bmsda = qkv;                              // msda out
    float* bca   = battn;                            // ca out
    float* bffn  = qkv;                              // ffn2 out
    float* out   = (float*)d_out;

    const dim3 g57_4(4, 57), g57_8(8, 57), g57_2(2, 57), g57_16(16, 57);

    // 1. qkv projection: q,k (A=tgt+qpos, N=512) and v (A=tgt, N=256) into fused [M1][768]
    gemm_mfma<true,  false, false><<<g57_8, 256, 0, stream>>>(
        tgt, qpos, sa_in_w, sa_in_b, nullptr, qkv, M1, D_, QKVW, 0);
    gemm_mfma<false, false, false><<<g57_4, 256, 0, stream>>>(
        tgt, nullptr, sa_in_w + 2 * D_ * D_, sa_in_b + 2 * D_, nullptr, qkv, M1, D_, QKVW, 512);
    // 2. value = src @ val_w^T + val_b   (bf16 out; direct-A, XCD-swizzled)
    gemm_val_bf16<<<VNB, 256, 0, stream>>>(src, val_w, val_b, value);
    // 3. bf16-MFMA flash self-attention
    attn_mfma<<<dim3((NQ_ + 63) / 64, BS_ * H_), 256, 0, stream>>>(qkv, battn);
    // 4. sa_out projection
    gemm_mfma<false, false, false><<<g57_4, 256, 0, stream>>>(
        battn, nullptr, sa_out_w, sa_out_b, nullptr, bsa, M1, D_, D_, 0);
    // 5. tgt2 = LN(tgt + sa)
    ln_kernel<<<M1, 64, 0, stream>>>(tgt, bsa, ln2_g, ln2_b, b2);
    // 6. off (N=256) + aw (N=128) projections, A = tgt2 + qpos, into fused [M1][384]
    gemm_mfma<true, false, false><<<g57_4, 256, 0, stream>>>(
        b2, qpos, off_w, off_b, nullptr, offaw, M1, D_, OAW, 0);
    gemm_mfma<true, false, false><<<g57_2, 256, 0, stream>>>(
        b2, qpos, aw_w, aw_b, nullptr, offaw, M1, D_, OAW, 256);
    // 7. softmax over aw logits
    aw_softmax_kernel<<<(M1 * H_ + 255) / 256, 256, 0, stream>>>(offaw);
    // 8. MSDA sampling (bf16 value)
    msda_kernel<<<M1 * H_ / 8, 256, 0, stream>>>(value, offaw, ref, bmsda);
    // 9. ca = msda @ out_w^T + out_b + tgt2
    gemm_mfma<false, false, true><<<g57_4, 256, 0, stream>>>(
        bmsda, nullptr, out_w, out_b, b2, bca, M1, D_, D_, 0);
    // 10. tgt3 = LN(tgt2 + ca)
    ln_kernel<<<M1, 64, 0, stream>>>(b2, bca, ln1_g, ln1_b, b4);
    // 11. FFN
    gemm_mfma<false, true,  false><<<g57_16, 256, 0, stream>>>(
        b4, nullptr, ffn1_w, ffn1_b, nullptr, hid, M1, D_, DF_, 0);
    gemm_mfma<false, false, false><<<g57_4, 256, 0, stream>>>(
        hid, nullptr, ffn2_w, ffn2_b, nullptr, bffn, M1, DF_, D_, 0);
    // 12. out = LN(tgt3 + ffn)
    ln_kernel<<<M1, 64, 0, stream>>>(b4, bffn, ln3_g, ln3_b, out);
}